// Round 2
// baseline (4957.359 us; speedup 1.0000x reference)
//
#include <hip/hip_runtime.h>
#include <hip/hip_bf16.h>

#define TTT_LR 0.01f
#define LN_EPS 1e-5f

// Problem dims (fixed by reference)
#define BB 4
#define SS 2048
#define DD 1024
#define DSZ 64

typedef __hip_bfloat16 bf16;
typedef __bf16 bf16x8 __attribute__((ext_vector_type(8)));
typedef float f32x4 __attribute__((ext_vector_type(4)));

// ---------------------------------------------------------------------------
// Kernel 0: convert Wv (fp32) -> bf16 for the MFMA V-projection.
// ---------------------------------------------------------------------------
__global__ __launch_bounds__(256) void cvt_kernel(
    const float* __restrict__ src, bf16* __restrict__ dst, int n)
{
    int i = blockIdx.x * 256 + threadIdx.x;
    if (i < n) dst[i] = __float2bfloat16(src[i]);
}

// ---------------------------------------------------------------------------
// Kernel 1: LayerNorm + K/Q projections, all fp32 (h kept fp32 in LDS; h
// also stored to global as bf16 for the MFMA V-projection).
// One block (256 thr) per (b,s) row.
// ---------------------------------------------------------------------------
__global__ __launch_bounds__(256) void ln_kq_kernel(
    const float* __restrict__ x, const float* __restrict__ Wk, const float* __restrict__ bk,
    const float* __restrict__ Wq, const float* __restrict__ bq,
    const float* __restrict__ gamma, const float* __restrict__ beta,
    bf16* __restrict__ hb, float* __restrict__ kbuf, float* __restrict__ qbuf)
{
    __shared__ float hsh[DD];
    __shared__ float red[256];
    __shared__ float red2[256];
    __shared__ float part[256];

    const int row = blockIdx.x;          // 0..B*S-1
    const int tid = threadIdx.x;
    const float* xr = x + (size_t)row * DD;

    float4 v0 = *reinterpret_cast<const float4*>(xr + tid * 4);
    float s = v0.x + v0.y + v0.z + v0.w;
    float s2 = v0.x * v0.x + v0.y * v0.y + v0.z * v0.z + v0.w * v0.w;
    red[tid] = s; red2[tid] = s2;
    __syncthreads();
    for (int off = 128; off > 0; off >>= 1) {
        if (tid < off) { red[tid] += red[tid + off]; red2[tid] += red2[tid + off]; }
        __syncthreads();
    }
    const float mu = red[0] * (1.0f / DD);
    const float var = red2[0] * (1.0f / DD) - mu * mu;
    const float rs = rsqrtf(var + LN_EPS);

    const float vv[4] = {v0.x, v0.y, v0.z, v0.w};
    #pragma unroll
    for (int j = 0; j < 4; ++j) {
        int d = tid * 4 + j;
        float h = (vv[j] - mu) * rs * gamma[d] + beta[d];
        hsh[d] = h;
        hb[(size_t)row * DD + d] = __float2bfloat16(h);
    }
    __syncthreads();

    // k/q projections: 2 threads per output element (128 outputs: 64 k + 64 q)
    const int e = tid >> 1;
    const int half = tid & 1;
    const float* Wrow = (e < DSZ) ? (Wk + (size_t)e * DD) : (Wq + (size_t)(e - DSZ) * DD);
    float acc = 0.f;
    const int d0 = half * 512;
    for (int d = d0; d < d0 + 512; ++d)
        acc = fmaf(hsh[d], Wrow[d], acc);
    part[tid] = acc;
    __syncthreads();
    if (tid < 128) {
        float r = part[tid * 2] + part[tid * 2 + 1];
        if (tid < DSZ) kbuf[(size_t)row * DSZ + tid] = r + bk[tid];
        else           qbuf[(size_t)row * DSZ + (tid - DSZ)] = r + bq[tid - DSZ];
    }
}

// ---------------------------------------------------------------------------
// Kernel 2: values = h @ Wv^T + bv  via bf16 MFMA 16x16x32, fp32 accumulate.
// Block = 4 waves; each block computes a 64x64 output tile (each wave 16x64).
// Fragments loaded directly from global (both operands are K-contiguous).
// A-frag: A[m=lane&15][k=quad*8+j]; C/D: col=lane&15, row=quad*4+reg.
// ---------------------------------------------------------------------------
__global__ __launch_bounds__(256) void vproj_kernel(
    const bf16* __restrict__ h, const bf16* __restrict__ Wv, const float* __restrict__ bv,
    float* __restrict__ vbuf)
{
    const int lane = threadIdx.x & 63;
    const int wave = threadIdx.x >> 6;
    const int m = lane & 15;
    const int quad = lane >> 4;          // 0..3
    const int rbase = blockIdx.y * 64 + wave * 16;
    const int cbase = blockIdx.x * 64;

    f32x4 acc[4] = {};
    for (int k0 = 0; k0 < DD; k0 += 32) {
        const int ko = k0 + quad * 8;
        bf16x8 a = *reinterpret_cast<const bf16x8*>(h + (size_t)(rbase + m) * DD + ko);
        #pragma unroll
        for (int j = 0; j < 4; ++j) {
            bf16x8 bfr = *reinterpret_cast<const bf16x8*>(Wv + (size_t)(cbase + j * 16 + m) * DD + ko);
            acc[j] = __builtin_amdgcn_mfma_f32_16x16x32_bf16(a, bfr, acc[j], 0, 0, 0);
        }
    }
    #pragma unroll
    for (int j = 0; j < 4; ++j) {
        const int col = cbase + j * 16 + m;
        const float bias = bv[col];
        #pragma unroll
        for (int r = 0; r < 4; ++r) {
            const int row = rbase + quad * 4 + r;
            vbuf[(size_t)row * DD + col] = acc[j][r] + bias;
        }
    }
}

// ---------------------------------------------------------------------------
// Kernel 3: the TTT scan. Fully decomposed per (b,d) row: each thread owns
// W[d, 0:64] in registers. k_t/q_t addresses are wave-uniform.
// y_t uses PRE-update W (matches reference scan order).
// ---------------------------------------------------------------------------
__global__ __launch_bounds__(64) void scan_kernel(
    const float* __restrict__ kbuf, const float* __restrict__ qbuf,
    const float* __restrict__ vbuf, const float* __restrict__ x,
    float* __restrict__ out)
{
    const int b = blockIdx.x >> 4;                       // 16 blocks per batch
    const int d = (blockIdx.x & 15) * 64 + threadIdx.x;  // 0..1023

    float W[DSZ];
    #pragma unroll
    for (int s = 0; s < DSZ; ++s) W[s] = 0.f;

    const float* kp = kbuf + (size_t)b * SS * DSZ;
    const float* qp = qbuf + (size_t)b * SS * DSZ;
    const float* vp = vbuf + (size_t)b * SS * DD + d;
    const float* xp = x + (size_t)b * SS * DD + d;
    float* op = out + (size_t)b * SS * DD + d;

    for (int t = 0; t < SS; ++t) {
        const float* kt = kp + (size_t)t * DSZ;
        const float* qt = qp + (size_t)t * DSZ;
        float y = 0.f, p = 0.f;
        #pragma unroll
        for (int s = 0; s < DSZ; ++s) {
            p = fmaf(W[s], kt[s], p);
            y = fmaf(W[s], qt[s], y);
        }
        const float err = p - vp[(size_t)t * DD];
        const float sc = TTT_LR * err;
        #pragma unroll
        for (int s = 0; s < DSZ; ++s)
            W[s] = fmaf(-sc, kt[s], W[s]);
        op[(size_t)t * DD] = xp[(size_t)t * DD] + y;
    }
}

// ---------------------------------------------------------------------------
extern "C" void kernel_launch(void* const* d_in, const int* in_sizes, int n_in,
                              void* d_out, int out_size, void* d_ws, size_t ws_size,
                              hipStream_t stream)
{
    const float* x     = (const float*)d_in[0];
    const float* Wk    = (const float*)d_in[1];
    const float* bk    = (const float*)d_in[2];
    const float* Wv    = (const float*)d_in[3];
    const float* bv    = (const float*)d_in[4];
    const float* Wq    = (const float*)d_in[5];
    const float* bq    = (const float*)d_in[6];
    const float* gamma = (const float*)d_in[7];
    const float* beta  = (const float*)d_in[8];

    char* ws = (char*)d_ws;
    // layout (bytes):
    //   hb   bf16  B*S*D*2   = 16 MiB   @ 0
    //   Wvb  bf16  D*D*2     =  2 MiB   @ 16 MiB
    //   kbuf f32   B*S*DS*4  =  2 MiB   @ 18 MiB
    //   qbuf f32   B*S*DS*4  =  2 MiB   @ 20 MiB
    //   vbuf f32   B*S*D*4   = 32 MiB   @ 22 MiB      (total ~54 MiB)
    const size_t HB_B = (size_t)BB * SS * DD * 2;
    const size_t WV_B = (size_t)DD * DD * 2;
    const size_t KQ_B = (size_t)BB * SS * DSZ * 4;
    bf16*  hb   = (bf16*)ws;
    bf16*  Wvb  = (bf16*)(ws + HB_B);
    float* kbuf = (float*)(ws + HB_B + WV_B);
    float* qbuf = (float*)(ws + HB_B + WV_B + KQ_B);
    float* vbuf = (float*)(ws + HB_B + WV_B + 2 * KQ_B);

    cvt_kernel<<<(DD * DD + 255) / 256, 256, 0, stream>>>(Wv, Wvb, DD * DD);
    ln_kq_kernel<<<BB * SS, 256, 0, stream>>>(x, Wk, bk, Wq, bq, gamma, beta, hb, kbuf, qbuf);
    vproj_kernel<<<dim3(DD / 64, BB * SS / 64), 256, 0, stream>>>(hb, Wvb, bv, vbuf);
    scan_kernel<<<64, 64, 0, stream>>>(kbuf, qbuf, vbuf, x, (float*)d_out);
}

// Round 3
// 1073.764 us; speedup vs baseline: 4.6168x; 4.6168x over previous
//
#include <hip/hip_runtime.h>
#include <hip/hip_bf16.h>

#define TTT_LR 0.01f
#define LN_EPS 1e-5f

// Problem dims (fixed by reference)
#define BB 4
#define SS 2048
#define DD 1024
#define DSZ 64
#define CHUNK 64
#define NC (SS / CHUNK)   // 32
#define MiB (1024ull * 1024ull)

typedef __hip_bfloat16 bf16;
typedef __bf16 bf16x8 __attribute__((ext_vector_type(8)));
typedef float f32x4 __attribute__((ext_vector_type(4)));

// ---------------------------------------------------------------------------
// Kernel 0: convert Wv (fp32) -> bf16 for the MFMA V-projection.
// ---------------------------------------------------------------------------
__global__ __launch_bounds__(256) void cvt_kernel(
    const float* __restrict__ src, bf16* __restrict__ dst, int n)
{
    int i = blockIdx.x * 256 + threadIdx.x;
    if (i < n) dst[i] = __float2bfloat16(src[i]);
}

// ---------------------------------------------------------------------------
// Kernel 1: LayerNorm + K/Q projections, fp32. One block per (b,s) row.
// ---------------------------------------------------------------------------
__global__ __launch_bounds__(256) void ln_kq_kernel(
    const float* __restrict__ x, const float* __restrict__ Wk, const float* __restrict__ bk,
    const float* __restrict__ Wq, const float* __restrict__ bq,
    const float* __restrict__ gamma, const float* __restrict__ beta,
    bf16* __restrict__ hb, float* __restrict__ kbuf, float* __restrict__ qbuf)
{
    __shared__ float hsh[DD];
    __shared__ float red[256];
    __shared__ float red2[256];
    __shared__ float part[256];

    const int row = blockIdx.x;          // 0..B*S-1
    const int tid = threadIdx.x;
    const float* xr = x + (size_t)row * DD;

    float4 v0 = *reinterpret_cast<const float4*>(xr + tid * 4);
    float s = v0.x + v0.y + v0.z + v0.w;
    float s2 = v0.x * v0.x + v0.y * v0.y + v0.z * v0.z + v0.w * v0.w;
    red[tid] = s; red2[tid] = s2;
    __syncthreads();
    for (int off = 128; off > 0; off >>= 1) {
        if (tid < off) { red[tid] += red[tid + off]; red2[tid] += red2[tid + off]; }
        __syncthreads();
    }
    const float mu = red[0] * (1.0f / DD);
    const float var = red2[0] * (1.0f / DD) - mu * mu;
    const float rs = rsqrtf(var + LN_EPS);

    const float vv[4] = {v0.x, v0.y, v0.z, v0.w};
    #pragma unroll
    for (int j = 0; j < 4; ++j) {
        int d = tid * 4 + j;
        float h = (vv[j] - mu) * rs * gamma[d] + beta[d];
        hsh[d] = h;
        hb[(size_t)row * DD + d] = __float2bfloat16(h);
    }
    __syncthreads();

    // k/q projections: 2 threads per output element (64 k + 64 q outputs)
    const int e = tid >> 1;
    const int half = tid & 1;
    const float* Wrow = (e < DSZ) ? (Wk + (size_t)e * DD) : (Wq + (size_t)(e - DSZ) * DD);
    float acc = 0.f;
    const int d0 = half * 512;
    for (int d = d0; d < d0 + 512; d += 4) {
        float4 w = *reinterpret_cast<const float4*>(Wrow + d);
        float4 h4 = *reinterpret_cast<const float4*>(hsh + d);
        acc = fmaf(h4.x, w.x, acc);
        acc = fmaf(h4.y, w.y, acc);
        acc = fmaf(h4.z, w.z, acc);
        acc = fmaf(h4.w, w.w, acc);
    }
    part[tid] = acc;
    __syncthreads();
    if (tid < 128) {
        float r = part[tid * 2] + part[tid * 2 + 1];
        if (tid < DSZ) kbuf[(size_t)row * DSZ + tid] = r + bk[tid];
        else           qbuf[(size_t)row * DSZ + (tid - DSZ)] = r + bq[tid - DSZ];
    }
}

// ---------------------------------------------------------------------------
// Kernel 2: values = h @ Wv^T + bv via bf16 MFMA 16x16x32, fp32 accumulate.
// ---------------------------------------------------------------------------
__global__ __launch_bounds__(256) void vproj_kernel(
    const bf16* __restrict__ h, const bf16* __restrict__ Wv, const float* __restrict__ bv,
    float* __restrict__ vbuf)
{
    const int lane = threadIdx.x & 63;
    const int wave = threadIdx.x >> 6;
    const int m = lane & 15;
    const int quad = lane >> 4;          // 0..3
    const int rbase = blockIdx.y * 64 + wave * 16;
    const int cbase = blockIdx.x * 64;

    f32x4 acc[4] = {};
    for (int k0 = 0; k0 < DD; k0 += 32) {
        const int ko = k0 + quad * 8;
        bf16x8 a = *reinterpret_cast<const bf16x8*>(h + (size_t)(rbase + m) * DD + ko);
        #pragma unroll
        for (int j = 0; j < 4; ++j) {
            bf16x8 bfr = *reinterpret_cast<const bf16x8*>(Wv + (size_t)(cbase + j * 16 + m) * DD + ko);
            acc[j] = __builtin_amdgcn_mfma_f32_16x16x32_bf16(a, bfr, acc[j], 0, 0, 0);
        }
    }
    #pragma unroll
    for (int j = 0; j < 4; ++j) {
        const int col = cbase + j * 16 + m;
        const float bias = bv[col];
        #pragma unroll
        for (int r = 0; r < 4; ++r) {
            const int row = rbase + quad * 4 + r;
            vbuf[(size_t)row * DD + col] = acc[j][r] + bias;
        }
    }
}

// ---------------------------------------------------------------------------
// Kernel 3: per-(b,chunk) prep. G = K K^T, A = Q K^T, forward-sub for
// B (b_t = lr(k_t - sum_{j<t} G[t,j] b_j)), Qt = Q - trilS(A) B.
// Stores G, A, B, Qt. Grid (NC, B), block 256.
// ---------------------------------------------------------------------------
__global__ __launch_bounds__(256) void prep_kernel(
    const float* __restrict__ kbuf, const float* __restrict__ qbuf,
    float* __restrict__ Gb, float* __restrict__ Ab,
    float* __restrict__ Bb, float* __restrict__ Qtb)
{
    __shared__ float Ksh[64 * 65];
    __shared__ float Qsh[64 * 65];
    __shared__ float Gsh[64 * 65];
    __shared__ float Ash[64 * 65];
    __shared__ float Bsh[64 * 65];

    const int c = blockIdx.x, b = blockIdx.y;
    const int tid = threadIdx.x;
    const float* kp = kbuf + ((size_t)b * SS + c * 64) * DSZ;
    const float* qp = qbuf + ((size_t)b * SS + c * 64) * DSZ;

    for (int i = tid; i < 4096; i += 256) {
        Ksh[(i >> 6) * 65 + (i & 63)] = kp[i];
        Qsh[(i >> 6) * 65 + (i & 63)] = qp[i];
    }
    __syncthreads();

    // G[t][j] = k_j . k_t ; A[t][j] = k_j . q_t
    for (int e = tid; e < 4096; e += 256) {
        int t = e >> 6, j = e & 63;
        float g = 0.f, a = 0.f;
        for (int s = 0; s < 64; ++s) {
            float kj = Ksh[j * 65 + s];
            g = fmaf(Ksh[t * 65 + s], kj, g);
            a = fmaf(Qsh[t * 65 + s], kj, a);
        }
        Gsh[t * 65 + j] = g;
        Ash[t * 65 + j] = a;
    }
    __syncthreads();

    // forward substitution for B (wave 0 only; lane = DS column)
    if (tid < 64) {
        for (int t = 0; t < 64; ++t) {
            float acc = Ksh[t * 65 + tid];
            for (int j = 0; j < t; ++j)
                acc = fmaf(-Gsh[t * 65 + j], Bsh[j * 65 + tid], acc);
            Bsh[t * 65 + tid] = TTT_LR * acc;
        }
    }
    __syncthreads();

    // Qt = Q - trilS(A) B ; write all outputs
    const size_t cb = ((size_t)b * NC + c) * 4096;
    for (int e = tid; e < 4096; e += 256) {
        int t = e >> 6, s = e & 63;
        float acc = Qsh[t * 65 + s];
        for (int j = 0; j < t; ++j)
            acc = fmaf(-Ash[t * 65 + j], Bsh[j * 65 + s], acc);
        Qtb[cb + e] = acc;
        Bb[cb + e] = Bsh[t * 65 + s];
        Gb[cb + e] = Gsh[t * 65 + s];
        Ab[cb + e] = Ash[t * 65 + s];
    }
}

// ---------------------------------------------------------------------------
// Kernel 4: U forward-sub (in-place over vbuf) + intra-chunk output.
// u_t = lr(v_t - sum_{j<t} G[t,j] u_j);  out = x + trilS(A) U.
// Grid (4, NC, B) [256 D-cols per block], block 256, one column per thread.
// No intra-loop syncs: each thread touches only its own column.
// ---------------------------------------------------------------------------
__global__ __launch_bounds__(256) void usolve_kernel(
    const float* __restrict__ Gb, const float* __restrict__ Ab,
    const float* __restrict__ x, float* __restrict__ vbuf, float* __restrict__ out)
{
    __shared__ float Gsh[4096];
    __shared__ float Ash[4096];
    __shared__ float Ush[64 * 256];

    const int dblk = blockIdx.x;         // 0..3
    const int c = blockIdx.y, b = blockIdx.z;
    const int tid = threadIdx.x;
    const size_t cb = ((size_t)b * NC + c) * 4096;

    for (int i = tid; i < 4096; i += 256) { Gsh[i] = Gb[cb + i]; Ash[i] = Ab[cb + i]; }
    __syncthreads();

    const int col = dblk * 256 + tid;
    const size_t rowbase = (size_t)b * SS + (size_t)c * 64;

    float vcur = vbuf[(rowbase + 0) * DD + col];
    float xcur = x[(rowbase + 0) * DD + col];
    for (int t = 0; t < 64; ++t) {
        float vnext = 0.f, xnext = 0.f;
        if (t < 63) {                        // prefetch next row
            vnext = vbuf[(rowbase + t + 1) * DD + col];
            xnext = x[(rowbase + t + 1) * DD + col];
        }
        float accU = vcur;
        float accY = 0.f;
        for (int j = 0; j < t; ++j) {
            float uj = Ush[j * 256 + tid];
            accU = fmaf(-Gsh[t * 64 + j], uj, accU);
            accY = fmaf(Ash[t * 64 + j], uj, accY);
        }
        float u = TTT_LR * accU;
        Ush[t * 256 + tid] = u;
        const size_t off = (rowbase + t) * DD + col;
        vbuf[off] = u;                       // vbuf becomes U in place
        out[off] = xcur + accY;              // x + intra-chunk y
        vcur = vnext; xcur = xnext;
    }
}

// ---------------------------------------------------------------------------
// Kernel 5: sequential cross-chunk pass. Z = W0^T (DS x D) per batch, split
// into 16-column blocks (grid 64 x B = 256 blocks). Per chunk:
//   Y += Qt_c Z  (added to out);  Pm = B_c Z - U_c;  Z -= K_c^T Pm.
// Thread (col = tid&15, grp = tid>>4) owns 4 rows per phase.
// ---------------------------------------------------------------------------
__global__ __launch_bounds__(256) void seq_kernel(
    const float* __restrict__ kbuf, const float* __restrict__ Bb,
    const float* __restrict__ Qtb, const float* __restrict__ U,
    float* __restrict__ out)
{
    __shared__ float Ksh[64 * 65];
    __shared__ float Bsh[64 * 65];
    __shared__ float Qsh[64 * 65];
    __shared__ float Zsh[64 * 17];
    __shared__ float Psh[64 * 17];

    const int dblk = blockIdx.x;         // 0..63
    const int b = blockIdx.y;
    const int tid = threadIdx.x;
    const int col = tid & 15, grp = tid >> 4;
    const int d0 = dblk * 16;

    for (int i = tid; i < 64 * 17; i += 256) Zsh[i] = 0.f;
    __syncthreads();

    for (int c = 0; c < NC; ++c) {
        const size_t cb = ((size_t)b * NC + c) * 4096;
        const float* kp = kbuf + ((size_t)b * SS + c * 64) * DSZ;
        for (int i = tid; i < 4096; i += 256) {
            int r = i >> 6, s = i & 63;
            Ksh[r * 65 + s] = kp[i];
            Bsh[r * 65 + s] = Bb[cb + i];
            Qsh[r * 65 + s] = Qtb[cb + i];
        }
        __syncthreads();

        // phase PY: P = B_c Z, Y = Qt_c Z  (uses pre-update Z = W0^T)
        float accP[4] = {0.f, 0.f, 0.f, 0.f};
        float accY[4] = {0.f, 0.f, 0.f, 0.f};
        for (int s = 0; s < 64; ++s) {
            float zv = Zsh[s * 17 + col];
            #pragma unroll
            for (int r = 0; r < 4; ++r) {
                int t = grp * 4 + r;
                accP[r] = fmaf(Bsh[t * 65 + s], zv, accP[r]);
                accY[r] = fmaf(Qsh[t * 65 + s], zv, accY[r]);
            }
        }
        #pragma unroll
        for (int r = 0; r < 4; ++r) {
            int t = grp * 4 + r;
            size_t off = ((size_t)b * SS + (size_t)c * 64 + t) * DD + d0 + col;
            Psh[t * 17 + col] = accP[r] - U[off];
            out[off] += accY[r];
        }
        __syncthreads();

        // phase ZU: Z -= K_c^T Pm
        float accZ[4] = {0.f, 0.f, 0.f, 0.f};
        for (int t = 0; t < 64; ++t) {
            float pv = Psh[t * 17 + col];
            #pragma unroll
            for (int r = 0; r < 4; ++r)
                accZ[r] = fmaf(Ksh[t * 65 + grp * 4 + r], pv, accZ[r]);
        }
        #pragma unroll
        for (int r = 0; r < 4; ++r)
            Zsh[(grp * 4 + r) * 17 + col] -= accZ[r];
        __syncthreads();
    }
}

// ---------------------------------------------------------------------------
extern "C" void kernel_launch(void* const* d_in, const int* in_sizes, int n_in,
                              void* d_out, int out_size, void* d_ws, size_t ws_size,
                              hipStream_t stream)
{
    const float* x     = (const float*)d_in[0];
    const float* Wk    = (const float*)d_in[1];
    const float* bk    = (const float*)d_in[2];
    const float* Wv    = (const float*)d_in[3];
    const float* bv    = (const float*)d_in[4];
    const float* Wq    = (const float*)d_in[5];
    const float* bq    = (const float*)d_in[6];
    const float* gamma = (const float*)d_in[7];
    const float* beta  = (const float*)d_in[8];

    char* ws = (char*)d_ws;
    // layout (54 MiB total):
    //   [0, 16 MiB):  hb (bf16) -- dead after vproj; then reused as
    //                 Gb@0, Ab@2MiB, Bb@4MiB, Qtb@6MiB (2 MiB each, fp32)
    //   [16, 18):     Wvb (bf16)
    //   [18, 20):     kbuf (fp32)   [20, 22): qbuf (fp32)
    //   [22, 54):     vbuf (fp32) -> overwritten in place by U
    bf16*  hb   = (bf16*)ws;
    bf16*  Wvb  = (bf16*)(ws + 16 * MiB);
    float* kbuf = (float*)(ws + 18 * MiB);
    float* qbuf = (float*)(ws + 20 * MiB);
    float* vbuf = (float*)(ws + 22 * MiB);
    float* Gb   = (float*)(ws + 0 * MiB);
    float* Ab   = (float*)(ws + 2 * MiB);
    float* Bb   = (float*)(ws + 4 * MiB);
    float* Qtb  = (float*)(ws + 6 * MiB);

    cvt_kernel<<<(DD * DD + 255) / 256, 256, 0, stream>>>(Wv, Wvb, DD * DD);
    ln_kq_kernel<<<BB * SS, 256, 0, stream>>>(x, Wk, bk, Wq, bq, gamma, beta, hb, kbuf, qbuf);
    vproj_kernel<<<dim3(DD / 64, BB * SS / 64), 256, 0, stream>>>(hb, Wvb, bv, vbuf);
    prep_kernel<<<dim3(NC, BB), 256, 0, stream>>>(kbuf, qbuf, Gb, Ab, Bb, Qtb);
    usolve_kernel<<<dim3(4, NC, BB), 256, 0, stream>>>(Gb, Ab, x, vbuf, (float*)d_out);
    seq_kernel<<<dim3(DD / 16, BB), 256, 0, stream>>>(kbuf, Bb, Qtb, vbuf, (float*)d_out);
}

// Round 4
// 657.655 us; speedup vs baseline: 7.5379x; 1.6327x over previous
//
#include <hip/hip_runtime.h>
#include <hip/hip_bf16.h>

#define TTT_LR 0.01f
#define LN_EPS 1e-5f

// Problem dims (fixed by reference)
#define BB 4
#define SS 2048
#define DD 1024
#define DSZ 64
#define CHUNK 64
#define NC (SS / CHUNK)   // 32
#define NCAT 1152         // 64 k + 64 q + 1024 v output cols
#define MiB (1024ull * 1024ull)

typedef __hip_bfloat16 bf16;
typedef __bf16 bf16x8 __attribute__((ext_vector_type(8)));
typedef float f32x4 __attribute__((ext_vector_type(4)));

// ---------------------------------------------------------------------------
// Kernel 0: concat Wk/Wq/Wv -> bf16 Wcat (1152 x 1024, row-major).
// ---------------------------------------------------------------------------
__global__ __launch_bounds__(256) void cvt_cat_kernel(
    const float* __restrict__ Wk, const float* __restrict__ Wq,
    const float* __restrict__ Wv, bf16* __restrict__ Wcat)
{
    const int i = blockIdx.x * 256 + threadIdx.x;       // float4 group index
    if (i >= NCAT * DD / 4) return;
    const int idx = i * 4;
    const int row = idx >> 10, col = idx & 1023;
    const float* src = (row < 64)  ? (Wk + (size_t)row * DD)
                     : (row < 128) ? (Wq + (size_t)(row - 64) * DD)
                                   : (Wv + (size_t)(row - 128) * DD);
    float4 v = *reinterpret_cast<const float4*>(src + col);
    bf16 h4[4] = {__float2bfloat16(v.x), __float2bfloat16(v.y),
                  __float2bfloat16(v.z), __float2bfloat16(v.w)};
    *reinterpret_cast<ushort4*>(Wcat + idx) = *reinterpret_cast<ushort4*>(h4);
}

// ---------------------------------------------------------------------------
// Kernel 1: LayerNorm only -> h (bf16). One block (256 thr) per (b,s) row.
// Wave-shuffle reductions; fully coalesced float4 loads / 8B stores.
// ---------------------------------------------------------------------------
__global__ __launch_bounds__(256) void ln_kernel(
    const float* __restrict__ x, const float* __restrict__ gamma,
    const float* __restrict__ beta, bf16* __restrict__ hb)
{
    __shared__ float wsum[4], wsum2[4];
    const int row = blockIdx.x, tid = threadIdx.x;
    const int lane = tid & 63, wave = tid >> 6;

    float4 v0 = *reinterpret_cast<const float4*>(x + (size_t)row * DD + tid * 4);
    float s = v0.x + v0.y + v0.z + v0.w;
    float s2 = fmaf(v0.x, v0.x, fmaf(v0.y, v0.y, fmaf(v0.z, v0.z, v0.w * v0.w)));
    #pragma unroll
    for (int off = 32; off > 0; off >>= 1) {
        s  += __shfl_down(s, off, 64);
        s2 += __shfl_down(s2, off, 64);
    }
    if (lane == 0) { wsum[wave] = s; wsum2[wave] = s2; }
    __syncthreads();
    s  = wsum[0] + wsum[1] + wsum[2] + wsum[3];
    s2 = wsum2[0] + wsum2[1] + wsum2[2] + wsum2[3];
    const float mu = s * (1.0f / DD);
    const float rs = rsqrtf(s2 * (1.0f / DD) - mu * mu + LN_EPS);

    float4 g  = *reinterpret_cast<const float4*>(gamma + tid * 4);
    float4 be = *reinterpret_cast<const float4*>(beta + tid * 4);
    bf16 h4[4];
    h4[0] = __float2bfloat16((v0.x - mu) * rs * g.x + be.x);
    h4[1] = __float2bfloat16((v0.y - mu) * rs * g.y + be.y);
    h4[2] = __float2bfloat16((v0.z - mu) * rs * g.z + be.z);
    h4[3] = __float2bfloat16((v0.w - mu) * rs * g.w + be.w);
    *reinterpret_cast<ushort4*>(hb + (size_t)row * DD + tid * 4) =
        *reinterpret_cast<ushort4*>(h4);
}

// ---------------------------------------------------------------------------
// Kernel 2: fused kqv = h @ Wcat^T + bias via bf16 MFMA 16x16x32.
// Block = 4 waves; 64x64 output tile (each wave 16x64). Epilogue routes
// cols 0..63 -> kbuf, 64..127 -> qbuf, 128.. -> vbuf (block-uniform branch).
// A-frag: A[m=lane&15][k=quad*8+j]; C/D: col=lane&15, row=quad*4+reg.
// ---------------------------------------------------------------------------
__global__ __launch_bounds__(256) void kqv_kernel(
    const bf16* __restrict__ h, const bf16* __restrict__ Wcat,
    const float* __restrict__ bk, const float* __restrict__ bq,
    const float* __restrict__ bv,
    float* __restrict__ kbuf, float* __restrict__ qbuf, float* __restrict__ vbuf)
{
    const int lane = threadIdx.x & 63;
    const int wave = threadIdx.x >> 6;
    const int m = lane & 15;
    const int quad = lane >> 4;          // 0..3
    const int rbase = blockIdx.y * 64 + wave * 16;
    const int cbase = blockIdx.x * 64;

    f32x4 acc[4] = {};
    for (int k0 = 0; k0 < DD; k0 += 32) {
        const int ko = k0 + quad * 8;
        bf16x8 a = *reinterpret_cast<const bf16x8*>(h + (size_t)(rbase + m) * DD + ko);
        #pragma unroll
        for (int j = 0; j < 4; ++j) {
            bf16x8 bfr = *reinterpret_cast<const bf16x8*>(Wcat + (size_t)(cbase + j * 16 + m) * DD + ko);
            acc[j] = __builtin_amdgcn_mfma_f32_16x16x32_bf16(a, bfr, acc[j], 0, 0, 0);
        }
    }
    #pragma unroll
    for (int j = 0; j < 4; ++j) {
        const int n = cbase + j * 16 + m;
        float bias; float* base; int coln; int ld;
        if (n < 64)       { bias = bk[n];       base = kbuf; coln = n;       ld = DSZ; }
        else if (n < 128) { bias = bq[n - 64];  base = qbuf; coln = n - 64;  ld = DSZ; }
        else              { bias = bv[n - 128]; base = vbuf; coln = n - 128; ld = DD; }
        #pragma unroll
        for (int r = 0; r < 4; ++r) {
            const int row = rbase + quad * 4 + r;
            base[(size_t)row * ld + coln] = acc[j][r] + bias;
        }
    }
}

// ---------------------------------------------------------------------------
// Kernel 3: per-(b,chunk) prep. G = K K^T, A = Q K^T, forward-sub for
// B (b_t = lr(k_t - sum_{j<t} G[t,j] b_j)), Qt = Q - trilS(A) B.
// ---------------------------------------------------------------------------
__global__ __launch_bounds__(256) void prep_kernel(
    const float* __restrict__ kbuf, const float* __restrict__ qbuf,
    float* __restrict__ Gb, float* __restrict__ Ab,
    float* __restrict__ Bb, float* __restrict__ Qtb)
{
    __shared__ float Ksh[64 * 65];
    __shared__ float Qsh[64 * 65];
    __shared__ float Gsh[64 * 65];
    __shared__ float Ash[64 * 65];
    __shared__ float Bsh[64 * 65];

    const int c = blockIdx.x, b = blockIdx.y;
    const int tid = threadIdx.x;
    const float* kp = kbuf + ((size_t)b * SS + c * 64) * DSZ;
    const float* qp = qbuf + ((size_t)b * SS + c * 64) * DSZ;

    for (int i = tid; i < 4096; i += 256) {
        Ksh[(i >> 6) * 65 + (i & 63)] = kp[i];
        Qsh[(i >> 6) * 65 + (i & 63)] = qp[i];
    }
    __syncthreads();

    for (int e = tid; e < 4096; e += 256) {
        int t = e >> 6, j = e & 63;
        float g = 0.f, a = 0.f;
        for (int s = 0; s < 64; ++s) {
            float kj = Ksh[j * 65 + s];
            g = fmaf(Ksh[t * 65 + s], kj, g);
            a = fmaf(Qsh[t * 65 + s], kj, a);
        }
        Gsh[t * 65 + j] = g;
        Ash[t * 65 + j] = a;
    }
    __syncthreads();

    if (tid < 64) {
        for (int t = 0; t < 64; ++t) {
            float acc = Ksh[t * 65 + tid];
            for (int j = 0; j < t; ++j)
                acc = fmaf(-Gsh[t * 65 + j], Bsh[j * 65 + tid], acc);
            Bsh[t * 65 + tid] = TTT_LR * acc;
        }
    }
    __syncthreads();

    const size_t cb = ((size_t)b * NC + c) * 4096;
    for (int e = tid; e < 4096; e += 256) {
        int t = e >> 6, s = e & 63;
        float acc = Qsh[t * 65 + s];
        for (int j = 0; j < t; ++j)
            acc = fmaf(-Ash[t * 65 + j], Bsh[j * 65 + s], acc);
        Qtb[cb + e] = acc;
        Bb[cb + e] = Bsh[t * 65 + s];
        Gb[cb + e] = Gsh[t * 65 + s];
        Ab[cb + e] = Ash[t * 65 + s];
    }
}

// ---------------------------------------------------------------------------
// Kernel 4: U forward-sub (in-place over vbuf) + intra-chunk output.
// ---------------------------------------------------------------------------
__global__ __launch_bounds__(256) void usolve_kernel(
    const float* __restrict__ Gb, const float* __restrict__ Ab,
    const float* __restrict__ x, float* __restrict__ vbuf, float* __restrict__ out)
{
    __shared__ float Gsh[4096];
    __shared__ float Ash[4096];
    __shared__ float Ush[64 * 256];

    const int dblk = blockIdx.x;         // 0..3
    const int c = blockIdx.y, b = blockIdx.z;
    const int tid = threadIdx.x;
    const size_t cb = ((size_t)b * NC + c) * 4096;

    for (int i = tid; i < 4096; i += 256) { Gsh[i] = Gb[cb + i]; Ash[i] = Ab[cb + i]; }
    __syncthreads();

    const int col = dblk * 256 + tid;
    const size_t rowbase = (size_t)b * SS + (size_t)c * 64;

    float vcur = vbuf[(rowbase + 0) * DD + col];
    float xcur = x[(rowbase + 0) * DD + col];
    for (int t = 0; t < 64; ++t) {
        float vnext = 0.f, xnext = 0.f;
        if (t < 63) {
            vnext = vbuf[(rowbase + t + 1) * DD + col];
            xnext = x[(rowbase + t + 1) * DD + col];
        }
        float accU = vcur;
        float accY = 0.f;
        for (int j = 0; j < t; ++j) {
            float uj = Ush[j * 256 + tid];
            accU = fmaf(-Gsh[t * 64 + j], uj, accU);
            accY = fmaf(Ash[t * 64 + j], uj, accY);
        }
        float u = TTT_LR * accU;
        Ush[t * 256 + tid] = u;
        const size_t off = (rowbase + t) * DD + col;
        vbuf[off] = u;
        out[off] = xcur + accY;
        vcur = vnext; xcur = xnext;
    }
}

// ---------------------------------------------------------------------------
// Kernel 5: sequential cross-chunk pass (32 chunk-steps), 256 blocks.
// ---------------------------------------------------------------------------
__global__ __launch_bounds__(256) void seq_kernel(
    const float* __restrict__ kbuf, const float* __restrict__ Bb,
    const float* __restrict__ Qtb, const float* __restrict__ U,
    float* __restrict__ out)
{
    __shared__ float Ksh[64 * 65];
    __shared__ float Bsh[64 * 65];
    __shared__ float Qsh[64 * 65];
    __shared__ float Zsh[64 * 17];
    __shared__ float Psh[64 * 17];

    const int dblk = blockIdx.x;         // 0..63
    const int b = blockIdx.y;
    const int tid = threadIdx.x;
    const int col = tid & 15, grp = tid >> 4;
    const int d0 = dblk * 16;

    for (int i = tid; i < 64 * 17; i += 256) Zsh[i] = 0.f;
    __syncthreads();

    for (int c = 0; c < NC; ++c) {
        const size_t cb = ((size_t)b * NC + c) * 4096;
        const float* kp = kbuf + ((size_t)b * SS + c * 64) * DSZ;
        for (int i = tid; i < 4096; i += 256) {
            int r = i >> 6, s = i & 63;
            Ksh[r * 65 + s] = kp[i];
            Bsh[r * 65 + s] = Bb[cb + i];
            Qsh[r * 65 + s] = Qtb[cb + i];
        }
        __syncthreads();

        float accP[4] = {0.f, 0.f, 0.f, 0.f};
        float accY[4] = {0.f, 0.f, 0.f, 0.f};
        for (int s = 0; s < 64; ++s) {
            float zv = Zsh[s * 17 + col];
            #pragma unroll
            for (int r = 0; r < 4; ++r) {
                int t = grp * 4 + r;
                accP[r] = fmaf(Bsh[t * 65 + s], zv, accP[r]);
                accY[r] = fmaf(Qsh[t * 65 + s], zv, accY[r]);
            }
        }
        #pragma unroll
        for (int r = 0; r < 4; ++r) {
            int t = grp * 4 + r;
            size_t off = ((size_t)b * SS + (size_t)c * 64 + t) * DD + d0 + col;
            Psh[t * 17 + col] = accP[r] - U[off];
            out[off] += accY[r];
        }
        __syncthreads();

        float accZ[4] = {0.f, 0.f, 0.f, 0.f};
        for (int t = 0; t < 64; ++t) {
            float pv = Psh[t * 17 + col];
            #pragma unroll
            for (int r = 0; r < 4; ++r)
                accZ[r] = fmaf(Ksh[t * 65 + grp * 4 + r], pv, accZ[r]);
        }
        #pragma unroll
        for (int r = 0; r < 4; ++r)
            Zsh[(grp * 4 + r) * 17 + col] -= accZ[r];
        __syncthreads();
    }
}

// ---------------------------------------------------------------------------
extern "C" void kernel_launch(void* const* d_in, const int* in_sizes, int n_in,
                              void* d_out, int out_size, void* d_ws, size_t ws_size,
                              hipStream_t stream)
{
    const float* x     = (const float*)d_in[0];
    const float* Wk    = (const float*)d_in[1];
    const float* bk    = (const float*)d_in[2];
    const float* Wv    = (const float*)d_in[3];
    const float* bv    = (const float*)d_in[4];
    const float* Wq    = (const float*)d_in[5];
    const float* bq    = (const float*)d_in[6];
    const float* gamma = (const float*)d_in[7];
    const float* beta  = (const float*)d_in[8];

    char* ws = (char*)d_ws;
    // layout (bytes), ~54.25 MiB total:
    //   [0, 16 MiB):       hb (bf16, 8192x1024) -- dead after kqv; then reused
    //                      as Gb@0, Ab@2MiB, Bb@4MiB, Qtb@6MiB (2 MiB each)
    //   [16, +2.25 MiB):   Wcat (bf16, 1152x1024)
    //   next 2 MiB:        kbuf (fp32, 8192x64)
    //   next 2 MiB:        qbuf (fp32, 8192x64)
    //   next 32 MiB:       vbuf (fp32, 8192x1024) -> overwritten in place by U
    const size_t WCAT_B = (size_t)NCAT * DD * 2;   // 2.25 MiB
    bf16*  hb   = (bf16*)ws;
    bf16*  Wcat = (bf16*)(ws + 16 * MiB);
    float* kbuf = (float*)(ws + 16 * MiB + WCAT_B);
    float* qbuf = (float*)(ws + 18 * MiB + WCAT_B);
    float* vbuf = (float*)(ws + 20 * MiB + WCAT_B);
    float* Gb   = (float*)(ws + 0 * MiB);
    float* Ab   = (float*)(ws + 2 * MiB);
    float* Bb   = (float*)(ws + 4 * MiB);
    float* Qtb  = (float*)(ws + 6 * MiB);

    cvt_cat_kernel<<<(NCAT * DD / 4 + 255) / 256, 256, 0, stream>>>(Wk, Wq, Wv, Wcat);
    ln_kernel<<<BB * SS, 256, 0, stream>>>(x, gamma, beta, hb);
    kqv_kernel<<<dim3(NCAT / 64, BB * SS / 64), 256, 0, stream>>>(
        hb, Wcat, bk, bq, bv, kbuf, qbuf, vbuf);
    prep_kernel<<<dim3(NC, BB), 256, 0, stream>>>(kbuf, qbuf, Gb, Ab, Bb, Qtb);
    usolve_kernel<<<dim3(4, NC, BB), 256, 0, stream>>>(Gb, Ab, x, vbuf, (float*)d_out);
    seq_kernel<<<dim3(DD / 16, BB), 256, 0, stream>>>(kbuf, Bb, Qtb, vbuf, (float*)d_out);
}

// Round 5
// 367.589 us; speedup vs baseline: 13.4861x; 1.7891x over previous
//
#include <hip/hip_runtime.h>
#include <hip/hip_bf16.h>

#define TTT_LR 0.01f
#define LN_EPS 1e-5f

// Problem dims (fixed by reference)
#define BB 4
#define SS 2048
#define DD 1024
#define DSZ 64
#define CHUNK 64
#define NC (SS / CHUNK)   // 32
#define NCAT 1152         // 64 k + 64 q + 1024 v output cols
#define MiB (1024ull * 1024ull)

typedef __hip_bfloat16 bf16;
typedef __bf16 bf16x8 __attribute__((ext_vector_type(8)));
typedef float f32x4 __attribute__((ext_vector_type(4)));

__device__ __forceinline__ void gload_lds16(const void* g, void* l) {
    __builtin_amdgcn_global_load_lds(
        (const __attribute__((address_space(1))) unsigned int*)g,
        (__attribute__((address_space(3))) unsigned int*)l, 16, 0, 0);
}

// ---------------------------------------------------------------------------
// Kernel 0: concat Wk/Wq/Wv -> bf16 Wcat (1152 x 1024, row-major).
// ---------------------------------------------------------------------------
__global__ __launch_bounds__(256) void cvt_cat_kernel(
    const float* __restrict__ Wk, const float* __restrict__ Wq,
    const float* __restrict__ Wv, bf16* __restrict__ Wcat)
{
    const int i = blockIdx.x * 256 + threadIdx.x;       // float4 group index
    if (i >= NCAT * DD / 4) return;
    const int idx = i * 4;
    const int row = idx >> 10, col = idx & 1023;
    const float* src = (row < 64)  ? (Wk + (size_t)row * DD)
                     : (row < 128) ? (Wq + (size_t)(row - 64) * DD)
                                   : (Wv + (size_t)(row - 128) * DD);
    float4 v = *reinterpret_cast<const float4*>(src + col);
    bf16 h4[4] = {__float2bfloat16(v.x), __float2bfloat16(v.y),
                  __float2bfloat16(v.z), __float2bfloat16(v.w)};
    *reinterpret_cast<ushort4*>(Wcat + idx) = *reinterpret_cast<ushort4*>(h4);
}

// ---------------------------------------------------------------------------
// Kernel 1: LayerNorm only -> h (bf16). One block (256 thr) per (b,s) row.
// ---------------------------------------------------------------------------
__global__ __launch_bounds__(256) void ln_kernel(
    const float* __restrict__ x, const float* __restrict__ gamma,
    const float* __restrict__ beta, bf16* __restrict__ hb)
{
    __shared__ float wsum[4], wsum2[4];
    const int row = blockIdx.x, tid = threadIdx.x;
    const int lane = tid & 63, wave = tid >> 6;

    float4 v0 = *reinterpret_cast<const float4*>(x + (size_t)row * DD + tid * 4);
    float s = v0.x + v0.y + v0.z + v0.w;
    float s2 = fmaf(v0.x, v0.x, fmaf(v0.y, v0.y, fmaf(v0.z, v0.z, v0.w * v0.w)));
    #pragma unroll
    for (int off = 32; off > 0; off >>= 1) {
        s  += __shfl_down(s, off, 64);
        s2 += __shfl_down(s2, off, 64);
    }
    if (lane == 0) { wsum[wave] = s; wsum2[wave] = s2; }
    __syncthreads();
    s  = wsum[0] + wsum[1] + wsum[2] + wsum[3];
    s2 = wsum2[0] + wsum2[1] + wsum2[2] + wsum2[3];
    const float mu = s * (1.0f / DD);
    const float rs = rsqrtf(s2 * (1.0f / DD) - mu * mu + LN_EPS);

    float4 g  = *reinterpret_cast<const float4*>(gamma + tid * 4);
    float4 be = *reinterpret_cast<const float4*>(beta + tid * 4);
    bf16 h4[4];
    h4[0] = __float2bfloat16((v0.x - mu) * rs * g.x + be.x);
    h4[1] = __float2bfloat16((v0.y - mu) * rs * g.y + be.y);
    h4[2] = __float2bfloat16((v0.z - mu) * rs * g.z + be.z);
    h4[3] = __float2bfloat16((v0.w - mu) * rs * g.w + be.w);
    *reinterpret_cast<ushort4*>(hb + (size_t)row * DD + tid * 4) =
        *reinterpret_cast<ushort4*>(h4);
}

// ---------------------------------------------------------------------------
// Kernel 2: fused kqv = h @ Wcat^T + bias. m97-style: 128x128 tile, BK=64,
// global_load_lds(16B) staging, XOR-swizzled 16B blocks (swizzle on global
// source address; frag reads un-swizzle -> 2-way banking = free).
// Wave w -> (wr=w>>1, wc=w&1) 64x64 quadrant; 4x4 f32x4 accumulators.
// ---------------------------------------------------------------------------
__global__ __launch_bounds__(256) void kqv_kernel(
    const bf16* __restrict__ h, const bf16* __restrict__ Wcat,
    const float* __restrict__ bk, const float* __restrict__ bq,
    const float* __restrict__ bv,
    float* __restrict__ kbuf, float* __restrict__ qbuf, float* __restrict__ vbuf)
{
    __shared__ bf16 Ash[128 * 64];
    __shared__ bf16 Bsh[128 * 64];
    const int tid = threadIdx.x, lane = tid & 63, wave = tid >> 6;
    const int m = lane & 15, quad = lane >> 4;
    const int wr = wave >> 1, wc = wave & 1;
    const int m0 = blockIdx.y * 128;     // h rows
    const int n0 = blockIdx.x * 128;     // Wcat rows

    const int srow = wave * 8 + (lane >> 3);   // staging row (+ i*32)
    const int scb = lane & 7;                  // staging 16B-block in row

    f32x4 acc[4][4] = {};

    for (int k0 = 0; k0 < DD; k0 += 64) {
        __syncthreads();                       // prior frag reads done
        #pragma unroll
        for (int i = 0; i < 4; ++i) {
            const int row = i * 32 + srow;
            const int g16 = scb ^ (row & 7);   // swizzled source block
            gload_lds16(h    + (size_t)(m0 + row) * DD + k0 + g16 * 8,
                        (char*)Ash + (size_t)(i * 32 + wave * 8) * 128);
            gload_lds16(Wcat + (size_t)(n0 + row) * DD + k0 + g16 * 8,
                        (char*)Bsh + (size_t)(i * 32 + wave * 8) * 128);
        }
        __syncthreads();                       // DMA drained (vmcnt0 @ barrier)
        #pragma unroll
        for (int ks = 0; ks < 2; ++ks) {
            bf16x8 af[4], bfr[4];
            #pragma unroll
            for (int mt = 0; mt < 4; ++mt) {
                const int row = wr * 64 + mt * 16 + m;
                const int kb = (ks * 4 + quad) ^ (row & 7);
                af[mt] = *reinterpret_cast<const bf16x8*>(&Ash[row * 64 + kb * 8]);
            }
            #pragma unroll
            for (int nt = 0; nt < 4; ++nt) {
                const int row = wc * 64 + nt * 16 + m;
                const int kb = (ks * 4 + quad) ^ (row & 7);
                bfr[nt] = *reinterpret_cast<const bf16x8*>(&Bsh[row * 64 + kb * 8]);
            }
            #pragma unroll
            for (int mt = 0; mt < 4; ++mt)
                #pragma unroll
                for (int nt = 0; nt < 4; ++nt)
                    acc[mt][nt] = __builtin_amdgcn_mfma_f32_16x16x32_bf16(
                        af[mt], bfr[nt], acc[mt][nt], 0, 0, 0);
        }
    }

    #pragma unroll
    for (int nt = 0; nt < 4; ++nt) {
        const int n = n0 + wc * 64 + nt * 16 + m;
        float bias; float* base; int coln, ld;
        if (n < 64)       { bias = bk[n];       base = kbuf; coln = n;       ld = DSZ; }
        else if (n < 128) { bias = bq[n - 64];  base = qbuf; coln = n - 64;  ld = DSZ; }
        else              { bias = bv[n - 128]; base = vbuf; coln = n - 128; ld = DD; }
        #pragma unroll
        for (int mt = 0; mt < 4; ++mt) {
            const int row = m0 + wr * 64 + mt * 16 + quad * 4;
            #pragma unroll
            for (int r = 0; r < 4; ++r)
                base[(size_t)(row + r) * ld + coln] = acc[mt][nt][r] + bias;
        }
    }
}

// ---------------------------------------------------------------------------
// Kernel 3: per-(b,chunk) prep (fp32 internally). Outputs:
//   Gb, Ab (fp32, for usolve); Bb16, Qtb16 (bf16 [t][s]); Ktb16 = -K^T
//   (bf16 [s][t]) for the MFMA seq pass.
// ---------------------------------------------------------------------------
__global__ __launch_bounds__(256) void prep_kernel(
    const float* __restrict__ kbuf, const float* __restrict__ qbuf,
    float* __restrict__ Gb, float* __restrict__ Ab,
    bf16* __restrict__ Bb16, bf16* __restrict__ Qtb16, bf16* __restrict__ Ktb16)
{
    __shared__ float Ksh[64 * 65];
    __shared__ float Qsh[64 * 65];
    __shared__ float Gsh[64 * 65];
    __shared__ float Ash[64 * 65];
    __shared__ float Bsh[64 * 65];

    const int c = blockIdx.x, b = blockIdx.y;
    const int tid = threadIdx.x;
    const float* kp = kbuf + ((size_t)b * SS + c * 64) * DSZ;
    const float* qp = qbuf + ((size_t)b * SS + c * 64) * DSZ;

    for (int i = tid; i < 4096; i += 256) {
        Ksh[(i >> 6) * 65 + (i & 63)] = kp[i];
        Qsh[(i >> 6) * 65 + (i & 63)] = qp[i];
    }
    __syncthreads();

    for (int e = tid; e < 4096; e += 256) {
        int t = e >> 6, j = e & 63;
        float g = 0.f, a = 0.f;
        for (int s = 0; s < 64; ++s) {
            float kj = Ksh[j * 65 + s];
            g = fmaf(Ksh[t * 65 + s], kj, g);
            a = fmaf(Qsh[t * 65 + s], kj, a);
        }
        Gsh[t * 65 + j] = g;
        Ash[t * 65 + j] = a;
    }
    __syncthreads();

    if (tid < 64) {
        for (int t = 0; t < 64; ++t) {
            float acc = Ksh[t * 65 + tid];
            for (int j = 0; j < t; ++j)
                acc = fmaf(-Gsh[t * 65 + j], Bsh[j * 65 + tid], acc);
            Bsh[t * 65 + tid] = TTT_LR * acc;
        }
    }
    __syncthreads();

    const size_t cb = ((size_t)b * NC + c) * 4096;
    for (int e = tid; e < 4096; e += 256) {
        int t = e >> 6, s = e & 63;
        float acc = Qsh[t * 65 + s];
        for (int j = 0; j < t; ++j)
            acc = fmaf(-Ash[t * 65 + j], Bsh[j * 65 + s], acc);
        Qtb16[cb + e] = __float2bfloat16(acc);
        Bb16[cb + e] = __float2bfloat16(Bsh[t * 65 + s]);
        Gb[cb + e] = Gsh[t * 65 + s];
        Ab[cb + e] = Ash[t * 65 + s];
        Ktb16[cb + s * 64 + t] = __float2bfloat16(-Ksh[t * 65 + s]);
    }
}

// ---------------------------------------------------------------------------
// Kernel 4: U forward-sub (in-place over vbuf) + intra-chunk output.
// ---------------------------------------------------------------------------
__global__ __launch_bounds__(256) void usolve_kernel(
    const float* __restrict__ Gb, const float* __restrict__ Ab,
    const float* __restrict__ x, float* __restrict__ vbuf, float* __restrict__ out)
{
    __shared__ float Gsh[4096];
    __shared__ float Ash[4096];
    __shared__ float Ush[64 * 256];

    const int dblk = blockIdx.x;         // 0..3
    const int c = blockIdx.y, b = blockIdx.z;
    const int tid = threadIdx.x;
    const size_t cb = ((size_t)b * NC + c) * 4096;

    for (int i = tid; i < 4096; i += 256) { Gsh[i] = Gb[cb + i]; Ash[i] = Ab[cb + i]; }
    __syncthreads();

    const int col = dblk * 256 + tid;
    const size_t rowbase = (size_t)b * SS + (size_t)c * 64;

    float vcur = vbuf[(rowbase + 0) * DD + col];
    float xcur = x[(rowbase + 0) * DD + col];
    for (int t = 0; t < 64; ++t) {
        float vnext = 0.f, xnext = 0.f;
        if (t < 63) {
            vnext = vbuf[(rowbase + t + 1) * DD + col];
            xnext = x[(rowbase + t + 1) * DD + col];
        }
        float accU = vcur;
        float accY = 0.f;
        for (int j = 0; j < t; ++j) {
            float uj = Ush[j * 256 + tid];
            accU = fmaf(-Gsh[t * 64 + j], uj, accU);
            accY = fmaf(Ash[t * 64 + j], uj, accY);
        }
        float u = TTT_LR * accU;
        Ush[t * 256 + tid] = u;
        const size_t off = (rowbase + t) * DD + col;
        vbuf[off] = u;
        out[off] = xcur + accY;
        vcur = vnext; xcur = xnext;
    }
}

// ---------------------------------------------------------------------------
// Kernel 5: sequential cross-chunk pass, MFMA version. 256 blocks
// (64 D-column-blocks x 4 batches), 4 waves each. Per chunk (3 matmuls,
// each 64x16x64, 2 MFMA per wave):
//   P = B_c Z - U;  out += Qt_c Z;  Z += (-K^T) P   (Z fp32 in C/D regs,
//   bf16 round-trip via LDS for the next B-operand).
// Zsh/Psh col-major [d][t], stride 72 bf16 (16B-aligned rows, 2-way banks).
// ---------------------------------------------------------------------------
__global__ __launch_bounds__(256) void seq_kernel(
    const bf16* __restrict__ Bb16, const bf16* __restrict__ Qtb16,
    const bf16* __restrict__ Ktb16, const float* __restrict__ U,
    float* __restrict__ out)
{
    __shared__ bf16 Zsh[16][72];
    __shared__ bf16 Psh[16][72];
    const int dblk = blockIdx.x, b = blockIdx.y;
    const int tid = threadIdx.x, lane = tid & 63, w = tid >> 6;
    const int m = lane & 15, quad = lane >> 4;
    const int d0 = dblk * 16;
    const int arow = w * 16 + m;          // A-frag row (all 3 matmuls)
    const int trow = w * 16 + quad * 4;   // first C/D row for this thread

    f32x4 zacc = {0.f, 0.f, 0.f, 0.f};
    for (int i = tid; i < 16 * 72; i += 256)
        (&Zsh[0][0])[i] = __float2bfloat16(0.f);

    for (int c = 0; c < NC; ++c) {
        const size_t cb = ((size_t)b * NC + c) * 4096;
        const size_t gbase = ((size_t)b * SS + (size_t)c * 64 + trow) * DD + d0 + m;
        // issue all global loads up front (independent of LDS state)
        const bf16x8 aB0 = *reinterpret_cast<const bf16x8*>(Bb16 + cb + arow * 64 + quad * 8);
        const bf16x8 aB1 = *reinterpret_cast<const bf16x8*>(Bb16 + cb + arow * 64 + 32 + quad * 8);
        const bf16x8 aQ0 = *reinterpret_cast<const bf16x8*>(Qtb16 + cb + arow * 64 + quad * 8);
        const bf16x8 aQ1 = *reinterpret_cast<const bf16x8*>(Qtb16 + cb + arow * 64 + 32 + quad * 8);
        const bf16x8 aK0 = *reinterpret_cast<const bf16x8*>(Ktb16 + cb + arow * 64 + quad * 8);
        const bf16x8 aK1 = *reinterpret_cast<const bf16x8*>(Ktb16 + cb + arow * 64 + 32 + quad * 8);
        float uld[4], old[4];
        #pragma unroll
        for (int r = 0; r < 4; ++r) {
            uld[r] = U[gbase + (size_t)r * DD];
            old[r] = out[gbase + (size_t)r * DD];
        }

        __syncthreads();                  // A: Zsh ready, Psh free
        const bf16x8 z0 = *reinterpret_cast<const bf16x8*>(&Zsh[m][quad * 8]);
        const bf16x8 z1 = *reinterpret_cast<const bf16x8*>(&Zsh[m][32 + quad * 8]);
        f32x4 pacc = {0.f, 0.f, 0.f, 0.f};
        f32x4 yacc = {0.f, 0.f, 0.f, 0.f};
        pacc = __builtin_amdgcn_mfma_f32_16x16x32_bf16(aB0, z0, pacc, 0, 0, 0);
        pacc = __builtin_amdgcn_mfma_f32_16x16x32_bf16(aB1, z1, pacc, 0, 0, 0);
        yacc = __builtin_amdgcn_mfma_f32_16x16x32_bf16(aQ0, z0, yacc, 0, 0, 0);
        yacc = __builtin_amdgcn_mfma_f32_16x16x32_bf16(aQ1, z1, yacc, 0, 0, 0);

        alignas(8) bf16 pb[4];
        #pragma unroll
        for (int r = 0; r < 4; ++r) {
            out[gbase + (size_t)r * DD] = old[r] + yacc[r];
            pb[r] = __float2bfloat16(pacc[r] - uld[r]);
        }
        *reinterpret_cast<uint2*>(&Psh[m][trow]) = *reinterpret_cast<uint2*>(pb);

        __syncthreads();                  // B: Psh ready, Zsh reads done
        const bf16x8 p0 = *reinterpret_cast<const bf16x8*>(&Psh[m][quad * 8]);
        const bf16x8 p1 = *reinterpret_cast<const bf16x8*>(&Psh[m][32 + quad * 8]);
        zacc = __builtin_amdgcn_mfma_f32_16x16x32_bf16(aK0, p0, zacc, 0, 0, 0);
        zacc = __builtin_amdgcn_mfma_f32_16x16x32_bf16(aK1, p1, zacc, 0, 0, 0);

        alignas(8) bf16 zb[4];
        #pragma unroll
        for (int r = 0; r < 4; ++r) zb[r] = __float2bfloat16(zacc[r]);
        *reinterpret_cast<uint2*>(&Zsh[m][trow]) = *reinterpret_cast<uint2*>(zb);
    }
}

// ---------------------------------------------------------------------------
extern "C" void kernel_launch(void* const* d_in, const int* in_sizes, int n_in,
                              void* d_out, int out_size, void* d_ws, size_t ws_size,
                              hipStream_t stream)
{
    const float* x     = (const float*)d_in[0];
    const float* Wk    = (const float*)d_in[1];
    const float* bk    = (const float*)d_in[2];
    const float* Wv    = (const float*)d_in[3];
    const float* bv    = (const float*)d_in[4];
    const float* Wq    = (const float*)d_in[5];
    const float* bq    = (const float*)d_in[6];
    const float* gamma = (const float*)d_in[7];
    const float* beta  = (const float*)d_in[8];

    char* ws = (char*)d_ws;
    // layout (~54.25 MiB):
    //   [0,16 MiB):  hb (bf16) -- dead after kqv; reused as:
    //                Gb@0 (2 MiB), Ab@2 (2 MiB), Bb16@4 (1 MiB),
    //                Qtb16@5 (1 MiB), Ktb16@6 (1 MiB)
    //   [16 MiB, +2.25):  Wcat (bf16 1152x1024)
    //   +2 MiB: kbuf (fp32)   +2 MiB: qbuf (fp32)
    //   +32 MiB: vbuf (fp32) -> overwritten in place by U
    const size_t WCAT_B = (size_t)NCAT * DD * 2;   // 2.25 MiB
    bf16*  hb    = (bf16*)ws;
    bf16*  Wcat  = (bf16*)(ws + 16 * MiB);
    float* kbuf  = (float*)(ws + 16 * MiB + WCAT_B);
    float* qbuf  = (float*)(ws + 18 * MiB + WCAT_B);
    float* vbuf  = (float*)(ws + 20 * MiB + WCAT_B);
    float* Gb    = (float*)(ws + 0 * MiB);
    float* Ab    = (float*)(ws + 2 * MiB);
    bf16*  Bb16  = (bf16*)(ws + 4 * MiB);
    bf16*  Qtb16 = (bf16*)(ws + 5 * MiB);
    bf16*  Ktb16 = (bf16*)(ws + 6 * MiB);

    cvt_cat_kernel<<<(NCAT * DD / 4 + 255) / 256, 256, 0, stream>>>(Wk, Wq, Wv, Wcat);
    ln_kernel<<<BB * SS, 256, 0, stream>>>(x, gamma, beta, hb);
    kqv_kernel<<<dim3(NCAT / 128, BB * SS / 128), 256, 0, stream>>>(
        hb, Wcat, bk, bq, bv, kbuf, qbuf, vbuf);
    prep_kernel<<<dim3(NC, BB), 256, 0, stream>>>(kbuf, qbuf, Gb, Ab, Bb16, Qtb16, Ktb16);
    usolve_kernel<<<dim3(4, NC, BB), 256, 0, stream>>>(Gb, Ab, x, vbuf, (float*)d_out);
    seq_kernel<<<dim3(DD / 16, BB), 256, 0, stream>>>(Bb16, Qtb16, Ktb16, vbuf, (float*)d_out);
}

// Round 6
// 287.396 us; speedup vs baseline: 17.2492x; 1.2790x over previous
//
#include <hip/hip_runtime.h>
#include <hip/hip_bf16.h>

#define TTT_LR 0.01f
#define LN_EPS 1e-5f

// Problem dims (fixed by reference)
#define BB 4
#define SS 2048
#define DD 1024
#define DSZ 64
#define CHUNK 64
#define NC (SS / CHUNK)   // 32
#define NCAT 1152         // 64 k + 64 q + 1024 v output cols
#define MiB (1024ull * 1024ull)

typedef __hip_bfloat16 bf16;
typedef __bf16 bf16x8 __attribute__((ext_vector_type(8)));
typedef float f32x4 __attribute__((ext_vector_type(4)));

__device__ __forceinline__ void gload_lds16(const void* g, void* l) {
    __builtin_amdgcn_global_load_lds(
        (const __attribute__((address_space(1))) unsigned int*)g,
        (__attribute__((address_space(3))) unsigned int*)l, 16, 0, 0);
}

// ---------------------------------------------------------------------------
// Kernel 0: concat Wk/Wq/Wv -> bf16 Wcat (1152 x 1024, row-major).
// ---------------------------------------------------------------------------
__global__ __launch_bounds__(256) void cvt_cat_kernel(
    const float* __restrict__ Wk, const float* __restrict__ Wq,
    const float* __restrict__ Wv, bf16* __restrict__ Wcat)
{
    const int i = blockIdx.x * 256 + threadIdx.x;       // float4 group index
    if (i >= NCAT * DD / 4) return;
    const int idx = i * 4;
    const int row = idx >> 10, col = idx & 1023;
    const float* src = (row < 64)  ? (Wk + (size_t)row * DD)
                     : (row < 128) ? (Wq + (size_t)(row - 64) * DD)
                                   : (Wv + (size_t)(row - 128) * DD);
    float4 v = *reinterpret_cast<const float4*>(src + col);
    bf16 h4[4] = {__float2bfloat16(v.x), __float2bfloat16(v.y),
                  __float2bfloat16(v.z), __float2bfloat16(v.w)};
    *reinterpret_cast<ushort4*>(Wcat + idx) = *reinterpret_cast<ushort4*>(h4);
}

// ---------------------------------------------------------------------------
// Kernel 1: LayerNorm only -> h (bf16). One block (256 thr) per (b,s) row.
// ---------------------------------------------------------------------------
__global__ __launch_bounds__(256) void ln_kernel(
    const float* __restrict__ x, const float* __restrict__ gamma,
    const float* __restrict__ beta, bf16* __restrict__ hb)
{
    __shared__ float wsum[4], wsum2[4];
    const int row = blockIdx.x, tid = threadIdx.x;
    const int lane = tid & 63, wave = tid >> 6;

    float4 v0 = *reinterpret_cast<const float4*>(x + (size_t)row * DD + tid * 4);
    float s = v0.x + v0.y + v0.z + v0.w;
    float s2 = fmaf(v0.x, v0.x, fmaf(v0.y, v0.y, fmaf(v0.z, v0.z, v0.w * v0.w)));
    #pragma unroll
    for (int off = 32; off > 0; off >>= 1) {
        s  += __shfl_down(s, off, 64);
        s2 += __shfl_down(s2, off, 64);
    }
    if (lane == 0) { wsum[wave] = s; wsum2[wave] = s2; }
    __syncthreads();
    s  = wsum[0] + wsum[1] + wsum[2] + wsum[3];
    s2 = wsum2[0] + wsum2[1] + wsum2[2] + wsum2[3];
    const float mu = s * (1.0f / DD);
    const float rs = rsqrtf(s2 * (1.0f / DD) - mu * mu + LN_EPS);

    float4 g  = *reinterpret_cast<const float4*>(gamma + tid * 4);
    float4 be = *reinterpret_cast<const float4*>(beta + tid * 4);
    bf16 h4[4];
    h4[0] = __float2bfloat16((v0.x - mu) * rs * g.x + be.x);
    h4[1] = __float2bfloat16((v0.y - mu) * rs * g.y + be.y);
    h4[2] = __float2bfloat16((v0.z - mu) * rs * g.z + be.z);
    h4[3] = __float2bfloat16((v0.w - mu) * rs * g.w + be.w);
    *reinterpret_cast<ushort4*>(hb + (size_t)row * DD + tid * 4) =
        *reinterpret_cast<ushort4*>(h4);
}

// ---------------------------------------------------------------------------
// Kernel 2: fused kqv = h @ Wcat^T + bias. 128x128 tile, BK=64,
// global_load_lds(16B) staging, XOR-swizzled 16B blocks. k/q stored fp32;
// v stored bf16 (vbuf16) for the MFMA usolve.
// ---------------------------------------------------------------------------
__global__ __launch_bounds__(256) void kqv_kernel(
    const bf16* __restrict__ h, const bf16* __restrict__ Wcat,
    const float* __restrict__ bk, const float* __restrict__ bq,
    const float* __restrict__ bv,
    float* __restrict__ kbuf, float* __restrict__ qbuf, bf16* __restrict__ vbuf16)
{
    __shared__ bf16 Ash[128 * 64];
    __shared__ bf16 Bsh[128 * 64];
    const int tid = threadIdx.x, lane = tid & 63, wave = tid >> 6;
    const int m = lane & 15, quad = lane >> 4;
    const int wr = wave >> 1, wc = wave & 1;
    const int m0 = blockIdx.y * 128;     // h rows
    const int n0 = blockIdx.x * 128;     // Wcat rows

    const int srow = wave * 8 + (lane >> 3);   // staging row (+ i*32)
    const int scb = lane & 7;                  // staging 16B-block in row

    f32x4 acc[4][4] = {};

    for (int k0 = 0; k0 < DD; k0 += 64) {
        __syncthreads();                       // prior frag reads done
        #pragma unroll
        for (int i = 0; i < 4; ++i) {
            const int row = i * 32 + srow;
            const int g16 = scb ^ (row & 7);   // swizzled source block
            gload_lds16(h    + (size_t)(m0 + row) * DD + k0 + g16 * 8,
                        (char*)Ash + (size_t)(i * 32 + wave * 8) * 128);
            gload_lds16(Wcat + (size_t)(n0 + row) * DD + k0 + g16 * 8,
                        (char*)Bsh + (size_t)(i * 32 + wave * 8) * 128);
        }
        __syncthreads();                       // DMA drained (vmcnt0 @ barrier)
        #pragma unroll
        for (int ks = 0; ks < 2; ++ks) {
            bf16x8 af[4], bfr[4];
            #pragma unroll
            for (int mt = 0; mt < 4; ++mt) {
                const int row = wr * 64 + mt * 16 + m;
                const int kb = (ks * 4 + quad) ^ (row & 7);
                af[mt] = *reinterpret_cast<const bf16x8*>(&Ash[row * 64 + kb * 8]);
            }
            #pragma unroll
            for (int nt = 0; nt < 4; ++nt) {
                const int row = wc * 64 + nt * 16 + m;
                const int kb = (ks * 4 + quad) ^ (row & 7);
                bfr[nt] = *reinterpret_cast<const bf16x8*>(&Bsh[row * 64 + kb * 8]);
            }
            #pragma unroll
            for (int mt = 0; mt < 4; ++mt)
                #pragma unroll
                for (int nt = 0; nt < 4; ++nt)
                    acc[mt][nt] = __builtin_amdgcn_mfma_f32_16x16x32_bf16(
                        af[mt], bfr[nt], acc[mt][nt], 0, 0, 0);
        }
    }

    #pragma unroll
    for (int nt = 0; nt < 4; ++nt) {
        const int n = n0 + wc * 64 + nt * 16 + m;
        if (n < 64) {
            const float bias = bk[n];
            #pragma unroll
            for (int mt = 0; mt < 4; ++mt) {
                const int row = m0 + wr * 64 + mt * 16 + quad * 4;
                #pragma unroll
                for (int r = 0; r < 4; ++r)
                    kbuf[(size_t)(row + r) * DSZ + n] = acc[mt][nt][r] + bias;
            }
        } else if (n < 128) {
            const float bias = bq[n - 64];
            #pragma unroll
            for (int mt = 0; mt < 4; ++mt) {
                const int row = m0 + wr * 64 + mt * 16 + quad * 4;
                #pragma unroll
                for (int r = 0; r < 4; ++r)
                    qbuf[(size_t)(row + r) * DSZ + (n - 64)] = acc[mt][nt][r] + bias;
            }
        } else {
            const float bias = bv[n - 128];
            #pragma unroll
            for (int mt = 0; mt < 4; ++mt) {
                const int row = m0 + wr * 64 + mt * 16 + quad * 4;
                #pragma unroll
                for (int r = 0; r < 4; ++r)
                    vbuf16[(size_t)(row + r) * DD + (n - 128)] =
                        __float2bfloat16(acc[mt][nt][r] + bias);
            }
        }
    }
}

// ---------------------------------------------------------------------------
// Kernel 3: per-(b,chunk) prep (fp32 internally). L = I + lr*trilS(G).
// Outputs (all bf16, 64x64 per chunk):
//   Mb16  = lr * L^-1                     (for U = Mb16 @ V)
//   AMb16 = lr * trilS(A) @ L^-1          (for Y_intra = AMb16 @ V)
//   Bb16  = L^-1 * lr*K,  Qtb16 = Q - trilS(A) B,  Ktb16 = -K^T  (for seq)
// ---------------------------------------------------------------------------
__global__ __launch_bounds__(256) void prep_kernel(
    const float* __restrict__ kbuf, const float* __restrict__ qbuf,
    bf16* __restrict__ Mb16, bf16* __restrict__ AMb16,
    bf16* __restrict__ Bb16, bf16* __restrict__ Qtb16, bf16* __restrict__ Ktb16)
{
    __shared__ float Ksh[64 * 65];
    __shared__ float Qsh[64 * 65];
    __shared__ float Gsh[64 * 65];
    __shared__ float Ash[64 * 65];
    __shared__ float Msh[64 * 65];
    __shared__ float Bsh[64 * 65];

    const int c = blockIdx.x, b = blockIdx.y;
    const int tid = threadIdx.x;
    const float* kp = kbuf + ((size_t)b * SS + c * 64) * DSZ;
    const float* qp = qbuf + ((size_t)b * SS + c * 64) * DSZ;

    for (int i = tid; i < 4096; i += 256) {
        Ksh[(i >> 6) * 65 + (i & 63)] = kp[i];
        Qsh[(i >> 6) * 65 + (i & 63)] = qp[i];
    }
    __syncthreads();

    // G[t][j] = k_t . k_j ; A[t][j] = q_t . k_j
    for (int e = tid; e < 4096; e += 256) {
        int t = e >> 6, j = e & 63;
        float g = 0.f, a = 0.f;
        for (int s = 0; s < 64; ++s) {
            float kj = Ksh[j * 65 + s];
            g = fmaf(Ksh[t * 65 + s], kj, g);
            a = fmaf(Qsh[t * 65 + s], kj, a);
        }
        Gsh[t * 65 + j] = g;
        Ash[t * 65 + j] = a;
    }
    __syncthreads();

    // Minv forward-sub (wave 0; lane = column j). Upper part falls out as 0.
    if (tid < 64) {
        for (int t = 0; t < 64; ++t) {
            float acc = (t == tid) ? 1.f : 0.f;
            for (int i = 0; i < t; ++i)
                acc = fmaf(-TTT_LR * Gsh[t * 65 + i], Msh[i * 65 + tid], acc);
            Msh[t * 65 + tid] = acc;
        }
    }
    __syncthreads();

    // B = Minv * (lr K)
    for (int e = tid; e < 4096; e += 256) {
        int t = e >> 6, s = e & 63;
        float acc = 0.f;
        for (int j = 0; j <= t; ++j)
            acc = fmaf(Msh[t * 65 + j], Ksh[j * 65 + s], acc);
        Bsh[t * 65 + s] = TTT_LR * acc;
    }
    __syncthreads();

    const size_t cb = ((size_t)b * NC + c) * 4096;
    for (int e = tid; e < 4096; e += 256) {
        int t = e >> 6, s = e & 63;
        float qt = Qsh[t * 65 + s];
        float am = 0.f;
        for (int j = 0; j < t; ++j) {
            float aj = Ash[t * 65 + j];
            qt = fmaf(-aj, Bsh[j * 65 + s], qt);
            am = fmaf(aj, Msh[j * 65 + s], am);
        }
        Qtb16[cb + e] = __float2bfloat16(qt);
        AMb16[cb + e] = __float2bfloat16(TTT_LR * am);
        Mb16[cb + e]  = __float2bfloat16(TTT_LR * Msh[t * 65 + s]);
        Bb16[cb + e]  = __float2bfloat16(Bsh[t * 65 + s]);
        Ktb16[cb + s * 64 + t] = __float2bfloat16(-Ksh[t * 65 + s]);
    }
}

// ---------------------------------------------------------------------------
// Kernel 4: usolve via MFMA. Per (b,c,dblk=128 cols):
//   U = Mb16 @ V ; out = x + AMb16 @ V.
// V tile (64t x 128d bf16) staged row-major in LDS (stride 136), B-frags
// read transposed (scalar u16, <=4-way bank alias). A-frags from global.
// Wave w covers d-range w*32..+31 (2 n-tiles) x all 64 t (4 m-tiles).
// ---------------------------------------------------------------------------
__global__ __launch_bounds__(256) void usolve_kernel(
    const bf16* __restrict__ Mb16, const bf16* __restrict__ AMb16,
    const bf16* __restrict__ v16, const float* __restrict__ x,
    bf16* __restrict__ U16, float* __restrict__ out)
{
    __shared__ bf16 Vsh[64 * 136];
    const int tid = threadIdx.x, lane = tid & 63, w = tid >> 6;
    const int m = lane & 15, quad = lane >> 4;
    const int dblk = blockIdx.x, c = blockIdx.y, b = blockIdx.z;
    const int d0 = dblk * 128;
    const size_t cb = ((size_t)b * NC + c) * 4096;
    const size_t rowbase = (size_t)b * SS + (size_t)c * 64;

    // stage V tile (coalesced 16B loads, 16B-aligned LDS writes)
    #pragma unroll
    for (int it = 0; it < 4; ++it) {
        const int j = (tid >> 4) + it * 16;
        const int dd = (tid & 15) * 8;
        bf16x8 vv = *reinterpret_cast<const bf16x8*>(
            v16 + (rowbase + j) * DD + d0 + dd);
        *reinterpret_cast<bf16x8*>(&Vsh[j * 136 + dd]) = vv;
    }

    // A-frags (M and AM) from global: t = mt*16+m, k = ks*32+quad*8
    bf16x8 fM[4][2], fA[4][2];
    #pragma unroll
    for (int mt = 0; mt < 4; ++mt)
        #pragma unroll
        for (int ks = 0; ks < 2; ++ks) {
            const int off = (mt * 16 + m) * 64 + ks * 32 + quad * 8;
            fM[mt][ks] = *reinterpret_cast<const bf16x8*>(Mb16 + cb + off);
            fA[mt][ks] = *reinterpret_cast<const bf16x8*>(AMb16 + cb + off);
        }
    __syncthreads();

    f32x4 uacc[4][2] = {}, yacc[4][2] = {};
    #pragma unroll
    for (int ks = 0; ks < 2; ++ks)
        #pragma unroll
        for (int nt = 0; nt < 2; ++nt) {
            const int d = w * 32 + nt * 16 + m;
            alignas(16) unsigned short tmp[8];
            #pragma unroll
            for (int jj = 0; jj < 8; ++jj)
                tmp[jj] = *reinterpret_cast<const unsigned short*>(
                    &Vsh[(ks * 32 + quad * 8 + jj) * 136 + d]);
            bf16x8 bfrag = *reinterpret_cast<bf16x8*>(tmp);
            #pragma unroll
            for (int mt = 0; mt < 4; ++mt) {
                uacc[mt][nt] = __builtin_amdgcn_mfma_f32_16x16x32_bf16(
                    fM[mt][ks], bfrag, uacc[mt][nt], 0, 0, 0);
                yacc[mt][nt] = __builtin_amdgcn_mfma_f32_16x16x32_bf16(
                    fA[mt][ks], bfrag, yacc[mt][nt], 0, 0, 0);
            }
        }

    #pragma unroll
    for (int mt = 0; mt < 4; ++mt)
        #pragma unroll
        for (int nt = 0; nt < 2; ++nt) {
            const int dcol = d0 + w * 32 + nt * 16 + m;
            #pragma unroll
            for (int r = 0; r < 4; ++r) {
                const int t = mt * 16 + quad * 4 + r;
                const size_t off = (rowbase + t) * DD + dcol;
                U16[off] = __float2bfloat16(uacc[mt][nt][r]);
                out[off] = x[off] + yacc[mt][nt][r];
            }
        }
}

// ---------------------------------------------------------------------------
// Kernel 5: sequential cross-chunk pass, MFMA. 256 blocks. Per chunk:
//   P = B_c Z - U;  out += Qt_c Z;  Z += (-K^T) P.
// ---------------------------------------------------------------------------
__global__ __launch_bounds__(256) void seq_kernel(
    const bf16* __restrict__ Bb16, const bf16* __restrict__ Qtb16,
    const bf16* __restrict__ Ktb16, const bf16* __restrict__ U16,
    float* __restrict__ out)
{
    __shared__ bf16 Zsh[16][72];
    __shared__ bf16 Psh[16][72];
    const int dblk = blockIdx.x, b = blockIdx.y;
    const int tid = threadIdx.x, lane = tid & 63, w = tid >> 6;
    const int m = lane & 15, quad = lane >> 4;
    const int d0 = dblk * 16;
    const int arow = w * 16 + m;          // A-frag row (all 3 matmuls)
    const int trow = w * 16 + quad * 4;   // first C/D row for this thread

    f32x4 zacc = {0.f, 0.f, 0.f, 0.f};
    for (int i = tid; i < 16 * 72; i += 256)
        (&Zsh[0][0])[i] = __float2bfloat16(0.f);

    for (int c = 0; c < NC; ++c) {
        const size_t cb = ((size_t)b * NC + c) * 4096;
        const size_t gbase = ((size_t)b * SS + (size_t)c * 64 + trow) * DD + d0 + m;
        const bf16x8 aB0 = *reinterpret_cast<const bf16x8*>(Bb16 + cb + arow * 64 + quad * 8);
        const bf16x8 aB1 = *reinterpret_cast<const bf16x8*>(Bb16 + cb + arow * 64 + 32 + quad * 8);
        const bf16x8 aQ0 = *reinterpret_cast<const bf16x8*>(Qtb16 + cb + arow * 64 + quad * 8);
        const bf16x8 aQ1 = *reinterpret_cast<const bf16x8*>(Qtb16 + cb + arow * 64 + 32 + quad * 8);
        const bf16x8 aK0 = *reinterpret_cast<const bf16x8*>(Ktb16 + cb + arow * 64 + quad * 8);
        const bf16x8 aK1 = *reinterpret_cast<const bf16x8*>(Ktb16 + cb + arow * 64 + 32 + quad * 8);
        float uld[4], old[4];
        #pragma unroll
        for (int r = 0; r < 4; ++r) {
            uld[r] = __bfloat162float(U16[gbase + (size_t)r * DD]);
            old[r] = out[gbase + (size_t)r * DD];
        }

        __syncthreads();                  // A: Zsh ready, Psh free
        const bf16x8 z0 = *reinterpret_cast<const bf16x8*>(&Zsh[m][quad * 8]);
        const bf16x8 z1 = *reinterpret_cast<const bf16x8*>(&Zsh[m][32 + quad * 8]);
        f32x4 pacc = {0.f, 0.f, 0.f, 0.f};
        f32x4 yacc = {0.f, 0.f, 0.f, 0.f};
        pacc = __builtin_amdgcn_mfma_f32_16x16x32_bf16(aB0, z0, pacc, 0, 0, 0);
        pacc = __builtin_amdgcn_mfma_f32_16x16x32_bf16(aB1, z1, pacc, 0, 0, 0);
        yacc = __builtin_amdgcn_mfma_f32_16x16x32_bf16(aQ0, z0, yacc, 0, 0, 0);
        yacc = __builtin_amdgcn_mfma_f32_16x16x32_bf16(aQ1, z1, yacc, 0, 0, 0);

        alignas(8) bf16 pb[4];
        #pragma unroll
        for (int r = 0; r < 4; ++r) {
            out[gbase + (size_t)r * DD] = old[r] + yacc[r];
            pb[r] = __float2bfloat16(pacc[r] - uld[r]);
        }
        *reinterpret_cast<uint2*>(&Psh[m][trow]) = *reinterpret_cast<uint2*>(pb);

        __syncthreads();                  // B: Psh ready, Zsh reads done
        const bf16x8 p0 = *reinterpret_cast<const bf16x8*>(&Psh[m][quad * 8]);
        const bf16x8 p1 = *reinterpret_cast<const bf16x8*>(&Psh[m][32 + quad * 8]);
        zacc = __builtin_amdgcn_mfma_f32_16x16x32_bf16(aK0, p0, zacc, 0, 0, 0);
        zacc = __builtin_amdgcn_mfma_f32_16x16x32_bf16(aK1, p1, zacc, 0, 0, 0);

        alignas(8) bf16 zb[4];
        #pragma unroll
        for (int r = 0; r < 4; ++r) zb[r] = __float2bfloat16(zacc[r]);
        *reinterpret_cast<uint2*>(&Zsh[m][trow]) = *reinterpret_cast<uint2*>(zb);
    }
}

// ---------------------------------------------------------------------------
extern "C" void kernel_launch(void* const* d_in, const int* in_sizes, int n_in,
                              void* d_out, int out_size, void* d_ws, size_t ws_size,
                              hipStream_t stream)
{
    const float* x     = (const float*)d_in[0];
    const float* Wk    = (const float*)d_in[1];
    const float* bk    = (const float*)d_in[2];
    const float* Wv    = (const float*)d_in[3];
    const float* bv    = (const float*)d_in[4];
    const float* Wq    = (const float*)d_in[5];
    const float* bq    = (const float*)d_in[6];
    const float* gamma = (const float*)d_in[7];
    const float* beta  = (const float*)d_in[8];

    char* ws = (char*)d_ws;
    // layout (54.25 MiB total, same footprint as round 5):
    //   [0,16 MiB): hb (bf16, ln->kqv) -- dead after kqv; reused by prep as:
    //     Bb16@0, Qtb16@1MiB, Ktb16@2MiB, Mb16@3MiB, AMb16@4MiB (1 MiB each)
    //   [16 MiB, +2.25): Wcat (bf16 1152x1024)
    //   +2 MiB: kbuf (fp32)   +2 MiB: qbuf (fp32)
    //   +16 MiB: vbuf16 (bf16 8192x1024)
    //   +16 MiB: U16 (bf16 8192x1024)
    const size_t WCAT_B = (size_t)NCAT * DD * 2;   // 2.25 MiB
    bf16*  hb    = (bf16*)ws;
    bf16*  Bb16  = (bf16*)(ws + 0 * MiB);
    bf16*  Qtb16 = (bf16*)(ws + 1 * MiB);
    bf16*  Ktb16 = (bf16*)(ws + 2 * MiB);
    bf16*  Mb16  = (bf16*)(ws + 3 * MiB);
    bf16*  AMb16 = (bf16*)(ws + 4 * MiB);
    bf16*  Wcat  = (bf16*)(ws + 16 * MiB);
    float* kbuf  = (float*)(ws + 16 * MiB + WCAT_B);
    float* qbuf  = (float*)(ws + 18 * MiB + WCAT_B);
    bf16*  v16   = (bf16*)(ws + 20 * MiB + WCAT_B);
    bf16*  U16   = (bf16*)(ws + 36 * MiB + WCAT_B);

    cvt_cat_kernel<<<(NCAT * DD / 4 + 255) / 256, 256, 0, stream>>>(Wk, Wq, Wv, Wcat);
    ln_kernel<<<BB * SS, 256, 0, stream>>>(x, gamma, beta, hb);
    kqv_kernel<<<dim3(NCAT / 128, BB * SS / 128), 256, 0, stream>>>(
        hb, Wcat, bk, bq, bv, kbuf, qbuf, v16);
    prep_kernel<<<dim3(NC, BB), 256, 0, stream>>>(
        kbuf, qbuf, Mb16, AMb16, Bb16, Qtb16, Ktb16);
    usolve_kernel<<<dim3(DD / 128, NC, BB), 256, 0, stream>>>(
        Mb16, AMb16, v16, x, U16, (float*)d_out);
    seq_kernel<<<dim3(DD / 16, BB), 256, 0, stream>>>(
        Bb16, Qtb16, Ktb16, U16, (float*)d_out);
}

// Round 7
// 235.752 us; speedup vs baseline: 21.0279x; 1.2191x over previous
//
#include <hip/hip_runtime.h>
#include <hip/hip_bf16.h>

#define TTT_LR 0.01f
#define LN_EPS 1e-5f

// Problem dims (fixed by reference)
#define BB 4
#define SS 2048
#define DD 1024
#define DSZ 64
#define CHUNK 64
#define NC (SS / CHUNK)   // 32
#define NCAT 1152         // 64 k + 64 q + 1024 v output cols
#define MiB (1024ull * 1024ull)

typedef __hip_bfloat16 bf16;
typedef __bf16 bf16x8 __attribute__((ext_vector_type(8)));
typedef float f32x4 __attribute__((ext_vector_type(4)));

__device__ __forceinline__ void gload_lds16(const void* g, void* l) {
    __builtin_amdgcn_global_load_lds(
        (const __attribute__((address_space(1))) unsigned int*)g,
        (__attribute__((address_space(3))) unsigned int*)l, 16, 0, 0);
}

// ---------------------------------------------------------------------------
// Kernel 0: concat Wk/Wq/Wv -> bf16 Wcat (1152 x 1024, row-major).
// ---------------------------------------------------------------------------
__global__ __launch_bounds__(256) void cvt_cat_kernel(
    const float* __restrict__ Wk, const float* __restrict__ Wq,
    const float* __restrict__ Wv, bf16* __restrict__ Wcat)
{
    const int i = blockIdx.x * 256 + threadIdx.x;       // float4 group index
    if (i >= NCAT * DD / 4) return;
    const int idx = i * 4;
    const int row = idx >> 10, col = idx & 1023;
    const float* src = (row < 64)  ? (Wk + (size_t)row * DD)
                     : (row < 128) ? (Wq + (size_t)(row - 64) * DD)
                                   : (Wv + (size_t)(row - 128) * DD);
    float4 v = *reinterpret_cast<const float4*>(src + col);
    bf16 h4[4] = {__float2bfloat16(v.x), __float2bfloat16(v.y),
                  __float2bfloat16(v.z), __float2bfloat16(v.w)};
    *reinterpret_cast<ushort4*>(Wcat + idx) = *reinterpret_cast<ushort4*>(h4);
}

// ---------------------------------------------------------------------------
// Kernel 1: LayerNorm only -> h (bf16). One block (256 thr) per (b,s) row.
// ---------------------------------------------------------------------------
__global__ __launch_bounds__(256) void ln_kernel(
    const float* __restrict__ x, const float* __restrict__ gamma,
    const float* __restrict__ beta, bf16* __restrict__ hb)
{
    __shared__ float wsum[4], wsum2[4];
    const int row = blockIdx.x, tid = threadIdx.x;
    const int lane = tid & 63, wave = tid >> 6;

    float4 v0 = *reinterpret_cast<const float4*>(x + (size_t)row * DD + tid * 4);
    float s = v0.x + v0.y + v0.z + v0.w;
    float s2 = fmaf(v0.x, v0.x, fmaf(v0.y, v0.y, fmaf(v0.z, v0.z, v0.w * v0.w)));
    #pragma unroll
    for (int off = 32; off > 0; off >>= 1) {
        s  += __shfl_down(s, off, 64);
        s2 += __shfl_down(s2, off, 64);
    }
    if (lane == 0) { wsum[wave] = s; wsum2[wave] = s2; }
    __syncthreads();
    s  = wsum[0] + wsum[1] + wsum[2] + wsum[3];
    s2 = wsum2[0] + wsum2[1] + wsum2[2] + wsum2[3];
    const float mu = s * (1.0f / DD);
    const float rs = rsqrtf(s2 * (1.0f / DD) - mu * mu + LN_EPS);

    float4 g  = *reinterpret_cast<const float4*>(gamma + tid * 4);
    float4 be = *reinterpret_cast<const float4*>(beta + tid * 4);
    bf16 h4[4];
    h4[0] = __float2bfloat16((v0.x - mu) * rs * g.x + be.x);
    h4[1] = __float2bfloat16((v0.y - mu) * rs * g.y + be.y);
    h4[2] = __float2bfloat16((v0.z - mu) * rs * g.z + be.z);
    h4[3] = __float2bfloat16((v0.w - mu) * rs * g.w + be.w);
    *reinterpret_cast<ushort4*>(hb + (size_t)row * DD + tid * 4) =
        *reinterpret_cast<ushort4*>(h4);
}

// ---------------------------------------------------------------------------
// Kernel 2: fused kqv = h @ Wcat^T + bias. 128x128 tile, BK=64,
// global_load_lds(16B) staging, XOR-swizzled 16B blocks. k/q stored fp32;
// v stored bf16 (vbuf16) for the MFMA usolve.
// ---------------------------------------------------------------------------
__global__ __launch_bounds__(256) void kqv_kernel(
    const bf16* __restrict__ h, const bf16* __restrict__ Wcat,
    const float* __restrict__ bk, const float* __restrict__ bq,
    const float* __restrict__ bv,
    float* __restrict__ kbuf, float* __restrict__ qbuf, bf16* __restrict__ vbuf16)
{
    __shared__ bf16 Ash[128 * 64];
    __shared__ bf16 Bsh[128 * 64];
    const int tid = threadIdx.x, lane = tid & 63, wave = tid >> 6;
    const int m = lane & 15, quad = lane >> 4;
    const int wr = wave >> 1, wc = wave & 1;
    const int m0 = blockIdx.y * 128;     // h rows
    const int n0 = blockIdx.x * 128;     // Wcat rows

    const int srow = wave * 8 + (lane >> 3);   // staging row (+ i*32)
    const int scb = lane & 7;                  // staging 16B-block in row

    f32x4 acc[4][4] = {};

    for (int k0 = 0; k0 < DD; k0 += 64) {
        __syncthreads();                       // prior frag reads done
        #pragma unroll
        for (int i = 0; i < 4; ++i) {
            const int row = i * 32 + srow;
            const int g16 = scb ^ (row & 7);   // swizzled source block
            gload_lds16(h    + (size_t)(m0 + row) * DD + k0 + g16 * 8,
                        (char*)Ash + (size_t)(i * 32 + wave * 8) * 128);
            gload_lds16(Wcat + (size_t)(n0 + row) * DD + k0 + g16 * 8,
                        (char*)Bsh + (size_t)(i * 32 + wave * 8) * 128);
        }
        __syncthreads();                       // DMA drained (vmcnt0 @ barrier)
        #pragma unroll
        for (int ks = 0; ks < 2; ++ks) {
            bf16x8 af[4], bfr[4];
            #pragma unroll
            for (int mt = 0; mt < 4; ++mt) {
                const int row = wr * 64 + mt * 16 + m;
                const int kb = (ks * 4 + quad) ^ (row & 7);
                af[mt] = *reinterpret_cast<const bf16x8*>(&Ash[row * 64 + kb * 8]);
            }
            #pragma unroll
            for (int nt = 0; nt < 4; ++nt) {
                const int row = wc * 64 + nt * 16 + m;
                const int kb = (ks * 4 + quad) ^ (row & 7);
                bfr[nt] = *reinterpret_cast<const bf16x8*>(&Bsh[row * 64 + kb * 8]);
            }
            #pragma unroll
            for (int mt = 0; mt < 4; ++mt)
                #pragma unroll
                for (int nt = 0; nt < 4; ++nt)
                    acc[mt][nt] = __builtin_amdgcn_mfma_f32_16x16x32_bf16(
                        af[mt], bfr[nt], acc[mt][nt], 0, 0, 0);
        }
    }

    #pragma unroll
    for (int nt = 0; nt < 4; ++nt) {
        const int n = n0 + wc * 64 + nt * 16 + m;
        if (n < 64) {
            const float bias = bk[n];
            #pragma unroll
            for (int mt = 0; mt < 4; ++mt) {
                const int row = m0 + wr * 64 + mt * 16 + quad * 4;
                #pragma unroll
                for (int r = 0; r < 4; ++r)
                    kbuf[(size_t)(row + r) * DSZ + n] = acc[mt][nt][r] + bias;
            }
        } else if (n < 128) {
            const float bias = bq[n - 64];
            #pragma unroll
            for (int mt = 0; mt < 4; ++mt) {
                const int row = m0 + wr * 64 + mt * 16 + quad * 4;
                #pragma unroll
                for (int r = 0; r < 4; ++r)
                    qbuf[(size_t)(row + r) * DSZ + (n - 64)] = acc[mt][nt][r] + bias;
            }
        } else {
            const float bias = bv[n - 128];
            #pragma unroll
            for (int mt = 0; mt < 4; ++mt) {
                const int row = m0 + wr * 64 + mt * 16 + quad * 4;
                #pragma unroll
                for (int r = 0; r < 4; ++r)
                    vbuf16[(size_t)(row + r) * DD + (n - 128)] =
                        __float2bfloat16(acc[mt][nt][r] + bias);
            }
        }
    }
}

// ---------------------------------------------------------------------------
// Kernel 3: per-(b,chunk) prep — MFMA version. All 64x64x64 products on the
// matrix pipe; only the L^-1 forward-substitution (serial by nature) stays
// on VALU (wave 0, fp32). Semantics identical to round-6 prep:
//   G = K K^T (kept as lr*G fp32 for the solve), A = Q K^T (strict-lower bf16)
//   Minv = (I + lr*trilS(G))^-1            [serial solve, fp32]
//   Mb16  = lr*Minv          B = (lr*Minv)*K = Bb16
//   AMb16 = Astl*(lr*Minv)   Qt = Q - Astl*B  (C-init with Q)
//   Ktb16 = -K^T
// mfma idiom: result = X * Y^T with A-frag = X rows, B-frag = Y rows.
// ---------------------------------------------------------------------------
__global__ __launch_bounds__(256) void prep_kernel(
    const float* __restrict__ kbuf, const float* __restrict__ qbuf,
    bf16* __restrict__ Mb16, bf16* __restrict__ AMb16,
    bf16* __restrict__ Bb16, bf16* __restrict__ Qtb16, bf16* __restrict__ Ktb16)
{
    __shared__ bf16 K16[64 * 72];      // K  [t][s]
    __shared__ bf16 Kt16[64 * 72];     // K^T [s][t]
    __shared__ bf16 Q16[64 * 72];      // Q  [t][s]
    __shared__ bf16 Astl[64 * 72];     // strict-lower A, zeros elsewhere
    __shared__ bf16 Minv16[64 * 72];   // lr*Minv [t][j]
    __shared__ bf16 MinvT16[64 * 72];  // (lr*Minv)^T [j][t]
    __shared__ bf16 BnegT[64 * 72];    // -B^T [s][t]
    __shared__ float Gf[64 * 65];      // lr*G (fp32, solve input)
    __shared__ float Mf[64 * 65];      // Minv (fp32, solve output)

    const int c = blockIdx.x, b = blockIdx.y;
    const int tid = threadIdx.x, lane = tid & 63, w = tid >> 6;
    const int m = lane & 15, quad = lane >> 4;
    const float* kp = kbuf + ((size_t)b * SS + c * 64) * DSZ;
    const float* qp = qbuf + ((size_t)b * SS + c * 64) * DSZ;
    const size_t cb = ((size_t)b * NC + c) * 4096;

    // ---- stage K (row + transposed) and Q as bf16
    #pragma unroll
    for (int it = 0; it < 4; ++it) {
        const int f4 = tid + it * 256;          // float4 index 0..1023
        const int t = f4 >> 4;
        const int s = (f4 & 15) * 4;
        float4 kv = *reinterpret_cast<const float4*>(kp + t * DSZ + s);
        float4 qv = *reinterpret_cast<const float4*>(qp + t * DSZ + s);
        bf16 kb4[4] = {__float2bfloat16(kv.x), __float2bfloat16(kv.y),
                       __float2bfloat16(kv.z), __float2bfloat16(kv.w)};
        bf16 qb4[4] = {__float2bfloat16(qv.x), __float2bfloat16(qv.y),
                       __float2bfloat16(qv.z), __float2bfloat16(qv.w)};
        *reinterpret_cast<ushort4*>(&K16[t * 72 + s]) = *reinterpret_cast<ushort4*>(kb4);
        *reinterpret_cast<ushort4*>(&Q16[t * 72 + s]) = *reinterpret_cast<ushort4*>(qb4);
        #pragma unroll
        for (int i = 0; i < 4; ++i) Kt16[(s + i) * 72 + t] = kb4[i];
    }
    __syncthreads();

    // ---- G = K K^T (store lr*G fp32), A = Q K^T (store strict-lower bf16)
    bf16x8 afK[2], afQ[2], bfK[4][2];
    #pragma unroll
    for (int ks = 0; ks < 2; ++ks) {
        afK[ks] = *reinterpret_cast<const bf16x8*>(&K16[(w * 16 + m) * 72 + ks * 32 + quad * 8]);
        afQ[ks] = *reinterpret_cast<const bf16x8*>(&Q16[(w * 16 + m) * 72 + ks * 32 + quad * 8]);
        #pragma unroll
        for (int nt = 0; nt < 4; ++nt)
            bfK[nt][ks] = *reinterpret_cast<const bf16x8*>(&K16[(nt * 16 + m) * 72 + ks * 32 + quad * 8]);
    }
    f32x4 gacc[4] = {}, aacc[4] = {};
    #pragma unroll
    for (int ks = 0; ks < 2; ++ks)
        #pragma unroll
        for (int nt = 0; nt < 4; ++nt) {
            gacc[nt] = __builtin_amdgcn_mfma_f32_16x16x32_bf16(afK[ks], bfK[nt][ks], gacc[nt], 0, 0, 0);
            aacc[nt] = __builtin_amdgcn_mfma_f32_16x16x32_bf16(afQ[ks], bfK[nt][ks], aacc[nt], 0, 0, 0);
        }
    #pragma unroll
    for (int nt = 0; nt < 4; ++nt)
        #pragma unroll
        for (int r = 0; r < 4; ++r) {
            const int t = w * 16 + quad * 4 + r, j = nt * 16 + m;
            Gf[t * 65 + j] = TTT_LR * gacc[nt][r];
            Astl[t * 72 + j] = __float2bfloat16(j < t ? aacc[nt][r] : 0.f);
        }
    __syncthreads();

    // ---- serial forward-substitution: Minv = (I + lr*trilS(G))^-1 (fp32)
    if (tid < 64) {
        for (int t = 0; t < 64; ++t) {
            float acc = (t == tid) ? 1.f : 0.f;
            for (int i = 0; i < t; ++i)
                acc = fmaf(-Gf[t * 65 + i], Mf[i * 65 + tid], acc);
            Mf[t * 65 + tid] = acc;
        }
    }
    __syncthreads();

    // ---- lr*Minv -> bf16 (row + transposed); write Mb16 and Ktb16 = -K^T
    #pragma unroll
    for (int it = 0; it < 16; ++it) {
        const int e = tid + it * 256;           // 0..4095
        const int t = e >> 6, j = e & 63;
        const bf16 vb = __float2bfloat16(TTT_LR * Mf[t * 65 + j]);
        Minv16[t * 72 + j] = vb;
        MinvT16[j * 72 + t] = vb;
        Mb16[cb + e] = vb;
        // Ktb16[cb + s*64 + t'] = -K[t'][s]; e == s*64 + t'
        const unsigned short ku =
            *reinterpret_cast<const unsigned short*>(&Kt16[t * 72 + j]) ^ 0x8000u;
        *reinterpret_cast<unsigned short*>(&Ktb16[cb + e]) = ku;
    }
    __syncthreads();

    // ---- B = (lr*Minv) * K  via mfma(Minv16 rows, Kt16 rows)
    bf16x8 afM[2], afA[2], bfKt[4][2], bfMt[4][2];
    #pragma unroll
    for (int ks = 0; ks < 2; ++ks) {
        afM[ks] = *reinterpret_cast<const bf16x8*>(&Minv16[(w * 16 + m) * 72 + ks * 32 + quad * 8]);
        afA[ks] = *reinterpret_cast<const bf16x8*>(&Astl[(w * 16 + m) * 72 + ks * 32 + quad * 8]);
        #pragma unroll
        for (int nt = 0; nt < 4; ++nt) {
            bfKt[nt][ks] = *reinterpret_cast<const bf16x8*>(&Kt16[(nt * 16 + m) * 72 + ks * 32 + quad * 8]);
            bfMt[nt][ks] = *reinterpret_cast<const bf16x8*>(&MinvT16[(nt * 16 + m) * 72 + ks * 32 + quad * 8]);
        }
    }
    f32x4 bacc[4] = {};
    #pragma unroll
    for (int ks = 0; ks < 2; ++ks)
        #pragma unroll
        for (int nt = 0; nt < 4; ++nt)
            bacc[nt] = __builtin_amdgcn_mfma_f32_16x16x32_bf16(afM[ks], bfKt[nt][ks], bacc[nt], 0, 0, 0);
    #pragma unroll
    for (int nt = 0; nt < 4; ++nt)
        #pragma unroll
        for (int r = 0; r < 4; ++r) {
            const int t = w * 16 + quad * 4 + r, s = nt * 16 + m;
            Bb16[cb + t * 64 + s] = __float2bfloat16(bacc[nt][r]);
            BnegT[s * 72 + t] = __float2bfloat16(-bacc[nt][r]);
        }
    __syncthreads();

    // ---- Qt = Q - Astl*B (C-init = Q), AM = Astl*(lr*Minv)
    f32x4 qtacc[4], amacc[4] = {};
    #pragma unroll
    for (int nt = 0; nt < 4; ++nt)
        #pragma unroll
        for (int r = 0; r < 4; ++r)
            qtacc[nt][r] = qp[(w * 16 + quad * 4 + r) * DSZ + nt * 16 + m];
    #pragma unroll
    for (int ks = 0; ks < 2; ++ks)
        #pragma unroll
        for (int nt = 0; nt < 4; ++nt) {
            const bf16x8 bfBn = *reinterpret_cast<const bf16x8*>(
                &BnegT[(nt * 16 + m) * 72 + ks * 32 + quad * 8]);
            qtacc[nt] = __builtin_amdgcn_mfma_f32_16x16x32_bf16(afA[ks], bfBn, qtacc[nt], 0, 0, 0);
            amacc[nt] = __builtin_amdgcn_mfma_f32_16x16x32_bf16(afA[ks], bfMt[nt][ks], amacc[nt], 0, 0, 0);
        }
    #pragma unroll
    for (int nt = 0; nt < 4; ++nt)
        #pragma unroll
        for (int r = 0; r < 4; ++r) {
            const int t = w * 16 + quad * 4 + r, s = nt * 16 + m;
            Qtb16[cb + t * 64 + s] = __float2bfloat16(qtacc[nt][r]);
            AMb16[cb + t * 64 + s] = __float2bfloat16(amacc[nt][r]);
        }
}

// ---------------------------------------------------------------------------
// Kernel 4: usolve via MFMA. Per (b,c,dblk=128 cols):
//   U = Mb16 @ V ; out = x + AMb16 @ V.
// ---------------------------------------------------------------------------
__global__ __launch_bounds__(256) void usolve_kernel(
    const bf16* __restrict__ Mb16, const bf16* __restrict__ AMb16,
    const bf16* __restrict__ v16, const float* __restrict__ x,
    bf16* __restrict__ U16, float* __restrict__ out)
{
    __shared__ bf16 Vsh[64 * 136];
    const int tid = threadIdx.x, lane = tid & 63, w = tid >> 6;
    const int m = lane & 15, quad = lane >> 4;
    const int dblk = blockIdx.x, c = blockIdx.y, b = blockIdx.z;
    const int d0 = dblk * 128;
    const size_t cb = ((size_t)b * NC + c) * 4096;
    const size_t rowbase = (size_t)b * SS + (size_t)c * 64;

    #pragma unroll
    for (int it = 0; it < 4; ++it) {
        const int j = (tid >> 4) + it * 16;
        const int dd = (tid & 15) * 8;
        bf16x8 vv = *reinterpret_cast<const bf16x8*>(
            v16 + (rowbase + j) * DD + d0 + dd);
        *reinterpret_cast<bf16x8*>(&Vsh[j * 136 + dd]) = vv;
    }

    bf16x8 fM[4][2], fA[4][2];
    #pragma unroll
    for (int mt = 0; mt < 4; ++mt)
        #pragma unroll
        for (int ks = 0; ks < 2; ++ks) {
            const int off = (mt * 16 + m) * 64 + ks * 32 + quad * 8;
            fM[mt][ks] = *reinterpret_cast<const bf16x8*>(Mb16 + cb + off);
            fA[mt][ks] = *reinterpret_cast<const bf16x8*>(AMb16 + cb + off);
        }
    __syncthreads();

    f32x4 uacc[4][2] = {}, yacc[4][2] = {};
    #pragma unroll
    for (int ks = 0; ks < 2; ++ks)
        #pragma unroll
        for (int nt = 0; nt < 2; ++nt) {
            const int d = w * 32 + nt * 16 + m;
            alignas(16) unsigned short tmp[8];
            #pragma unroll
            for (int jj = 0; jj < 8; ++jj)
                tmp[jj] = *reinterpret_cast<const unsigned short*>(
                    &Vsh[(ks * 32 + quad * 8 + jj) * 136 + d]);
            bf16x8 bfrag = *reinterpret_cast<bf16x8*>(tmp);
            #pragma unroll
            for (int mt = 0; mt < 4; ++mt) {
                uacc[mt][nt] = __builtin_amdgcn_mfma_f32_16x16x32_bf16(
                    fM[mt][ks], bfrag, uacc[mt][nt], 0, 0, 0);
                yacc[mt][nt] = __builtin_amdgcn_mfma_f32_16x16x32_bf16(
                    fA[mt][ks], bfrag, yacc[mt][nt], 0, 0, 0);
            }
        }

    #pragma unroll
    for (int mt = 0; mt < 4; ++mt)
        #pragma unroll
        for (int nt = 0; nt < 2; ++nt) {
            const int dcol = d0 + w * 32 + nt * 16 + m;
            #pragma unroll
            for (int r = 0; r < 4; ++r) {
                const int t = mt * 16 + quad * 4 + r;
                const size_t off = (rowbase + t) * DD + dcol;
                U16[off] = __float2bfloat16(uacc[mt][nt][r]);
                out[off] = x[off] + yacc[mt][nt][r];
            }
        }
}

// ---------------------------------------------------------------------------
// Kernel 5: sequential cross-chunk pass, MFMA. 256 blocks. Per chunk:
//   P = B_c Z - U;  out += Qt_c Z;  Z += (-K^T) P.
// ---------------------------------------------------------------------------
__global__ __launch_bounds__(256) void seq_kernel(
    const bf16* __restrict__ Bb16, const bf16* __restrict__ Qtb16,
    const bf16* __restrict__ Ktb16, const bf16* __restrict__ U16,
    float* __restrict__ out)
{
    __shared__ bf16 Zsh[16][72];
    __shared__ bf16 Psh[16][72];
    const int dblk = blockIdx.x, b = blockIdx.y;
    const int tid = threadIdx.x, lane = tid & 63, w = tid >> 6;
    const int m = lane & 15, quad = lane >> 4;
    const int d0 = dblk * 16;
    const int arow = w * 16 + m;          // A-frag row (all 3 matmuls)
    const int trow = w * 16 + quad * 4;   // first C/D row for this thread

    f32x4 zacc = {0.f, 0.f, 0.f, 0.f};
    for (int i = tid; i < 16 * 72; i += 256)
        (&Zsh[0][0])[i] = __float2bfloat16(0.f);

    for (int c = 0; c < NC; ++c) {
        const size_t cb = ((size_t)b * NC + c) * 4096;
        const size_t gbase = ((size_t)b * SS + (size_t)c * 64 + trow) * DD + d0 + m;
        const bf16x8 aB0 = *reinterpret_cast<const bf16x8*>(Bb16 + cb + arow * 64 + quad * 8);
        const bf16x8 aB1 = *reinterpret_cast<const bf16x8*>(Bb16 + cb + arow * 64 + 32 + quad * 8);
        const bf16x8 aQ0 = *reinterpret_cast<const bf16x8*>(Qtb16 + cb + arow * 64 + quad * 8);
        const bf16x8 aQ1 = *reinterpret_cast<const bf16x8*>(Qtb16 + cb + arow * 64 + 32 + quad * 8);
        const bf16x8 aK0 = *reinterpret_cast<const bf16x8*>(Ktb16 + cb + arow * 64 + quad * 8);
        const bf16x8 aK1 = *reinterpret_cast<const bf16x8*>(Ktb16 + cb + arow * 64 + 32 + quad * 8);
        float uld[4], old[4];
        #pragma unroll
        for (int r = 0; r < 4; ++r) {
            uld[r] = __bfloat162float(U16[gbase + (size_t)r * DD]);
            old[r] = out[gbase + (size_t)r * DD];
        }

        __syncthreads();                  // A: Zsh ready, Psh free
        const bf16x8 z0 = *reinterpret_cast<const bf16x8*>(&Zsh[m][quad * 8]);
        const bf16x8 z1 = *reinterpret_cast<const bf16x8*>(&Zsh[m][32 + quad * 8]);
        f32x4 pacc = {0.f, 0.f, 0.f, 0.f};
        f32x4 yacc = {0.f, 0.f, 0.f, 0.f};
        pacc = __builtin_amdgcn_mfma_f32_16x16x32_bf16(aB0, z0, pacc, 0, 0, 0);
        pacc = __builtin_amdgcn_mfma_f32_16x16x32_bf16(aB1, z1, pacc, 0, 0, 0);
        yacc = __builtin_amdgcn_mfma_f32_16x16x32_bf16(aQ0, z0, yacc, 0, 0, 0);
        yacc = __builtin_amdgcn_mfma_f32_16x16x32_bf16(aQ1, z1, yacc, 0, 0, 0);

        alignas(8) bf16 pb[4];
        #pragma unroll
        for (int r = 0; r < 4; ++r) {
            out[gbase + (size_t)r * DD] = old[r] + yacc[r];
            pb[r] = __float2bfloat16(pacc[r] - uld[r]);
        }
        *reinterpret_cast<uint2*>(&Psh[m][trow]) = *reinterpret_cast<uint2*>(pb);

        __syncthreads();                  // B: Psh ready, Zsh reads done
        const bf16x8 p0 = *reinterpret_cast<const bf16x8*>(&Psh[m][quad * 8]);
        const bf16x8 p1 = *reinterpret_cast<const bf16x8*>(&Psh[m][32 + quad * 8]);
        zacc = __builtin_amdgcn_mfma_f32_16x16x32_bf16(aK0, p0, zacc, 0, 0, 0);
        zacc = __builtin_amdgcn_mfma_f32_16x16x32_bf16(aK1, p1, zacc, 0, 0, 0);

        alignas(8) bf16 zb[4];
        #pragma unroll
        for (int r = 0; r < 4; ++r) zb[r] = __float2bfloat16(zacc[r]);
        *reinterpret_cast<uint2*>(&Zsh[m][trow]) = *reinterpret_cast<uint2*>(zb);
    }
}

// ---------------------------------------------------------------------------
extern "C" void kernel_launch(void* const* d_in, const int* in_sizes, int n_in,
                              void* d_out, int out_size, void* d_ws, size_t ws_size,
                              hipStream_t stream)
{
    const float* x     = (const float*)d_in[0];
    const float* Wk    = (const float*)d_in[1];
    const float* bk    = (const float*)d_in[2];
    const float* Wv    = (const float*)d_in[3];
    const float* bv    = (const float*)d_in[4];
    const float* Wq    = (const float*)d_in[5];
    const float* bq    = (const float*)d_in[6];
    const float* gamma = (const float*)d_in[7];
    const float* beta  = (const float*)d_in[8];

    char* ws = (char*)d_ws;
    // layout (54.25 MiB total):
    //   [0,16 MiB): hb (bf16, ln->kqv) -- dead after kqv; reused by prep as:
    //     Bb16@0, Qtb16@1MiB, Ktb16@2MiB, Mb16@3MiB, AMb16@4MiB (1 MiB each)
    //   [16 MiB, +2.25): Wcat (bf16 1152x1024)
    //   +2 MiB: kbuf (fp32)   +2 MiB: qbuf (fp32)
    //   +16 MiB: vbuf16 (bf16 8192x1024)
    //   +16 MiB: U16 (bf16 8192x1024)
    const size_t WCAT_B = (size_t)NCAT * DD * 2;   // 2.25 MiB
    bf16*  hb    = (bf16*)ws;
    bf16*  Bb16  = (bf16*)(ws + 0 * MiB);
    bf16*  Qtb16 = (bf16*)(ws + 1 * MiB);
    bf16*  Ktb16 = (bf16*)(ws + 2 * MiB);
    bf16*  Mb16  = (bf16*)(ws + 3 * MiB);
    bf16*  AMb16 = (bf16*)(ws + 4 * MiB);
    bf16*  Wcat  = (bf16*)(ws + 16 * MiB);
    float* kbuf  = (float*)(ws + 16 * MiB + WCAT_B);
    float* qbuf  = (float*)(ws + 18 * MiB + WCAT_B);
    bf16*  v16   = (bf16*)(ws + 20 * MiB + WCAT_B);
    bf16*  U16   = (bf16*)(ws + 36 * MiB + WCAT_B);

    cvt_cat_kernel<<<(NCAT * DD / 4 + 255) / 256, 256, 0, stream>>>(Wk, Wq, Wv, Wcat);
    ln_kernel<<<BB * SS, 256, 0, stream>>>(x, gamma, beta, hb);
    kqv_kernel<<<dim3(NCAT / 128, BB * SS / 128), 256, 0, stream>>>(
        hb, Wcat, bk, bq, bv, kbuf, qbuf, v16);
    prep_kernel<<<dim3(NC, BB), 256, 0, stream>>>(
        kbuf, qbuf, Mb16, AMb16, Bb16, Qtb16, Ktb16);
    usolve_kernel<<<dim3(DD / 128, NC, BB), 256, 0, stream>>>(
        Mb16, AMb16, v16, x, U16, (float*)d_out);
    seq_kernel<<<dim3(DD / 16, BB), 256, 0, stream>>>(
        Bb16, Qtb16, Ktb16, U16, (float*)d_out);
}

// Round 8
// 233.401 us; speedup vs baseline: 21.2396x; 1.0101x over previous
//
#include <hip/hip_runtime.h>
#include <hip/hip_bf16.h>

#define TTT_LR 0.01f
#define LN_EPS 1e-5f

// Problem dims (fixed by reference)
#define BB 4
#define SS 2048
#define DD 1024
#define DSZ 64
#define CHUNK 64
#define NC (SS / CHUNK)   // 32
#define NCAT 1152         // 64 k + 64 q + 1024 v output cols
#define MiB (1024ull * 1024ull)

typedef __hip_bfloat16 bf16;
typedef __bf16 bf16x8 __attribute__((ext_vector_type(8)));
typedef float f32x4 __attribute__((ext_vector_type(4)));

__device__ __forceinline__ void gload_lds16(const void* g, void* l) {
    __builtin_amdgcn_global_load_lds(
        (const __attribute__((address_space(1))) unsigned int*)g,
        (__attribute__((address_space(3))) unsigned int*)l, 16, 0, 0);
}

// ---------------------------------------------------------------------------
// Kernel 0: concat Wk/Wq/Wv -> bf16 Wcat (1152 x 1024, row-major).
// ---------------------------------------------------------------------------
__global__ __launch_bounds__(256) void cvt_cat_kernel(
    const float* __restrict__ Wk, const float* __restrict__ Wq,
    const float* __restrict__ Wv, bf16* __restrict__ Wcat)
{
    const int i = blockIdx.x * 256 + threadIdx.x;       // float4 group index
    if (i >= NCAT * DD / 4) return;
    const int idx = i * 4;
    const int row = idx >> 10, col = idx & 1023;
    const float* src = (row < 64)  ? (Wk + (size_t)row * DD)
                     : (row < 128) ? (Wq + (size_t)(row - 64) * DD)
                                   : (Wv + (size_t)(row - 128) * DD);
    float4 v = *reinterpret_cast<const float4*>(src + col);
    bf16 h4[4] = {__float2bfloat16(v.x), __float2bfloat16(v.y),
                  __float2bfloat16(v.z), __float2bfloat16(v.w)};
    *reinterpret_cast<ushort4*>(Wcat + idx) = *reinterpret_cast<ushort4*>(h4);
}

// ---------------------------------------------------------------------------
// Kernel 1: LayerNorm only -> h (bf16). One block (256 thr) per (b,s) row.
// ---------------------------------------------------------------------------
__global__ __launch_bounds__(256) void ln_kernel(
    const float* __restrict__ x, const float* __restrict__ gamma,
    const float* __restrict__ beta, bf16* __restrict__ hb)
{
    __shared__ float wsum[4], wsum2[4];
    const int row = blockIdx.x, tid = threadIdx.x;
    const int lane = tid & 63, wave = tid >> 6;

    float4 v0 = *reinterpret_cast<const float4*>(x + (size_t)row * DD + tid * 4);
    float s = v0.x + v0.y + v0.z + v0.w;
    float s2 = fmaf(v0.x, v0.x, fmaf(v0.y, v0.y, fmaf(v0.z, v0.z, v0.w * v0.w)));
    #pragma unroll
    for (int off = 32; off > 0; off >>= 1) {
        s  += __shfl_down(s, off, 64);
        s2 += __shfl_down(s2, off, 64);
    }
    if (lane == 0) { wsum[wave] = s; wsum2[wave] = s2; }
    __syncthreads();
    s  = wsum[0] + wsum[1] + wsum[2] + wsum[3];
    s2 = wsum2[0] + wsum2[1] + wsum2[2] + wsum2[3];
    const float mu = s * (1.0f / DD);
    const float rs = rsqrtf(s2 * (1.0f / DD) - mu * mu + LN_EPS);

    float4 g  = *reinterpret_cast<const float4*>(gamma + tid * 4);
    float4 be = *reinterpret_cast<const float4*>(beta + tid * 4);
    bf16 h4[4];
    h4[0] = __float2bfloat16((v0.x - mu) * rs * g.x + be.x);
    h4[1] = __float2bfloat16((v0.y - mu) * rs * g.y + be.y);
    h4[2] = __float2bfloat16((v0.z - mu) * rs * g.z + be.z);
    h4[3] = __float2bfloat16((v0.w - mu) * rs * g.w + be.w);
    *reinterpret_cast<ushort4*>(hb + (size_t)row * DD + tid * 4) =
        *reinterpret_cast<ushort4*>(h4);
}

// ---------------------------------------------------------------------------
// Kernel 2: fused kqv = h @ Wcat^T + bias. 128x128 tile, BK=64,
// global_load_lds(16B) staging, XOR-swizzled 16B blocks. k/q stored fp32;
// v stored bf16 (vbuf16) for the MFMA scan.
// ---------------------------------------------------------------------------
__global__ __launch_bounds__(256) void kqv_kernel(
    const bf16* __restrict__ h, const bf16* __restrict__ Wcat,
    const float* __restrict__ bk, const float* __restrict__ bq,
    const float* __restrict__ bv,
    float* __restrict__ kbuf, float* __restrict__ qbuf, bf16* __restrict__ vbuf16)
{
    __shared__ bf16 Ash[128 * 64];
    __shared__ bf16 Bsh[128 * 64];
    const int tid = threadIdx.x, lane = tid & 63, wave = tid >> 6;
    const int m = lane & 15, quad = lane >> 4;
    const int wr = wave >> 1, wc = wave & 1;
    const int m0 = blockIdx.y * 128;     // h rows
    const int n0 = blockIdx.x * 128;     // Wcat rows

    const int srow = wave * 8 + (lane >> 3);   // staging row (+ i*32)
    const int scb = lane & 7;                  // staging 16B-block in row

    f32x4 acc[4][4] = {};

    for (int k0 = 0; k0 < DD; k0 += 64) {
        __syncthreads();                       // prior frag reads done
        #pragma unroll
        for (int i = 0; i < 4; ++i) {
            const int row = i * 32 + srow;
            const int g16 = scb ^ (row & 7);   // swizzled source block
            gload_lds16(h    + (size_t)(m0 + row) * DD + k0 + g16 * 8,
                        (char*)Ash + (size_t)(i * 32 + wave * 8) * 128);
            gload_lds16(Wcat + (size_t)(n0 + row) * DD + k0 + g16 * 8,
                        (char*)Bsh + (size_t)(i * 32 + wave * 8) * 128);
        }
        __syncthreads();                       // DMA drained (vmcnt0 @ barrier)
        #pragma unroll
        for (int ks = 0; ks < 2; ++ks) {
            bf16x8 af[4], bfr[4];
            #pragma unroll
            for (int mt = 0; mt < 4; ++mt) {
                const int row = wr * 64 + mt * 16 + m;
                const int kb = (ks * 4 + quad) ^ (row & 7);
                af[mt] = *reinterpret_cast<const bf16x8*>(&Ash[row * 64 + kb * 8]);
            }
            #pragma unroll
            for (int nt = 0; nt < 4; ++nt) {
                const int row = wc * 64 + nt * 16 + m;
                const int kb = (ks * 4 + quad) ^ (row & 7);
                bfr[nt] = *reinterpret_cast<const bf16x8*>(&Bsh[row * 64 + kb * 8]);
            }
            #pragma unroll
            for (int mt = 0; mt < 4; ++mt)
                #pragma unroll
                for (int nt = 0; nt < 4; ++nt)
                    acc[mt][nt] = __builtin_amdgcn_mfma_f32_16x16x32_bf16(
                        af[mt], bfr[nt], acc[mt][nt], 0, 0, 0);
        }
    }

    #pragma unroll
    for (int nt = 0; nt < 4; ++nt) {
        const int n = n0 + wc * 64 + nt * 16 + m;
        if (n < 64) {
            const float bias = bk[n];
            #pragma unroll
            for (int mt = 0; mt < 4; ++mt) {
                const int row = m0 + wr * 64 + mt * 16 + quad * 4;
                #pragma unroll
                for (int r = 0; r < 4; ++r)
                    kbuf[(size_t)(row + r) * DSZ + n] = acc[mt][nt][r] + bias;
            }
        } else if (n < 128) {
            const float bias = bq[n - 64];
            #pragma unroll
            for (int mt = 0; mt < 4; ++mt) {
                const int row = m0 + wr * 64 + mt * 16 + quad * 4;
                #pragma unroll
                for (int r = 0; r < 4; ++r)
                    qbuf[(size_t)(row + r) * DSZ + (n - 64)] = acc[mt][nt][r] + bias;
            }
        } else {
            const float bias = bv[n - 128];
            #pragma unroll
            for (int mt = 0; mt < 4; ++mt) {
                const int row = m0 + wr * 64 + mt * 16 + quad * 4;
                #pragma unroll
                for (int r = 0; r < 4; ++r)
                    vbuf16[(size_t)(row + r) * DD + (n - 128)] =
                        __float2bfloat16(acc[mt][nt][r] + bias);
            }
        }
    }
}

// ---------------------------------------------------------------------------
// Kernel 3: per-(b,chunk) prep — MFMA version (unchanged from round 7).
//   G = K K^T (lr*G fp32), A = Q K^T (strict-lower bf16)
//   Minv = (I + lr*trilS(G))^-1            [serial solve, fp32]
//   Mb16 = lr*Minv ; Bb16 = (lr*Minv)*K ; AMb16 = Astl*(lr*Minv)
//   Qtb16 = Q - Astl*B ; Ktb16 = -K^T
// ---------------------------------------------------------------------------
__global__ __launch_bounds__(256) void prep_kernel(
    const float* __restrict__ kbuf, const float* __restrict__ qbuf,
    bf16* __restrict__ Mb16, bf16* __restrict__ AMb16,
    bf16* __restrict__ Bb16, bf16* __restrict__ Qtb16, bf16* __restrict__ Ktb16)
{
    __shared__ bf16 K16[64 * 72];      // K  [t][s]
    __shared__ bf16 Kt16[64 * 72];     // K^T [s][t]
    __shared__ bf16 Q16[64 * 72];      // Q  [t][s]
    __shared__ bf16 Astl[64 * 72];     // strict-lower A, zeros elsewhere
    __shared__ bf16 Minv16[64 * 72];   // lr*Minv [t][j]
    __shared__ bf16 MinvT16[64 * 72];  // (lr*Minv)^T [j][t]
    __shared__ bf16 BnegT[64 * 72];    // -B^T [s][t]
    __shared__ float Gf[64 * 65];      // lr*G (fp32, solve input)
    __shared__ float Mf[64 * 65];      // Minv (fp32, solve output)

    const int c = blockIdx.x, b = blockIdx.y;
    const int tid = threadIdx.x, lane = tid & 63, w = tid >> 6;
    const int m = lane & 15, quad = lane >> 4;
    const float* kp = kbuf + ((size_t)b * SS + c * 64) * DSZ;
    const float* qp = qbuf + ((size_t)b * SS + c * 64) * DSZ;
    const size_t cb = ((size_t)b * NC + c) * 4096;

    // ---- stage K (row + transposed) and Q as bf16
    #pragma unroll
    for (int it = 0; it < 4; ++it) {
        const int f4 = tid + it * 256;          // float4 index 0..1023
        const int t = f4 >> 4;
        const int s = (f4 & 15) * 4;
        float4 kv = *reinterpret_cast<const float4*>(kp + t * DSZ + s);
        float4 qv = *reinterpret_cast<const float4*>(qp + t * DSZ + s);
        bf16 kb4[4] = {__float2bfloat16(kv.x), __float2bfloat16(kv.y),
                       __float2bfloat16(kv.z), __float2bfloat16(kv.w)};
        bf16 qb4[4] = {__float2bfloat16(qv.x), __float2bfloat16(qv.y),
                       __float2bfloat16(qv.z), __float2bfloat16(qv.w)};
        *reinterpret_cast<ushort4*>(&K16[t * 72 + s]) = *reinterpret_cast<ushort4*>(kb4);
        *reinterpret_cast<ushort4*>(&Q16[t * 72 + s]) = *reinterpret_cast<ushort4*>(qb4);
        #pragma unroll
        for (int i = 0; i < 4; ++i) Kt16[(s + i) * 72 + t] = kb4[i];
    }
    __syncthreads();

    // ---- G = K K^T (store lr*G fp32), A = Q K^T (store strict-lower bf16)
    bf16x8 afK[2], afQ[2], bfK[4][2];
    #pragma unroll
    for (int ks = 0; ks < 2; ++ks) {
        afK[ks] = *reinterpret_cast<const bf16x8*>(&K16[(w * 16 + m) * 72 + ks * 32 + quad * 8]);
        afQ[ks] = *reinterpret_cast<const bf16x8*>(&Q16[(w * 16 + m) * 72 + ks * 32 + quad * 8]);
        #pragma unroll
        for (int nt = 0; nt < 4; ++nt)
            bfK[nt][ks] = *reinterpret_cast<const bf16x8*>(&K16[(nt * 16 + m) * 72 + ks * 32 + quad * 8]);
    }
    f32x4 gacc[4] = {}, aacc[4] = {};
    #pragma unroll
    for (int ks = 0; ks < 2; ++ks)
        #pragma unroll
        for (int nt = 0; nt < 4; ++nt) {
            gacc[nt] = __builtin_amdgcn_mfma_f32_16x16x32_bf16(afK[ks], bfK[nt][ks], gacc[nt], 0, 0, 0);
            aacc[nt] = __builtin_amdgcn_mfma_f32_16x16x32_bf16(afQ[ks], bfK[nt][ks], aacc[nt], 0, 0, 0);
        }
    #pragma unroll
    for (int nt = 0; nt < 4; ++nt)
        #pragma unroll
        for (int r = 0; r < 4; ++r) {
            const int t = w * 16 + quad * 4 + r, j = nt * 16 + m;
            Gf[t * 65 + j] = TTT_LR * gacc[nt][r];
            Astl[t * 72 + j] = __float2bfloat16(j < t ? aacc[nt][r] : 0.f);
        }
    __syncthreads();

    // ---- serial forward-substitution: Minv = (I + lr*trilS(G))^-1 (fp32)
    if (tid < 64) {
        for (int t = 0; t < 64; ++t) {
            float acc = (t == tid) ? 1.f : 0.f;
            for (int i = 0; i < t; ++i)
                acc = fmaf(-Gf[t * 65 + i], Mf[i * 65 + tid], acc);
            Mf[t * 65 + tid] = acc;
        }
    }
    __syncthreads();

    // ---- lr*Minv -> bf16 (row + transposed); write Mb16 and Ktb16 = -K^T
    #pragma unroll
    for (int it = 0; it < 16; ++it) {
        const int e = tid + it * 256;           // 0..4095
        const int t = e >> 6, j = e & 63;
        const bf16 vb = __float2bfloat16(TTT_LR * Mf[t * 65 + j]);
        Minv16[t * 72 + j] = vb;
        MinvT16[j * 72 + t] = vb;
        Mb16[cb + e] = vb;
        const unsigned short ku =
            *reinterpret_cast<const unsigned short*>(&Kt16[t * 72 + j]) ^ 0x8000u;
        *reinterpret_cast<unsigned short*>(&Ktb16[cb + e]) = ku;
    }
    __syncthreads();

    // ---- B = (lr*Minv) * K  via mfma(Minv16 rows, Kt16 rows)
    bf16x8 afM[2], afA[2], bfKt[4][2], bfMt[4][2];
    #pragma unroll
    for (int ks = 0; ks < 2; ++ks) {
        afM[ks] = *reinterpret_cast<const bf16x8*>(&Minv16[(w * 16 + m) * 72 + ks * 32 + quad * 8]);
        afA[ks] = *reinterpret_cast<const bf16x8*>(&Astl[(w * 16 + m) * 72 + ks * 32 + quad * 8]);
        #pragma unroll
        for (int nt = 0; nt < 4; ++nt) {
            bfKt[nt][ks] = *reinterpret_cast<const bf16x8*>(&Kt16[(nt * 16 + m) * 72 + ks * 32 + quad * 8]);
            bfMt[nt][ks] = *reinterpret_cast<const bf16x8*>(&MinvT16[(nt * 16 + m) * 72 + ks * 32 + quad * 8]);
        }
    }
    f32x4 bacc[4] = {};
    #pragma unroll
    for (int ks = 0; ks < 2; ++ks)
        #pragma unroll
        for (int nt = 0; nt < 4; ++nt)
            bacc[nt] = __builtin_amdgcn_mfma_f32_16x16x32_bf16(afM[ks], bfKt[nt][ks], bacc[nt], 0, 0, 0);
    #pragma unroll
    for (int nt = 0; nt < 4; ++nt)
        #pragma unroll
        for (int r = 0; r < 4; ++r) {
            const int t = w * 16 + quad * 4 + r, s = nt * 16 + m;
            Bb16[cb + t * 64 + s] = __float2bfloat16(bacc[nt][r]);
            BnegT[s * 72 + t] = __float2bfloat16(-bacc[nt][r]);
        }
    __syncthreads();

    // ---- Qt = Q - Astl*B (C-init = Q), AM = Astl*(lr*Minv)
    f32x4 qtacc[4], amacc[4] = {};
    #pragma unroll
    for (int nt = 0; nt < 4; ++nt)
        #pragma unroll
        for (int r = 0; r < 4; ++r)
            qtacc[nt][r] = qp[(w * 16 + quad * 4 + r) * DSZ + nt * 16 + m];
    #pragma unroll
    for (int ks = 0; ks < 2; ++ks)
        #pragma unroll
        for (int nt = 0; nt < 4; ++nt) {
            const bf16x8 bfBn = *reinterpret_cast<const bf16x8*>(
                &BnegT[(nt * 16 + m) * 72 + ks * 32 + quad * 8]);
            qtacc[nt] = __builtin_amdgcn_mfma_f32_16x16x32_bf16(afA[ks], bfBn, qtacc[nt], 0, 0, 0);
            amacc[nt] = __builtin_amdgcn_mfma_f32_16x16x32_bf16(afA[ks], bfMt[nt][ks], amacc[nt], 0, 0, 0);
        }
    #pragma unroll
    for (int nt = 0; nt < 4; ++nt)
        #pragma unroll
        for (int r = 0; r < 4; ++r) {
            const int t = w * 16 + quad * 4 + r, s = nt * 16 + m;
            Qtb16[cb + t * 64 + s] = __float2bfloat16(qtacc[nt][r]);
            AMb16[cb + t * 64 + s] = __float2bfloat16(amacc[nt][r]);
        }
}

// ---------------------------------------------------------------------------
// Kernel 4: fused scan (replaces usolve + seq). 256 blocks (64 d-stripes x
// 4 batches), 4 waves. Per chunk c (10 MFMAs, 2 barriers):
//   U  = M_c V_c          (fp32, registers — never hits memory)
//   Yi = AM_c V_c
//   P  = B_c Z - U        (register subtract; P -> LDS bf16)
//   out = x + Yi + Qt_c Z (single store per element)
//   Z += (-K^T) P         (fp32 C/D accumulator, bf16 round-trip via LDS)
// V stripe double-buffered in LDS (transposed [d][j]) so 2 barriers suffice.
// ---------------------------------------------------------------------------
__global__ __launch_bounds__(256) void scan2_kernel(
    const bf16* __restrict__ Mb16, const bf16* __restrict__ AMb16,
    const bf16* __restrict__ Bb16, const bf16* __restrict__ Qtb16,
    const bf16* __restrict__ Ktb16, const bf16* __restrict__ v16,
    const float* __restrict__ x, float* __restrict__ out)
{
    __shared__ bf16 Zsh[16][72];
    __shared__ bf16 Psh[16][72];
    __shared__ bf16 Vsh[2][16][72];
    const int dblk = blockIdx.x, b = blockIdx.y;
    const int tid = threadIdx.x, lane = tid & 63, w = tid >> 6;
    const int m = lane & 15, quad = lane >> 4;
    const int d0 = dblk * 16;
    const int arow = w * 16 + m;          // A-frag row (all matmuls)
    const int trow = w * 16 + quad * 4;   // first C/D row for this thread

    // V staging mapping: thread -> (row j, 4 cols starting at vd)
    const int vj = tid >> 2;              // 0..63
    const int vd = (tid & 3) * 4;         // 0,4,8,12

    f32x4 zacc = {0.f, 0.f, 0.f, 0.f};
    for (int i = tid; i < 16 * 72; i += 256)
        (&Zsh[0][0])[i] = __float2bfloat16(0.f);

    for (int c = 0; c < NC; ++c) {
        const size_t cb = ((size_t)b * NC + c) * 4096;
        const size_t rowbase = (size_t)b * SS + (size_t)c * 64;
        const size_t gbase = (rowbase + trow) * DD + d0 + m;

        // ---- issue all global loads up front
        const bf16x8 aM0 = *reinterpret_cast<const bf16x8*>(Mb16 + cb + arow * 64 + quad * 8);
        const bf16x8 aM1 = *reinterpret_cast<const bf16x8*>(Mb16 + cb + arow * 64 + 32 + quad * 8);
        const bf16x8 aA0 = *reinterpret_cast<const bf16x8*>(AMb16 + cb + arow * 64 + quad * 8);
        const bf16x8 aA1 = *reinterpret_cast<const bf16x8*>(AMb16 + cb + arow * 64 + 32 + quad * 8);
        const bf16x8 aB0 = *reinterpret_cast<const bf16x8*>(Bb16 + cb + arow * 64 + quad * 8);
        const bf16x8 aB1 = *reinterpret_cast<const bf16x8*>(Bb16 + cb + arow * 64 + 32 + quad * 8);
        const bf16x8 aQ0 = *reinterpret_cast<const bf16x8*>(Qtb16 + cb + arow * 64 + quad * 8);
        const bf16x8 aQ1 = *reinterpret_cast<const bf16x8*>(Qtb16 + cb + arow * 64 + 32 + quad * 8);
        const bf16x8 aK0 = *reinterpret_cast<const bf16x8*>(Ktb16 + cb + arow * 64 + quad * 8);
        const bf16x8 aK1 = *reinterpret_cast<const bf16x8*>(Ktb16 + cb + arow * 64 + 32 + quad * 8);
        alignas(8) bf16 va[4];
        *reinterpret_cast<uint2*>(va) = *reinterpret_cast<const uint2*>(
            v16 + (rowbase + vj) * DD + d0 + vd);
        float xld[4];
        #pragma unroll
        for (int r = 0; r < 4; ++r) xld[r] = x[gbase + (size_t)r * DD];

        // ---- stage V^T into this chunk's buffer (prev-iter reads were on
        //      the other buffer; 2-iters-ago reads long since drained)
        #pragma unroll
        for (int i = 0; i < 4; ++i) Vsh[c & 1][vd + i][vj] = va[i];

        __syncthreads();                  // (1) Zsh + Vsh[c&1] ready, Psh free
        const bf16x8 z0 = *reinterpret_cast<const bf16x8*>(&Zsh[m][quad * 8]);
        const bf16x8 z1 = *reinterpret_cast<const bf16x8*>(&Zsh[m][32 + quad * 8]);
        const bf16x8 v0 = *reinterpret_cast<const bf16x8*>(&Vsh[c & 1][m][quad * 8]);
        const bf16x8 v1 = *reinterpret_cast<const bf16x8*>(&Vsh[c & 1][m][32 + quad * 8]);

        f32x4 uacc = {0.f, 0.f, 0.f, 0.f};   // U = M V
        f32x4 yi   = {0.f, 0.f, 0.f, 0.f};   // Yi = AM V
        f32x4 pacc = {0.f, 0.f, 0.f, 0.f};   // B Z
        f32x4 yc   = {0.f, 0.f, 0.f, 0.f};   // Qt Z
        uacc = __builtin_amdgcn_mfma_f32_16x16x32_bf16(aM0, v0, uacc, 0, 0, 0);
        uacc = __builtin_amdgcn_mfma_f32_16x16x32_bf16(aM1, v1, uacc, 0, 0, 0);
        yi   = __builtin_amdgcn_mfma_f32_16x16x32_bf16(aA0, v0, yi, 0, 0, 0);
        yi   = __builtin_amdgcn_mfma_f32_16x16x32_bf16(aA1, v1, yi, 0, 0, 0);
        pacc = __builtin_amdgcn_mfma_f32_16x16x32_bf16(aB0, z0, pacc, 0, 0, 0);
        pacc = __builtin_amdgcn_mfma_f32_16x16x32_bf16(aB1, z1, pacc, 0, 0, 0);
        yc   = __builtin_amdgcn_mfma_f32_16x16x32_bf16(aQ0, z0, yc, 0, 0, 0);
        yc   = __builtin_amdgcn_mfma_f32_16x16x32_bf16(aQ1, z1, yc, 0, 0, 0);

        alignas(8) bf16 pb[4];
        #pragma unroll
        for (int r = 0; r < 4; ++r) {
            out[gbase + (size_t)r * DD] = xld[r] + yi[r] + yc[r];
            pb[r] = __float2bfloat16(pacc[r] - uacc[r]);
        }
        *reinterpret_cast<uint2*>(&Psh[m][trow]) = *reinterpret_cast<uint2*>(pb);

        __syncthreads();                  // (2) Psh ready, Zsh reads done
        const bf16x8 p0 = *reinterpret_cast<const bf16x8*>(&Psh[m][quad * 8]);
        const bf16x8 p1 = *reinterpret_cast<const bf16x8*>(&Psh[m][32 + quad * 8]);
        zacc = __builtin_amdgcn_mfma_f32_16x16x32_bf16(aK0, p0, zacc, 0, 0, 0);
        zacc = __builtin_amdgcn_mfma_f32_16x16x32_bf16(aK1, p1, zacc, 0, 0, 0);

        alignas(8) bf16 zb[4];
        #pragma unroll
        for (int r = 0; r < 4; ++r) zb[r] = __float2bfloat16(zacc[r]);
        *reinterpret_cast<uint2*>(&Zsh[m][trow]) = *reinterpret_cast<uint2*>(zb);
    }
}

// ---------------------------------------------------------------------------
extern "C" void kernel_launch(void* const* d_in, const int* in_sizes, int n_in,
                              void* d_out, int out_size, void* d_ws, size_t ws_size,
                              hipStream_t stream)
{
    const float* x     = (const float*)d_in[0];
    const float* Wk    = (const float*)d_in[1];
    const float* bk    = (const float*)d_in[2];
    const float* Wv    = (const float*)d_in[3];
    const float* bv    = (const float*)d_in[4];
    const float* Wq    = (const float*)d_in[5];
    const float* bq    = (const float*)d_in[6];
    const float* gamma = (const float*)d_in[7];
    const float* beta  = (const float*)d_in[8];

    char* ws = (char*)d_ws;
    // layout (~38.25 MiB):
    //   [0,16 MiB): hb (bf16, ln->kqv) -- dead after kqv; reused by prep as:
    //     Bb16@0, Qtb16@1MiB, Ktb16@2MiB, Mb16@3MiB, AMb16@4MiB (1 MiB each)
    //   [16 MiB, +2.25): Wcat (bf16 1152x1024)
    //   +2 MiB: kbuf (fp32)   +2 MiB: qbuf (fp32)
    //   +16 MiB: vbuf16 (bf16 8192x1024)
    const size_t WCAT_B = (size_t)NCAT * DD * 2;   // 2.25 MiB
    bf16*  hb    = (bf16*)ws;
    bf16*  Bb16  = (bf16*)(ws + 0 * MiB);
    bf16*  Qtb16 = (bf16*)(ws + 1 * MiB);
    bf16*  Ktb16 = (bf16*)(ws + 2 * MiB);
    bf16*  Mb16  = (bf16*)(ws + 3 * MiB);
    bf16*  AMb16 = (bf16*)(ws + 4 * MiB);
    bf16*  Wcat  = (bf16*)(ws + 16 * MiB);
    float* kbuf  = (float*)(ws + 16 * MiB + WCAT_B);
    float* qbuf  = (float*)(ws + 18 * MiB + WCAT_B);
    bf16*  v16   = (bf16*)(ws + 20 * MiB + WCAT_B);

    cvt_cat_kernel<<<(NCAT * DD / 4 + 255) / 256, 256, 0, stream>>>(Wk, Wq, Wv, Wcat);
    ln_kernel<<<BB * SS, 256, 0, stream>>>(x, gamma, beta, hb);
    kqv_kernel<<<dim3(NCAT / 128, BB * SS / 128), 256, 0, stream>>>(
        hb, Wcat, bk, bq, bv, kbuf, qbuf, v16);
    prep_kernel<<<dim3(NC, BB), 256, 0, stream>>>(
        kbuf, qbuf, Mb16, AMb16, Bb16, Qtb16, Ktb16);
    scan2_kernel<<<dim3(DD / 16, BB), 256, 0, stream>>>(
        Mb16, AMb16, Bb16, Qtb16, Ktb16, v16, x, (float*)d_out);
}

// Round 9
// 229.312 us; speedup vs baseline: 21.6184x; 1.0178x over previous
//
#include <hip/hip_runtime.h>
#include <hip/hip_bf16.h>

#define TTT_LR 0.01f
#define LN_EPS 1e-5f

// Problem dims (fixed by reference)
#define BB 4
#define SS 2048
#define DD 1024
#define DSZ 64
#define CHUNK 64
#define NC (SS / CHUNK)   // 32
#define NCAT 1152         // 64 k + 64 q + 1024 v output cols
#define NCVT (NCAT * DD / 4 / 256)   // 1152 cvt blocks
#define MiB (1024ull * 1024ull)

typedef __hip_bfloat16 bf16;
typedef __bf16 bf16x8 __attribute__((ext_vector_type(8)));
typedef float f32x4 __attribute__((ext_vector_type(4)));

__device__ __forceinline__ void gload_lds16(const void* g, void* l) {
    __builtin_amdgcn_global_load_lds(
        (const __attribute__((address_space(1))) unsigned int*)g,
        (__attribute__((address_space(3))) unsigned int*)l, 16, 0, 0);
}

// ---------------------------------------------------------------------------
// Kernel 1: merged pre-pass. Blocks [0,NCVT): Wk/Wq/Wv -> bf16 Wcat.
// Blocks [NCVT, NCVT+B*S): LayerNorm row -> h (bf16).
// ---------------------------------------------------------------------------
__global__ __launch_bounds__(256) void pre_kernel(
    const float* __restrict__ Wk, const float* __restrict__ Wq,
    const float* __restrict__ Wv, bf16* __restrict__ Wcat,
    const float* __restrict__ x, const float* __restrict__ gamma,
    const float* __restrict__ beta, bf16* __restrict__ hb)
{
    __shared__ float wsum[4], wsum2[4];
    const int tid = threadIdx.x;

    if (blockIdx.x < NCVT) {
        const int i = blockIdx.x * 256 + tid;           // float4 group index
        const int idx = i * 4;
        const int row = idx >> 10, col = idx & 1023;
        const float* src = (row < 64)  ? (Wk + (size_t)row * DD)
                         : (row < 128) ? (Wq + (size_t)(row - 64) * DD)
                                       : (Wv + (size_t)(row - 128) * DD);
        float4 v = *reinterpret_cast<const float4*>(src + col);
        bf16 h4[4] = {__float2bfloat16(v.x), __float2bfloat16(v.y),
                      __float2bfloat16(v.z), __float2bfloat16(v.w)};
        *reinterpret_cast<ushort4*>(Wcat + idx) = *reinterpret_cast<ushort4*>(h4);
        return;
    }

    const int row = blockIdx.x - NCVT;
    const int lane = tid & 63, wave = tid >> 6;

    float4 v0 = *reinterpret_cast<const float4*>(x + (size_t)row * DD + tid * 4);
    float s = v0.x + v0.y + v0.z + v0.w;
    float s2 = fmaf(v0.x, v0.x, fmaf(v0.y, v0.y, fmaf(v0.z, v0.z, v0.w * v0.w)));
    #pragma unroll
    for (int off = 32; off > 0; off >>= 1) {
        s  += __shfl_down(s, off, 64);
        s2 += __shfl_down(s2, off, 64);
    }
    if (lane == 0) { wsum[wave] = s; wsum2[wave] = s2; }
    __syncthreads();
    s  = wsum[0] + wsum[1] + wsum[2] + wsum[3];
    s2 = wsum2[0] + wsum2[1] + wsum2[2] + wsum2[3];
    const float mu = s * (1.0f / DD);
    const float rs = rsqrtf(s2 * (1.0f / DD) - mu * mu + LN_EPS);

    float4 g  = *reinterpret_cast<const float4*>(gamma + tid * 4);
    float4 be = *reinterpret_cast<const float4*>(beta + tid * 4);
    bf16 h4[4];
    h4[0] = __float2bfloat16((v0.x - mu) * rs * g.x + be.x);
    h4[1] = __float2bfloat16((v0.y - mu) * rs * g.y + be.y);
    h4[2] = __float2bfloat16((v0.z - mu) * rs * g.z + be.z);
    h4[3] = __float2bfloat16((v0.w - mu) * rs * g.w + be.w);
    *reinterpret_cast<ushort4*>(hb + (size_t)row * DD + tid * 4) =
        *reinterpret_cast<ushort4*>(h4);
}

// ---------------------------------------------------------------------------
// Kernel 2: fused kqv = h @ Wcat^T + bias. 128x128 tile, BK=64,
// global_load_lds(16B) staging, XOR-swizzled 16B blocks. k/q stored fp32;
// v stored bf16 (vbuf16) for the MFMA scan.
// ---------------------------------------------------------------------------
__global__ __launch_bounds__(256) void kqv_kernel(
    const bf16* __restrict__ h, const bf16* __restrict__ Wcat,
    const float* __restrict__ bk, const float* __restrict__ bq,
    const float* __restrict__ bv,
    float* __restrict__ kbuf, float* __restrict__ qbuf, bf16* __restrict__ vbuf16)
{
    __shared__ bf16 Ash[128 * 64];
    __shared__ bf16 Bsh[128 * 64];
    const int tid = threadIdx.x, lane = tid & 63, wave = tid >> 6;
    const int m = lane & 15, quad = lane >> 4;
    const int wr = wave >> 1, wc = wave & 1;
    const int m0 = blockIdx.y * 128;     // h rows
    const int n0 = blockIdx.x * 128;     // Wcat rows

    const int srow = wave * 8 + (lane >> 3);   // staging row (+ i*32)
    const int scb = lane & 7;                  // staging 16B-block in row

    f32x4 acc[4][4] = {};

    for (int k0 = 0; k0 < DD; k0 += 64) {
        __syncthreads();                       // prior frag reads done
        #pragma unroll
        for (int i = 0; i < 4; ++i) {
            const int row = i * 32 + srow;
            const int g16 = scb ^ (row & 7);   // swizzled source block
            gload_lds16(h    + (size_t)(m0 + row) * DD + k0 + g16 * 8,
                        (char*)Ash + (size_t)(i * 32 + wave * 8) * 128);
            gload_lds16(Wcat + (size_t)(n0 + row) * DD + k0 + g16 * 8,
                        (char*)Bsh + (size_t)(i * 32 + wave * 8) * 128);
        }
        __syncthreads();                       // DMA drained (vmcnt0 @ barrier)
        #pragma unroll
        for (int ks = 0; ks < 2; ++ks) {
            bf16x8 af[4], bfr[4];
            #pragma unroll
            for (int mt = 0; mt < 4; ++mt) {
                const int row = wr * 64 + mt * 16 + m;
                const int kb = (ks * 4 + quad) ^ (row & 7);
                af[mt] = *reinterpret_cast<const bf16x8*>(&Ash[row * 64 + kb * 8]);
            }
            #pragma unroll
            for (int nt = 0; nt < 4; ++nt) {
                const int row = wc * 64 + nt * 16 + m;
                const int kb = (ks * 4 + quad) ^ (row & 7);
                bfr[nt] = *reinterpret_cast<const bf16x8*>(&Bsh[row * 64 + kb * 8]);
            }
            #pragma unroll
            for (int mt = 0; mt < 4; ++mt)
                #pragma unroll
                for (int nt = 0; nt < 4; ++nt)
                    acc[mt][nt] = __builtin_amdgcn_mfma_f32_16x16x32_bf16(
                        af[mt], bfr[nt], acc[mt][nt], 0, 0, 0);
        }
    }

    #pragma unroll
    for (int nt = 0; nt < 4; ++nt) {
        const int n = n0 + wc * 64 + nt * 16 + m;
        if (n < 64) {
            const float bias = bk[n];
            #pragma unroll
            for (int mt = 0; mt < 4; ++mt) {
                const int row = m0 + wr * 64 + mt * 16 + quad * 4;
                #pragma unroll
                for (int r = 0; r < 4; ++r)
                    kbuf[(size_t)(row + r) * DSZ + n] = acc[mt][nt][r] + bias;
            }
        } else if (n < 128) {
            const float bias = bq[n - 64];
            #pragma unroll
            for (int mt = 0; mt < 4; ++mt) {
                const int row = m0 + wr * 64 + mt * 16 + quad * 4;
                #pragma unroll
                for (int r = 0; r < 4; ++r)
                    qbuf[(size_t)(row + r) * DSZ + (n - 64)] = acc[mt][nt][r] + bias;
            }
        } else {
            const float bias = bv[n - 128];
            #pragma unroll
            for (int mt = 0; mt < 4; ++mt) {
                const int row = m0 + wr * 64 + mt * 16 + quad * 4;
                #pragma unroll
                for (int r = 0; r < 4; ++r)
                    vbuf16[(size_t)(row + r) * DD + (n - 128)] =
                        __float2bfloat16(acc[mt][nt][r] + bias);
            }
        }
    }
}

// ---------------------------------------------------------------------------
// Kernel 3: per-(b,chunk) prep — MFMA version (unchanged from round 7/8).
// ---------------------------------------------------------------------------
__global__ __launch_bounds__(256) void prep_kernel(
    const float* __restrict__ kbuf, const float* __restrict__ qbuf,
    bf16* __restrict__ Mb16, bf16* __restrict__ AMb16,
    bf16* __restrict__ Bb16, bf16* __restrict__ Qtb16, bf16* __restrict__ Ktb16)
{
    __shared__ bf16 K16[64 * 72];      // K  [t][s]
    __shared__ bf16 Kt16[64 * 72];     // K^T [s][t]
    __shared__ bf16 Q16[64 * 72];      // Q  [t][s]
    __shared__ bf16 Astl[64 * 72];     // strict-lower A, zeros elsewhere
    __shared__ bf16 Minv16[64 * 72];   // lr*Minv [t][j]
    __shared__ bf16 MinvT16[64 * 72];  // (lr*Minv)^T [j][t]
    __shared__ bf16 BnegT[64 * 72];    // -B^T [s][t]
    __shared__ float Gf[64 * 65];      // lr*G (fp32, solve input)
    __shared__ float Mf[64 * 65];      // Minv (fp32, solve output)

    const int c = blockIdx.x, b = blockIdx.y;
    const int tid = threadIdx.x, lane = tid & 63, w = tid >> 6;
    const int m = lane & 15, quad = lane >> 4;
    const float* kp = kbuf + ((size_t)b * SS + c * 64) * DSZ;
    const float* qp = qbuf + ((size_t)b * SS + c * 64) * DSZ;
    const size_t cb = ((size_t)b * NC + c) * 4096;

    // ---- stage K (row + transposed) and Q as bf16
    #pragma unroll
    for (int it = 0; it < 4; ++it) {
        const int f4 = tid + it * 256;          // float4 index 0..1023
        const int t = f4 >> 4;
        const int s = (f4 & 15) * 4;
        float4 kv = *reinterpret_cast<const float4*>(kp + t * DSZ + s);
        float4 qv = *reinterpret_cast<const float4*>(qp + t * DSZ + s);
        bf16 kb4[4] = {__float2bfloat16(kv.x), __float2bfloat16(kv.y),
                       __float2bfloat16(kv.z), __float2bfloat16(kv.w)};
        bf16 qb4[4] = {__float2bfloat16(qv.x), __float2bfloat16(qv.y),
                       __float2bfloat16(qv.z), __float2bfloat16(qv.w)};
        *reinterpret_cast<ushort4*>(&K16[t * 72 + s]) = *reinterpret_cast<ushort4*>(kb4);
        *reinterpret_cast<ushort4*>(&Q16[t * 72 + s]) = *reinterpret_cast<ushort4*>(qb4);
        #pragma unroll
        for (int i = 0; i < 4; ++i) Kt16[(s + i) * 72 + t] = kb4[i];
    }
    __syncthreads();

    // ---- G = K K^T (store lr*G fp32), A = Q K^T (store strict-lower bf16)
    bf16x8 afK[2], afQ[2], bfK[4][2];
    #pragma unroll
    for (int ks = 0; ks < 2; ++ks) {
        afK[ks] = *reinterpret_cast<const bf16x8*>(&K16[(w * 16 + m) * 72 + ks * 32 + quad * 8]);
        afQ[ks] = *reinterpret_cast<const bf16x8*>(&Q16[(w * 16 + m) * 72 + ks * 32 + quad * 8]);
        #pragma unroll
        for (int nt = 0; nt < 4; ++nt)
            bfK[nt][ks] = *reinterpret_cast<const bf16x8*>(&K16[(nt * 16 + m) * 72 + ks * 32 + quad * 8]);
    }
    f32x4 gacc[4] = {}, aacc[4] = {};
    #pragma unroll
    for (int ks = 0; ks < 2; ++ks)
        #pragma unroll
        for (int nt = 0; nt < 4; ++nt) {
            gacc[nt] = __builtin_amdgcn_mfma_f32_16x16x32_bf16(afK[ks], bfK[nt][ks], gacc[nt], 0, 0, 0);
            aacc[nt] = __builtin_amdgcn_mfma_f32_16x16x32_bf16(afQ[ks], bfK[nt][ks], aacc[nt], 0, 0, 0);
        }
    #pragma unroll
    for (int nt = 0; nt < 4; ++nt)
        #pragma unroll
        for (int r = 0; r < 4; ++r) {
            const int t = w * 16 + quad * 4 + r, j = nt * 16 + m;
            Gf[t * 65 + j] = TTT_LR * gacc[nt][r];
            Astl[t * 72 + j] = __float2bfloat16(j < t ? aacc[nt][r] : 0.f);
        }
    __syncthreads();

    // ---- serial forward-substitution: Minv = (I + lr*trilS(G))^-1 (fp32)
    if (tid < 64) {
        for (int t = 0; t < 64; ++t) {
            float acc = (t == tid) ? 1.f : 0.f;
            for (int i = 0; i < t; ++i)
                acc = fmaf(-Gf[t * 65 + i], Mf[i * 65 + tid], acc);
            Mf[t * 65 + tid] = acc;
        }
    }
    __syncthreads();

    // ---- lr*Minv -> bf16 (row + transposed); write Mb16 and Ktb16 = -K^T
    #pragma unroll
    for (int it = 0; it < 16; ++it) {
        const int e = tid + it * 256;           // 0..4095
        const int t = e >> 6, j = e & 63;
        const bf16 vb = __float2bfloat16(TTT_LR * Mf[t * 65 + j]);
        Minv16[t * 72 + j] = vb;
        MinvT16[j * 72 + t] = vb;
        Mb16[cb + e] = vb;
        const unsigned short ku =
            *reinterpret_cast<const unsigned short*>(&Kt16[t * 72 + j]) ^ 0x8000u;
        *reinterpret_cast<unsigned short*>(&Ktb16[cb + e]) = ku;
    }
    __syncthreads();

    // ---- B = (lr*Minv) * K  via mfma(Minv16 rows, Kt16 rows)
    bf16x8 afM[2], afA[2], bfKt[4][2], bfMt[4][2];
    #pragma unroll
    for (int ks = 0; ks < 2; ++ks) {
        afM[ks] = *reinterpret_cast<const bf16x8*>(&Minv16[(w * 16 + m) * 72 + ks * 32 + quad * 8]);
        afA[ks] = *reinterpret_cast<const bf16x8*>(&Astl[(w * 16 + m) * 72 + ks * 32 + quad * 8]);
        #pragma unroll
        for (int nt = 0; nt < 4; ++nt) {
            bfKt[nt][ks] = *reinterpret_cast<const bf16x8*>(&Kt16[(nt * 16 + m) * 72 + ks * 32 + quad * 8]);
            bfMt[nt][ks] = *reinterpret_cast<const bf16x8*>(&MinvT16[(nt * 16 + m) * 72 + ks * 32 + quad * 8]);
        }
    }
    f32x4 bacc[4] = {};
    #pragma unroll
    for (int ks = 0; ks < 2; ++ks)
        #pragma unroll
        for (int nt = 0; nt < 4; ++nt)
            bacc[nt] = __builtin_amdgcn_mfma_f32_16x16x32_bf16(afM[ks], bfKt[nt][ks], bacc[nt], 0, 0, 0);
    #pragma unroll
    for (int nt = 0; nt < 4; ++nt)
        #pragma unroll
        for (int r = 0; r < 4; ++r) {
            const int t = w * 16 + quad * 4 + r, s = nt * 16 + m;
            Bb16[cb + t * 64 + s] = __float2bfloat16(bacc[nt][r]);
            BnegT[s * 72 + t] = __float2bfloat16(-bacc[nt][r]);
        }
    __syncthreads();

    // ---- Qt = Q - Astl*B (C-init = Q), AM = Astl*(lr*Minv)
    f32x4 qtacc[4], amacc[4] = {};
    #pragma unroll
    for (int nt = 0; nt < 4; ++nt)
        #pragma unroll
        for (int r = 0; r < 4; ++r)
            qtacc[nt][r] = qp[(w * 16 + quad * 4 + r) * DSZ + nt * 16 + m];
    #pragma unroll
    for (int ks = 0; ks < 2; ++ks)
        #pragma unroll
        for (int nt = 0; nt < 4; ++nt) {
            const bf16x8 bfBn = *reinterpret_cast<const bf16x8*>(
                &BnegT[(nt * 16 + m) * 72 + ks * 32 + quad * 8]);
            qtacc[nt] = __builtin_amdgcn_mfma_f32_16x16x32_bf16(afA[ks], bfBn, qtacc[nt], 0, 0, 0);
            amacc[nt] = __builtin_amdgcn_mfma_f32_16x16x32_bf16(afA[ks], bfMt[nt][ks], amacc[nt], 0, 0, 0);
        }
    #pragma unroll
    for (int nt = 0; nt < 4; ++nt)
        #pragma unroll
        for (int r = 0; r < 4; ++r) {
            const int t = w * 16 + quad * 4 + r, s = nt * 16 + m;
            Qtb16[cb + t * 64 + s] = __float2bfloat16(qtacc[nt][r]);
            AMb16[cb + t * 64 + s] = __float2bfloat16(amacc[nt][r]);
        }
}

// ---------------------------------------------------------------------------
// Kernel 4: fused scan, SOFTWARE-PIPELINED (prefetch chunk c+1's globals
// during chunk c's compute; 2-deep register rotation, NC even).
// Per chunk (10 MFMAs, 2 barriers):
//   U = M V ; Yi = AM V ; P = B Z - U ; out = x + Yi + Qt Z ; Z += (-K^T) P.
// ---------------------------------------------------------------------------
struct ChunkRegs {
    bf16x8 M0, M1, A0, A1, B0, B1, Q0, Q1, K0, K1;
    alignas(8) unsigned short va[4], vb[4];   // V rows (vj2, vj2+1) x 4 cols
    float xld[4];
};

__global__ __launch_bounds__(256) void scan2_kernel(
    const bf16* __restrict__ Mb16, const bf16* __restrict__ AMb16,
    const bf16* __restrict__ Bb16, const bf16* __restrict__ Qtb16,
    const bf16* __restrict__ Ktb16, const bf16* __restrict__ v16,
    const float* __restrict__ x, float* __restrict__ out)
{
    __shared__ bf16 Zsh[16][72];
    __shared__ bf16 Psh[16][72];
    __shared__ bf16 Vsh[2][16][72];
    const int dblk = blockIdx.x, b = blockIdx.y;
    const int tid = threadIdx.x, lane = tid & 63, w = tid >> 6;
    const int m = lane & 15, quad = lane >> 4;
    const int d0 = dblk * 16;
    const int arow = w * 16 + m;          // A-frag row (all matmuls)
    const int trow = w * 16 + quad * 4;   // first C/D row for this thread

    // V staging: tid<128; row pair vj2, col group vd (4 cols)
    const bool vact = tid < 128;
    const int vj2 = (tid & 31) * 2;
    const int vd = (tid >> 5) * 4;        // 0,4,8,12 for tid<128

    f32x4 zacc = {0.f, 0.f, 0.f, 0.f};
    for (int i = tid; i < 16 * 72; i += 256)
        (&Zsh[0][0])[i] = __float2bfloat16(0.f);

    auto load_chunk = [&](int c, ChunkRegs& R) {
        const size_t cb = ((size_t)b * NC + c) * 4096;
        const size_t rowbase = (size_t)b * SS + (size_t)c * 64;
        R.M0 = *reinterpret_cast<const bf16x8*>(Mb16 + cb + arow * 64 + quad * 8);
        R.M1 = *reinterpret_cast<const bf16x8*>(Mb16 + cb + arow * 64 + 32 + quad * 8);
        R.A0 = *reinterpret_cast<const bf16x8*>(AMb16 + cb + arow * 64 + quad * 8);
        R.A1 = *reinterpret_cast<const bf16x8*>(AMb16 + cb + arow * 64 + 32 + quad * 8);
        R.B0 = *reinterpret_cast<const bf16x8*>(Bb16 + cb + arow * 64 + quad * 8);
        R.B1 = *reinterpret_cast<const bf16x8*>(Bb16 + cb + arow * 64 + 32 + quad * 8);
        R.Q0 = *reinterpret_cast<const bf16x8*>(Qtb16 + cb + arow * 64 + quad * 8);
        R.Q1 = *reinterpret_cast<const bf16x8*>(Qtb16 + cb + arow * 64 + 32 + quad * 8);
        R.K0 = *reinterpret_cast<const bf16x8*>(Ktb16 + cb + arow * 64 + quad * 8);
        R.K1 = *reinterpret_cast<const bf16x8*>(Ktb16 + cb + arow * 64 + 32 + quad * 8);
        if (vact) {
            *reinterpret_cast<uint2*>(R.va) = *reinterpret_cast<const uint2*>(
                v16 + (rowbase + vj2) * DD + d0 + vd);
            *reinterpret_cast<uint2*>(R.vb) = *reinterpret_cast<const uint2*>(
                v16 + (rowbase + vj2 + 1) * DD + d0 + vd);
        }
        const size_t gbase = (rowbase + trow) * DD + d0 + m;
        #pragma unroll
        for (int r = 0; r < 4; ++r) R.xld[r] = x[gbase + (size_t)r * DD];
    };

    auto stage_v = [&](const ChunkRegs& R, int buf) {
        if (vact) {
            #pragma unroll
            for (int i = 0; i < 4; ++i) {
                const unsigned int pack =
                    (unsigned int)R.va[i] | ((unsigned int)R.vb[i] << 16);
                *reinterpret_cast<unsigned int*>(&Vsh[buf][vd + i][vj2]) = pack;
            }
        }
    };

    auto compute = [&](const ChunkRegs& R, int c, int buf) {
        const size_t gbase = ((size_t)b * SS + (size_t)c * 64 + trow) * DD + d0 + m;
        const bf16x8 z0 = *reinterpret_cast<const bf16x8*>(&Zsh[m][quad * 8]);
        const bf16x8 z1 = *reinterpret_cast<const bf16x8*>(&Zsh[m][32 + quad * 8]);
        const bf16x8 v0 = *reinterpret_cast<const bf16x8*>(&Vsh[buf][m][quad * 8]);
        const bf16x8 v1 = *reinterpret_cast<const bf16x8*>(&Vsh[buf][m][32 + quad * 8]);

        f32x4 uacc = {0.f, 0.f, 0.f, 0.f};
        f32x4 yi   = {0.f, 0.f, 0.f, 0.f};
        f32x4 pacc = {0.f, 0.f, 0.f, 0.f};
        f32x4 yc   = {0.f, 0.f, 0.f, 0.f};
        uacc = __builtin_amdgcn_mfma_f32_16x16x32_bf16(R.M0, v0, uacc, 0, 0, 0);
        uacc = __builtin_amdgcn_mfma_f32_16x16x32_bf16(R.M1, v1, uacc, 0, 0, 0);
        yi   = __builtin_amdgcn_mfma_f32_16x16x32_bf16(R.A0, v0, yi, 0, 0, 0);
        yi   = __builtin_amdgcn_mfma_f32_16x16x32_bf16(R.A1, v1, yi, 0, 0, 0);
        pacc = __builtin_amdgcn_mfma_f32_16x16x32_bf16(R.B0, z0, pacc, 0, 0, 0);
        pacc = __builtin_amdgcn_mfma_f32_16x16x32_bf16(R.B1, z1, pacc, 0, 0, 0);
        yc   = __builtin_amdgcn_mfma_f32_16x16x32_bf16(R.Q0, z0, yc, 0, 0, 0);
        yc   = __builtin_amdgcn_mfma_f32_16x16x32_bf16(R.Q1, z1, yc, 0, 0, 0);

        alignas(8) bf16 pb[4];
        #pragma unroll
        for (int r = 0; r < 4; ++r) {
            out[gbase + (size_t)r * DD] = R.xld[r] + yi[r] + yc[r];
            pb[r] = __float2bfloat16(pacc[r] - uacc[r]);
        }
        *reinterpret_cast<uint2*>(&Psh[m][trow]) = *reinterpret_cast<uint2*>(pb);

        __syncthreads();                  // Psh ready, Zsh reads done
        const bf16x8 p0 = *reinterpret_cast<const bf16x8*>(&Psh[m][quad * 8]);
        const bf16x8 p1 = *reinterpret_cast<const bf16x8*>(&Psh[m][32 + quad * 8]);
        zacc = __builtin_amdgcn_mfma_f32_16x16x32_bf16(R.K0, p0, zacc, 0, 0, 0);
        zacc = __builtin_amdgcn_mfma_f32_16x16x32_bf16(R.K1, p1, zacc, 0, 0, 0);

        alignas(8) bf16 zb[4];
        #pragma unroll
        for (int r = 0; r < 4; ++r) zb[r] = __float2bfloat16(zacc[r]);
        *reinterpret_cast<uint2*>(&Zsh[m][trow]) = *reinterpret_cast<uint2*>(zb);
    };

    ChunkRegs R0, R1;
    load_chunk(0, R0);
    for (int c = 0; c < NC; c += 2) {
        // phase 0: compute chunk c, prefetch c+1
        stage_v(R0, 0);
        __syncthreads();                  // Zsh(c-1 update) + Vsh[0] ready
        load_chunk(c + 1, R1);
        compute(R0, c, 0);
        // phase 1: compute chunk c+1, prefetch c+2
        stage_v(R1, 1);
        __syncthreads();
        if (c + 2 < NC) load_chunk(c + 2, R0);
        compute(R1, c + 1, 1);
    }
}

// ---------------------------------------------------------------------------
extern "C" void kernel_launch(void* const* d_in, const int* in_sizes, int n_in,
                              void* d_out, int out_size, void* d_ws, size_t ws_size,
                              hipStream_t stream)
{
    const float* x     = (const float*)d_in[0];
    const float* Wk    = (const float*)d_in[1];
    const float* bk    = (const float*)d_in[2];
    const float* Wv    = (const float*)d_in[3];
    const float* bv    = (const float*)d_in[4];
    const float* Wq    = (const float*)d_in[5];
    const float* bq    = (const float*)d_in[6];
    const float* gamma = (const float*)d_in[7];
    const float* beta  = (const float*)d_in[8];

    char* ws = (char*)d_ws;
    // layout (~38.25 MiB):
    //   [0,16 MiB): hb (bf16, pre->kqv) -- dead after kqv; reused by prep as:
    //     Bb16@0, Qtb16@1MiB, Ktb16@2MiB, Mb16@3MiB, AMb16@4MiB (1 MiB each)
    //   [16 MiB, +2.25): Wcat (bf16 1152x1024)
    //   +2 MiB: kbuf (fp32)   +2 MiB: qbuf (fp32)
    //   +16 MiB: vbuf16 (bf16 8192x1024)
    const size_t WCAT_B = (size_t)NCAT * DD * 2;   // 2.25 MiB
    bf16*  hb    = (bf16*)ws;
    bf16*  Bb16  = (bf16*)(ws + 0 * MiB);
    bf16*  Qtb16 = (bf16*)(ws + 1 * MiB);
    bf16*  Ktb16 = (bf16*)(ws + 2 * MiB);
    bf16*  Mb16  = (bf16*)(ws + 3 * MiB);
    bf16*  AMb16 = (bf16*)(ws + 4 * MiB);
    bf16*  Wcat  = (bf16*)(ws + 16 * MiB);
    float* kbuf  = (float*)(ws + 16 * MiB + WCAT_B);
    float* qbuf  = (float*)(ws + 18 * MiB + WCAT_B);
    bf16*  v16   = (bf16*)(ws + 20 * MiB + WCAT_B);

    pre_kernel<<<NCVT + BB * SS, 256, 0, stream>>>(
        Wk, Wq, Wv, Wcat, x, gamma, beta, hb);
    kqv_kernel<<<dim3(NCAT / 128, BB * SS / 128), 256, 0, stream>>>(
        hb, Wcat, bk, bq, bv, kbuf, qbuf, v16);
    prep_kernel<<<dim3(NC, BB), 256, 0, stream>>>(
        kbuf, qbuf, Mb16, AMb16, Bb16, Qtb16, Ktb16);
    scan2_kernel<<<dim3(DD / 16, BB), 256, 0, stream>>>(
        Mb16, AMb16, Bb16, Qtb16, Ktb16, v16, x, (float*)d_out);
}

// Round 10
// 221.596 us; speedup vs baseline: 22.3711x; 1.0348x over previous
//
#include <hip/hip_runtime.h>
#include <hip/hip_bf16.h>

#define TTT_LR 0.01f
#define LN_EPS 1e-5f

// Problem dims (fixed by reference)
#define BB 4
#define SS 2048
#define DD 1024
#define DSZ 64
#define CHUNK 64
#define NC (SS / CHUNK)   // 32
#define NCAT 1152         // 64 k + 64 q + 1024 v output cols
#define NCVT (NCAT * DD / 4 / 256)   // 1152 cvt blocks
#define MiB (1024ull * 1024ull)

typedef __hip_bfloat16 bf16;
typedef __bf16 bf16x8 __attribute__((ext_vector_type(8)));
typedef float f32x4 __attribute__((ext_vector_type(4)));

__device__ __forceinline__ void gload_lds16(const void* g, void* l) {
    __builtin_amdgcn_global_load_lds(
        (const __attribute__((address_space(1))) unsigned int*)g,
        (__attribute__((address_space(3))) unsigned int*)l, 16, 0, 0);
}

// ---------------------------------------------------------------------------
// Kernel 1: merged pre-pass. Blocks [0,NCVT): Wk/Wq/Wv -> bf16 Wcat.
// Blocks [NCVT, NCVT+B*S): LayerNorm row -> h (bf16).
// ---------------------------------------------------------------------------
__global__ __launch_bounds__(256) void pre_kernel(
    const float* __restrict__ Wk, const float* __restrict__ Wq,
    const float* __restrict__ Wv, bf16* __restrict__ Wcat,
    const float* __restrict__ x, const float* __restrict__ gamma,
    const float* __restrict__ beta, bf16* __restrict__ hb)
{
    __shared__ float wsum[4], wsum2[4];
    const int tid = threadIdx.x;

    if (blockIdx.x < NCVT) {
        const int i = blockIdx.x * 256 + tid;           // float4 group index
        const int idx = i * 4;
        const int row = idx >> 10, col = idx & 1023;
        const float* src = (row < 64)  ? (Wk + (size_t)row * DD)
                         : (row < 128) ? (Wq + (size_t)(row - 64) * DD)
                                       : (Wv + (size_t)(row - 128) * DD);
        float4 v = *reinterpret_cast<const float4*>(src + col);
        bf16 h4[4] = {__float2bfloat16(v.x), __float2bfloat16(v.y),
                      __float2bfloat16(v.z), __float2bfloat16(v.w)};
        *reinterpret_cast<ushort4*>(Wcat + idx) = *reinterpret_cast<ushort4*>(h4);
        return;
    }

    const int row = blockIdx.x - NCVT;
    const int lane = tid & 63, wave = tid >> 6;

    float4 v0 = *reinterpret_cast<const float4*>(x + (size_t)row * DD + tid * 4);
    float s = v0.x + v0.y + v0.z + v0.w;
    float s2 = fmaf(v0.x, v0.x, fmaf(v0.y, v0.y, fmaf(v0.z, v0.z, v0.w * v0.w)));
    #pragma unroll
    for (int off = 32; off > 0; off >>= 1) {
        s  += __shfl_down(s, off, 64);
        s2 += __shfl_down(s2, off, 64);
    }
    if (lane == 0) { wsum[wave] = s; wsum2[wave] = s2; }
    __syncthreads();
    s  = wsum[0] + wsum[1] + wsum[2] + wsum[3];
    s2 = wsum2[0] + wsum2[1] + wsum2[2] + wsum2[3];
    const float mu = s * (1.0f / DD);
    const float rs = rsqrtf(s2 * (1.0f / DD) - mu * mu + LN_EPS);

    float4 g  = *reinterpret_cast<const float4*>(gamma + tid * 4);
    float4 be = *reinterpret_cast<const float4*>(beta + tid * 4);
    bf16 h4[4];
    h4[0] = __float2bfloat16((v0.x - mu) * rs * g.x + be.x);
    h4[1] = __float2bfloat16((v0.y - mu) * rs * g.y + be.y);
    h4[2] = __float2bfloat16((v0.z - mu) * rs * g.z + be.z);
    h4[3] = __float2bfloat16((v0.w - mu) * rs * g.w + be.w);
    *reinterpret_cast<ushort4*>(hb + (size_t)row * DD + tid * 4) =
        *reinterpret_cast<ushort4*>(h4);
}

// ---------------------------------------------------------------------------
// Kernel 2: fused kqv = h @ Wcat^T + bias. 128x128 tile, BK=64,
// global_load_lds(16B) staging, XOR-swizzled 16B blocks. k/q stored fp32;
// v stored bf16 (vbuf16) for the MFMA scan.
// ---------------------------------------------------------------------------
__global__ __launch_bounds__(256) void kqv_kernel(
    const bf16* __restrict__ h, const bf16* __restrict__ Wcat,
    const float* __restrict__ bk, const float* __restrict__ bq,
    const float* __restrict__ bv,
    float* __restrict__ kbuf, float* __restrict__ qbuf, bf16* __restrict__ vbuf16)
{
    __shared__ bf16 Ash[128 * 64];
    __shared__ bf16 Bsh[128 * 64];
    const int tid = threadIdx.x, lane = tid & 63, wave = tid >> 6;
    const int m = lane & 15, quad = lane >> 4;
    const int wr = wave >> 1, wc = wave & 1;
    const int m0 = blockIdx.y * 128;     // h rows
    const int n0 = blockIdx.x * 128;     // Wcat rows

    const int srow = wave * 8 + (lane >> 3);   // staging row (+ i*32)
    const int scb = lane & 7;                  // staging 16B-block in row

    f32x4 acc[4][4] = {};

    for (int k0 = 0; k0 < DD; k0 += 64) {
        __syncthreads();                       // prior frag reads done
        #pragma unroll
        for (int i = 0; i < 4; ++i) {
            const int row = i * 32 + srow;
            const int g16 = scb ^ (row & 7);   // swizzled source block
            gload_lds16(h    + (size_t)(m0 + row) * DD + k0 + g16 * 8,
                        (char*)Ash + (size_t)(i * 32 + wave * 8) * 128);
            gload_lds16(Wcat + (size_t)(n0 + row) * DD + k0 + g16 * 8,
                        (char*)Bsh + (size_t)(i * 32 + wave * 8) * 128);
        }
        __syncthreads();                       // DMA drained (vmcnt0 @ barrier)
        #pragma unroll
        for (int ks = 0; ks < 2; ++ks) {
            bf16x8 af[4], bfr[4];
            #pragma unroll
            for (int mt = 0; mt < 4; ++mt) {
                const int row = wr * 64 + mt * 16 + m;
                const int kb = (ks * 4 + quad) ^ (row & 7);
                af[mt] = *reinterpret_cast<const bf16x8*>(&Ash[row * 64 + kb * 8]);
            }
            #pragma unroll
            for (int nt = 0; nt < 4; ++nt) {
                const int row = wc * 64 + nt * 16 + m;
                const int kb = (ks * 4 + quad) ^ (row & 7);
                bfr[nt] = *reinterpret_cast<const bf16x8*>(&Bsh[row * 64 + kb * 8]);
            }
            #pragma unroll
            for (int mt = 0; mt < 4; ++mt)
                #pragma unroll
                for (int nt = 0; nt < 4; ++nt)
                    acc[mt][nt] = __builtin_amdgcn_mfma_f32_16x16x32_bf16(
                        af[mt], bfr[nt], acc[mt][nt], 0, 0, 0);
        }
    }

    #pragma unroll
    for (int nt = 0; nt < 4; ++nt) {
        const int n = n0 + wc * 64 + nt * 16 + m;
        if (n < 64) {
            const float bias = bk[n];
            #pragma unroll
            for (int mt = 0; mt < 4; ++mt) {
                const int row = m0 + wr * 64 + mt * 16 + quad * 4;
                #pragma unroll
                for (int r = 0; r < 4; ++r)
                    kbuf[(size_t)(row + r) * DSZ + n] = acc[mt][nt][r] + bias;
            }
        } else if (n < 128) {
            const float bias = bq[n - 64];
            #pragma unroll
            for (int mt = 0; mt < 4; ++mt) {
                const int row = m0 + wr * 64 + mt * 16 + quad * 4;
                #pragma unroll
                for (int r = 0; r < 4; ++r)
                    qbuf[(size_t)(row + r) * DSZ + (n - 64)] = acc[mt][nt][r] + bias;
            }
        } else {
            const float bias = bv[n - 128];
            #pragma unroll
            for (int mt = 0; mt < 4; ++mt) {
                const int row = m0 + wr * 64 + mt * 16 + quad * 4;
                #pragma unroll
                for (int r = 0; r < 4; ++r)
                    vbuf16[(size_t)(row + r) * DD + (n - 128)] =
                        __float2bfloat16(acc[mt][nt][r] + bias);
            }
        }
    }
}

// ---------------------------------------------------------------------------
// Kernel 3: per-(b,chunk) prep — MFMA. Outputs 4 chunk matrices (bf16):
//   Qtb16 = Q - Astl*B          (A-rows = t)
//   AMb16 = Astl*(lr*Minv)      (A-rows = t)
//   Tb16  = -K^T B              (A-rows = s)   [Z-update transition]
//   Wb16  = K^T (lr*Minv)       (A-rows = s)   [Z-update drive]
// where B = (lr*Minv)*K, Minv = (I + lr*trilS(G))^-1 (serial solve, fp32),
// G = K K^T, A = Q K^T (strict-lower).
// ---------------------------------------------------------------------------
__global__ __launch_bounds__(256) void prep_kernel(
    const float* __restrict__ kbuf, const float* __restrict__ qbuf,
    bf16* __restrict__ Tb16, bf16* __restrict__ Wb16,
    bf16* __restrict__ AMb16, bf16* __restrict__ Qtb16)
{
    __shared__ bf16 K16[64 * 72];      // K  [t][s]
    __shared__ bf16 Kt16[64 * 72];     // K^T [s][t]
    __shared__ bf16 Q16[64 * 72];      // Q  [t][s]
    __shared__ bf16 Astl[64 * 72];     // strict-lower A, zeros elsewhere
    __shared__ bf16 Minv16[64 * 72];   // lr*Minv [t][j]
    __shared__ bf16 MinvT16[64 * 72];  // (lr*Minv)^T [j][t]
    __shared__ bf16 BnegT[64 * 72];    // -B^T [s][t]
    __shared__ float Gf[64 * 65];      // lr*G (fp32, solve input)
    __shared__ float Mf[64 * 65];      // Minv (fp32, solve output)

    const int c = blockIdx.x, b = blockIdx.y;
    const int tid = threadIdx.x, lane = tid & 63, w = tid >> 6;
    const int m = lane & 15, quad = lane >> 4;
    const float* kp = kbuf + ((size_t)b * SS + c * 64) * DSZ;
    const float* qp = qbuf + ((size_t)b * SS + c * 64) * DSZ;
    const size_t cb = ((size_t)b * NC + c) * 4096;

    // ---- stage K (row + transposed) and Q as bf16
    #pragma unroll
    for (int it = 0; it < 4; ++it) {
        const int f4 = tid + it * 256;          // float4 index 0..1023
        const int t = f4 >> 4;
        const int s = (f4 & 15) * 4;
        float4 kv = *reinterpret_cast<const float4*>(kp + t * DSZ + s);
        float4 qv = *reinterpret_cast<const float4*>(qp + t * DSZ + s);
        bf16 kb4[4] = {__float2bfloat16(kv.x), __float2bfloat16(kv.y),
                       __float2bfloat16(kv.z), __float2bfloat16(kv.w)};
        bf16 qb4[4] = {__float2bfloat16(qv.x), __float2bfloat16(qv.y),
                       __float2bfloat16(qv.z), __float2bfloat16(qv.w)};
        *reinterpret_cast<ushort4*>(&K16[t * 72 + s]) = *reinterpret_cast<ushort4*>(kb4);
        *reinterpret_cast<ushort4*>(&Q16[t * 72 + s]) = *reinterpret_cast<ushort4*>(qb4);
        #pragma unroll
        for (int i = 0; i < 4; ++i) Kt16[(s + i) * 72 + t] = kb4[i];
    }
    __syncthreads();

    // ---- G = K K^T (store lr*G fp32), A = Q K^T (store strict-lower bf16)
    bf16x8 afK[2], afQ[2], bfK[4][2];
    #pragma unroll
    for (int ks = 0; ks < 2; ++ks) {
        afK[ks] = *reinterpret_cast<const bf16x8*>(&K16[(w * 16 + m) * 72 + ks * 32 + quad * 8]);
        afQ[ks] = *reinterpret_cast<const bf16x8*>(&Q16[(w * 16 + m) * 72 + ks * 32 + quad * 8]);
        #pragma unroll
        for (int nt = 0; nt < 4; ++nt)
            bfK[nt][ks] = *reinterpret_cast<const bf16x8*>(&K16[(nt * 16 + m) * 72 + ks * 32 + quad * 8]);
    }
    f32x4 gacc[4] = {}, aacc[4] = {};
    #pragma unroll
    for (int ks = 0; ks < 2; ++ks)
        #pragma unroll
        for (int nt = 0; nt < 4; ++nt) {
            gacc[nt] = __builtin_amdgcn_mfma_f32_16x16x32_bf16(afK[ks], bfK[nt][ks], gacc[nt], 0, 0, 0);
            aacc[nt] = __builtin_amdgcn_mfma_f32_16x16x32_bf16(afQ[ks], bfK[nt][ks], aacc[nt], 0, 0, 0);
        }
    #pragma unroll
    for (int nt = 0; nt < 4; ++nt)
        #pragma unroll
        for (int r = 0; r < 4; ++r) {
            const int t = w * 16 + quad * 4 + r, j = nt * 16 + m;
            Gf[t * 65 + j] = TTT_LR * gacc[nt][r];
            Astl[t * 72 + j] = __float2bfloat16(j < t ? aacc[nt][r] : 0.f);
        }
    __syncthreads();

    // ---- serial forward-substitution: Minv = (I + lr*trilS(G))^-1 (fp32)
    if (tid < 64) {
        for (int t = 0; t < 64; ++t) {
            float acc = (t == tid) ? 1.f : 0.f;
            for (int i = 0; i < t; ++i)
                acc = fmaf(-Gf[t * 65 + i], Mf[i * 65 + tid], acc);
            Mf[t * 65 + tid] = acc;
        }
    }
    __syncthreads();

    // ---- lr*Minv -> bf16 (row + transposed)
    #pragma unroll
    for (int it = 0; it < 16; ++it) {
        const int e = tid + it * 256;           // 0..4095
        const int t = e >> 6, j = e & 63;
        const bf16 vb = __float2bfloat16(TTT_LR * Mf[t * 65 + j]);
        Minv16[t * 72 + j] = vb;
        MinvT16[j * 72 + t] = vb;
    }
    __syncthreads();

    // ---- B = (lr*Minv) * K  via mfma(Minv16 rows, Kt16 rows)
    bf16x8 afM[2], afA[2], afKt[2], bfKt[4][2], bfMt[4][2];
    #pragma unroll
    for (int ks = 0; ks < 2; ++ks) {
        afM[ks]  = *reinterpret_cast<const bf16x8*>(&Minv16[(w * 16 + m) * 72 + ks * 32 + quad * 8]);
        afA[ks]  = *reinterpret_cast<const bf16x8*>(&Astl[(w * 16 + m) * 72 + ks * 32 + quad * 8]);
        afKt[ks] = *reinterpret_cast<const bf16x8*>(&Kt16[(w * 16 + m) * 72 + ks * 32 + quad * 8]);
        #pragma unroll
        for (int nt = 0; nt < 4; ++nt) {
            bfKt[nt][ks] = *reinterpret_cast<const bf16x8*>(&Kt16[(nt * 16 + m) * 72 + ks * 32 + quad * 8]);
            bfMt[nt][ks] = *reinterpret_cast<const bf16x8*>(&MinvT16[(nt * 16 + m) * 72 + ks * 32 + quad * 8]);
        }
    }
    f32x4 bacc[4] = {};
    #pragma unroll
    for (int ks = 0; ks < 2; ++ks)
        #pragma unroll
        for (int nt = 0; nt < 4; ++nt)
            bacc[nt] = __builtin_amdgcn_mfma_f32_16x16x32_bf16(afM[ks], bfKt[nt][ks], bacc[nt], 0, 0, 0);
    #pragma unroll
    for (int nt = 0; nt < 4; ++nt)
        #pragma unroll
        for (int r = 0; r < 4; ++r) {
            const int t = w * 16 + quad * 4 + r, s = nt * 16 + m;
            BnegT[s * 72 + t] = __float2bfloat16(-bacc[nt][r]);
        }
    __syncthreads();

    // ---- Qt = Q - Astl*B (C-init = Q), AM = Astl*(lr*Minv),
    //      T' = -K^T B = mfma(Kt rows, BnegT rows),
    //      W  =  K^T (lr*Minv) = mfma(Kt rows, MinvT rows)
    f32x4 qtacc[4], amacc[4] = {}, tacc[4] = {}, wacc[4] = {};
    #pragma unroll
    for (int nt = 0; nt < 4; ++nt)
        #pragma unroll
        for (int r = 0; r < 4; ++r)
            qtacc[nt][r] = qp[(w * 16 + quad * 4 + r) * DSZ + nt * 16 + m];
    #pragma unroll
    for (int ks = 0; ks < 2; ++ks)
        #pragma unroll
        for (int nt = 0; nt < 4; ++nt) {
            const bf16x8 bfBn = *reinterpret_cast<const bf16x8*>(
                &BnegT[(nt * 16 + m) * 72 + ks * 32 + quad * 8]);
            qtacc[nt] = __builtin_amdgcn_mfma_f32_16x16x32_bf16(afA[ks], bfBn, qtacc[nt], 0, 0, 0);
            amacc[nt] = __builtin_amdgcn_mfma_f32_16x16x32_bf16(afA[ks], bfMt[nt][ks], amacc[nt], 0, 0, 0);
            tacc[nt]  = __builtin_amdgcn_mfma_f32_16x16x32_bf16(afKt[ks], bfBn, tacc[nt], 0, 0, 0);
            wacc[nt]  = __builtin_amdgcn_mfma_f32_16x16x32_bf16(afKt[ks], bfMt[nt][ks], wacc[nt], 0, 0, 0);
        }
    #pragma unroll
    for (int nt = 0; nt < 4; ++nt)
        #pragma unroll
        for (int r = 0; r < 4; ++r) {
            const int row = w * 16 + quad * 4 + r, col = nt * 16 + m;
            Qtb16[cb + row * 64 + col] = __float2bfloat16(qtacc[nt][r]);
            AMb16[cb + row * 64 + col] = __float2bfloat16(amacc[nt][r]);
            Tb16[cb + row * 64 + col]  = __float2bfloat16(tacc[nt][r]);
            Wb16[cb + row * 64 + col]  = __float2bfloat16(wacc[nt][r]);
        }
}

// ---------------------------------------------------------------------------
// Kernel 4: fused scan, ONE barrier per chunk. 256 blocks (64 d-stripes x
// 4 batches), 4 waves. Per chunk (8 MFMAs):
//   out  = x + AM V + Qt Z                         (single store)
//   zacc += T' Z + W V    (persistent fp32; Z_bf16 double-buffered in LDS)
// Z/V both read as B-frags from [d][.] LDS layouts; prefetch c+1 globals.
// ---------------------------------------------------------------------------
struct ChunkRegs {
    bf16x8 T0, T1, W0, W1, A0, A1, Q0, Q1;
    alignas(8) unsigned short va[4], vb[4];   // V rows (vj2, vj2+1) x 4 cols
    float xld[4];
};

__global__ __launch_bounds__(256) void scan2_kernel(
    const bf16* __restrict__ Tb16, const bf16* __restrict__ Wb16,
    const bf16* __restrict__ AMb16, const bf16* __restrict__ Qtb16,
    const bf16* __restrict__ v16, const float* __restrict__ x,
    float* __restrict__ out)
{
    __shared__ bf16 Zsh[2][16][72];
    __shared__ bf16 Vsh[2][16][72];
    const int dblk = blockIdx.x, b = blockIdx.y;
    const int tid = threadIdx.x, lane = tid & 63, w = tid >> 6;
    const int m = lane & 15, quad = lane >> 4;
    const int d0 = dblk * 16;
    const int arow = w * 16 + m;          // A-frag row (all matmuls)
    const int trow = w * 16 + quad * 4;   // first C/D row for this thread

    // V staging: tid<128; row pair vj2, col group vd (4 cols)
    const bool vact = tid < 128;
    const int vj2 = (tid & 31) * 2;
    const int vd = (tid >> 5) * 4;        // 0,4,8,12 for tid<128

    f32x4 zacc = {0.f, 0.f, 0.f, 0.f};
    for (int i = tid; i < 16 * 72; i += 256)
        (&Zsh[0][0][0])[i] = __float2bfloat16(0.f);

    auto load_chunk = [&](int c, ChunkRegs& R) {
        const size_t cb = ((size_t)b * NC + c) * 4096;
        const size_t rowbase = (size_t)b * SS + (size_t)c * 64;
        R.T0 = *reinterpret_cast<const bf16x8*>(Tb16 + cb + arow * 64 + quad * 8);
        R.T1 = *reinterpret_cast<const bf16x8*>(Tb16 + cb + arow * 64 + 32 + quad * 8);
        R.W0 = *reinterpret_cast<const bf16x8*>(Wb16 + cb + arow * 64 + quad * 8);
        R.W1 = *reinterpret_cast<const bf16x8*>(Wb16 + cb + arow * 64 + 32 + quad * 8);
        R.A0 = *reinterpret_cast<const bf16x8*>(AMb16 + cb + arow * 64 + quad * 8);
        R.A1 = *reinterpret_cast<const bf16x8*>(AMb16 + cb + arow * 64 + 32 + quad * 8);
        R.Q0 = *reinterpret_cast<const bf16x8*>(Qtb16 + cb + arow * 64 + quad * 8);
        R.Q1 = *reinterpret_cast<const bf16x8*>(Qtb16 + cb + arow * 64 + 32 + quad * 8);
        if (vact) {
            *reinterpret_cast<uint2*>(R.va) = *reinterpret_cast<const uint2*>(
                v16 + (rowbase + vj2) * DD + d0 + vd);
            *reinterpret_cast<uint2*>(R.vb) = *reinterpret_cast<const uint2*>(
                v16 + (rowbase + vj2 + 1) * DD + d0 + vd);
        }
        const size_t gbase = (rowbase + trow) * DD + d0 + m;
        #pragma unroll
        for (int r = 0; r < 4; ++r) R.xld[r] = x[gbase + (size_t)r * DD];
    };

    auto stage_v = [&](const ChunkRegs& R, int buf) {
        if (vact) {
            #pragma unroll
            for (int i = 0; i < 4; ++i) {
                const unsigned int pack =
                    (unsigned int)R.va[i] | ((unsigned int)R.vb[i] << 16);
                *reinterpret_cast<unsigned int*>(&Vsh[buf][vd + i][vj2]) = pack;
            }
        }
    };

    auto compute = [&](const ChunkRegs& R, int c, int buf) {
        const size_t gbase = ((size_t)b * SS + (size_t)c * 64 + trow) * DD + d0 + m;
        const bf16x8 z0 = *reinterpret_cast<const bf16x8*>(&Zsh[buf][m][quad * 8]);
        const bf16x8 z1 = *reinterpret_cast<const bf16x8*>(&Zsh[buf][m][32 + quad * 8]);
        const bf16x8 v0 = *reinterpret_cast<const bf16x8*>(&Vsh[buf][m][quad * 8]);
        const bf16x8 v1 = *reinterpret_cast<const bf16x8*>(&Vsh[buf][m][32 + quad * 8]);

        // Z update (persistent fp32 accumulator, increment form)
        zacc = __builtin_amdgcn_mfma_f32_16x16x32_bf16(R.T0, z0, zacc, 0, 0, 0);
        zacc = __builtin_amdgcn_mfma_f32_16x16x32_bf16(R.T1, z1, zacc, 0, 0, 0);
        zacc = __builtin_amdgcn_mfma_f32_16x16x32_bf16(R.W0, v0, zacc, 0, 0, 0);
        zacc = __builtin_amdgcn_mfma_f32_16x16x32_bf16(R.W1, v1, zacc, 0, 0, 0);

        // y = Qt Z + AM V
        f32x4 y = {0.f, 0.f, 0.f, 0.f};
        y = __builtin_amdgcn_mfma_f32_16x16x32_bf16(R.Q0, z0, y, 0, 0, 0);
        y = __builtin_amdgcn_mfma_f32_16x16x32_bf16(R.Q1, z1, y, 0, 0, 0);
        y = __builtin_amdgcn_mfma_f32_16x16x32_bf16(R.A0, v0, y, 0, 0, 0);
        y = __builtin_amdgcn_mfma_f32_16x16x32_bf16(R.A1, v1, y, 0, 0, 0);

        // write new Z (bf16) into the other buffer
        alignas(8) bf16 zb[4];
        #pragma unroll
        for (int r = 0; r < 4; ++r) zb[r] = __float2bfloat16(zacc[r]);
        *reinterpret_cast<uint2*>(&Zsh[buf ^ 1][m][trow]) =
            *reinterpret_cast<uint2*>(zb);

        #pragma unroll
        for (int r = 0; r < 4; ++r)
            out[gbase + (size_t)r * DD] = R.xld[r] + y[r];
    };

    ChunkRegs R0, R1;
    load_chunk(0, R0);
    for (int c = 0; c < NC; c += 2) {
        // phase 0: chunk c (buffers 0), prefetch c+1
        stage_v(R0, 0);
        __syncthreads();                  // Vsh[0] + Zsh[0] ready
        load_chunk(c + 1, R1);
        compute(R0, c, 0);                // reads buf 0, writes Zsh[1]
        // phase 1: chunk c+1 (buffers 1), prefetch c+2
        stage_v(R1, 1);
        __syncthreads();                  // Vsh[1] + Zsh[1] ready
        if (c + 2 < NC) load_chunk(c + 2, R0);
        compute(R1, c + 1, 1);            // reads buf 1, writes Zsh[0]
    }
}

// ---------------------------------------------------------------------------
extern "C" void kernel_launch(void* const* d_in, const int* in_sizes, int n_in,
                              void* d_out, int out_size, void* d_ws, size_t ws_size,
                              hipStream_t stream)
{
    const float* x     = (const float*)d_in[0];
    const float* Wk    = (const float*)d_in[1];
    const float* bk    = (const float*)d_in[2];
    const float* Wv    = (const float*)d_in[3];
    const float* bv    = (const float*)d_in[4];
    const float* Wq    = (const float*)d_in[5];
    const float* bq    = (const float*)d_in[6];
    const float* gamma = (const float*)d_in[7];
    const float* beta  = (const float*)d_in[8];

    char* ws = (char*)d_ws;
    // layout (~38.25 MiB):
    //   [0,16 MiB): hb (bf16, pre->kqv) -- dead after kqv; reused by prep as:
    //     Tb16@0, Qtb16@1MiB, Wb16@2MiB, AMb16@3MiB (1 MiB each)
    //   [16 MiB, +2.25): Wcat (bf16 1152x1024)
    //   +2 MiB: kbuf (fp32)   +2 MiB: qbuf (fp32)
    //   +16 MiB: vbuf16 (bf16 8192x1024)
    const size_t WCAT_B = (size_t)NCAT * DD * 2;   // 2.25 MiB
    bf16*  hb    = (bf16*)ws;
    bf16*  Tb16  = (bf16*)(ws + 0 * MiB);
    bf16*  Qtb16 = (bf16*)(ws + 1 * MiB);
    bf16*  Wb16  = (bf16*)(ws + 2 * MiB);
    bf16*  AMb16 = (bf16*)(ws + 3 * MiB);
    bf16*  Wcat  = (bf16*)(ws + 16 * MiB);
    float* kbuf  = (float*)(ws + 16 * MiB + WCAT_B);
    float* qbuf  = (float*)(ws + 18 * MiB + WCAT_B);
    bf16*  v16   = (bf16*)(ws + 20 * MiB + WCAT_B);

    pre_kernel<<<NCVT + BB * SS, 256, 0, stream>>>(
        Wk, Wq, Wv, Wcat, x, gamma, beta, hb);
    kqv_kernel<<<dim3(NCAT / 128, BB * SS / 128), 256, 0, stream>>>(
        hb, Wcat, bk, bq, bv, kbuf, qbuf, v16);
    prep_kernel<<<dim3(NC, BB), 256, 0, stream>>>(
        kbuf, qbuf, Tb16, Wb16, AMb16, Qtb16);
    scan2_kernel<<<dim3(DD / 16, BB), 256, 0, stream>>>(
        Tb16, Wb16, AMb16, Qtb16, v16, x, (float*)d_out);
}